// Round 1
// baseline (4640.639 us; speedup 1.0000x reference)
//
#include <hip/hip_runtime.h>
#include <math.h>

// Model dims
#define B_ 16
#define N_ 512
#define D_ 256
#define HEADS_ 8
#define DH_ 32
#define HIDEF_ 1024
#define NBLK_ 16     // N/BLOCK
#define BS_ 32       // BLOCK
#define BAND_ 160    // (2w+1)*BS, w=2
#define LEVELS_ 5
#define PYOUT_ 128
#define ROWS_ (B_ * N_)   // 8192

// ---------------------------------------------------------------- position
__global__ void pos_kernel(float* __restrict__ pos) {
    int idx = blockIdx.x * 256 + threadIdx.x;   // 512*256
    if (idx >= N_ * D_) return;
    int n = idx >> 8, i = idx & 255;
    double angle = (double)n / pow(10000.0, (double)(2 * (i >> 1)) / 256.0);
    pos[idx] = (float)((i & 1) ? cos(angle) : sin(angle));
}

// ---------------------------------------------------------------- GELU
__device__ __forceinline__ float gelu_f(float x) {
    float x3 = x * x * x;
    return 0.5f * x * (1.f + tanhf(0.7978845608028654f * (x + 0.044715f * x3)));
}

// ---------------------------------------------------------------- tiled GEMM
// C[M,Nn] = act(A[M,K] @ W[K,Nn] + bias) (+ resid).  M%64==0, Nn%64==0 or Nn==128, K%16==0
template <int ACT>   // 0 none, 1 gelu
__global__ __launch_bounds__(256) void gemm_kernel(
    const float* __restrict__ A, const float* __restrict__ W,
    const float* __restrict__ bias, const float* __restrict__ resid,
    float* __restrict__ C, int M, int K, int Nn) {
    __shared__ float As[64][17];
    __shared__ float Bs[16][65];
    int tid = threadIdx.x;
    int row0 = blockIdx.y * 64, col0 = blockIdx.x * 64;
    int ty = tid >> 4, tx = tid & 15;
    float acc[4][4] = {{0.f}};
    int ar = tid >> 2, ac4 = (tid & 3) * 4;   // A-tile load coords
    int br = tid >> 4, bc4 = (tid & 15) * 4;  // B-tile load coords
    for (int k0 = 0; k0 < K; k0 += 16) {
        float4 av = *reinterpret_cast<const float4*>(&A[(size_t)(row0 + ar) * K + k0 + ac4]);
        As[ar][ac4 + 0] = av.x; As[ar][ac4 + 1] = av.y;
        As[ar][ac4 + 2] = av.z; As[ar][ac4 + 3] = av.w;
        float4 bv = *reinterpret_cast<const float4*>(&W[(size_t)(k0 + br) * Nn + col0 + bc4]);
        Bs[br][bc4 + 0] = bv.x; Bs[br][bc4 + 1] = bv.y;
        Bs[br][bc4 + 2] = bv.z; Bs[br][bc4 + 3] = bv.w;
        __syncthreads();
#pragma unroll
        for (int k = 0; k < 16; k++) {
            float a[4], b[4];
#pragma unroll
            for (int i = 0; i < 4; i++) a[i] = As[ty * 4 + i][k];
#pragma unroll
            for (int j = 0; j < 4; j++) b[j] = Bs[k][tx * 4 + j];
#pragma unroll
            for (int i = 0; i < 4; i++)
#pragma unroll
                for (int j = 0; j < 4; j++) acc[i][j] += a[i] * b[j];
        }
        __syncthreads();
    }
#pragma unroll
    for (int i = 0; i < 4; i++) {
        int r = row0 + ty * 4 + i;
#pragma unroll
        for (int j = 0; j < 4; j++) {
            int c = col0 + tx * 4 + j;
            float v = acc[i][j] + bias[c];
            if (resid) v += resid[(size_t)r * Nn + c];
            if (ACT == 1) v = gelu_f(v);
            C[(size_t)r * Nn + c] = v;
        }
    }
}

// ---------------------------------------------------------------- LN + pos
__global__ __launch_bounds__(256) void ln_pos_kernel(
    const float* __restrict__ t, const float* __restrict__ g,
    const float* __restrict__ b, const float* __restrict__ pos,
    float* __restrict__ h) {
    int row = blockIdx.x;           // b*N + n
    int n = row & (N_ - 1);
    int d = threadIdx.x;
    float v = t[(size_t)row * D_ + d];
    __shared__ float red[256];
    red[d] = v; __syncthreads();
    for (int s = 128; s > 0; s >>= 1) { if (d < s) red[d] += red[d + s]; __syncthreads(); }
    float mean = red[0] / 256.f;
    __syncthreads();
    float dv = v - mean;
    red[d] = dv * dv; __syncthreads();
    for (int s = 128; s > 0; s >>= 1) { if (d < s) red[d] += red[d + s]; __syncthreads(); }
    float var = red[0] / 256.f;
    h[(size_t)row * D_ + d] = dv * rsqrtf(var + 1e-5f) * g[d] + b[d] + pos[n * D_ + d];
}

// ---------------------------------------------------------------- BN stats (per-channel over B*N)
__global__ __launch_bounds__(256) void bn_stats_kernel(
    const float* __restrict__ x, float* __restrict__ stats) {
    int c = blockIdx.x;             // 0..255
    int tid = threadIdx.x;
    float s = 0.f, s2 = 0.f;
    for (int i = tid; i < ROWS_; i += 256) {
        float v = x[(size_t)i * D_ + c];
        s += v; s2 += v * v;
    }
    __shared__ float r1[256], r2[256];
    r1[tid] = s; r2[tid] = s2; __syncthreads();
    for (int st = 128; st > 0; st >>= 1) {
        if (tid < st) { r1[tid] += r1[tid + st]; r2[tid] += r2[tid + st]; }
        __syncthreads();
    }
    if (tid == 0) {
        float m = r1[0] / (float)ROWS_;
        stats[c] = m;
        stats[D_ + c] = r2[0] / (float)ROWS_ - m * m;
    }
}

__global__ __launch_bounds__(256) void bn_apply_kernel(
    const float* __restrict__ x, const float* __restrict__ stats,
    const float* __restrict__ g, const float* __restrict__ b,
    float* __restrict__ y) {
    int row = blockIdx.x;
    int c = threadIdx.x;
    float m = stats[c], var = stats[D_ + c];
    float v = x[(size_t)row * D_ + c];
    y[(size_t)row * D_ + c] = (v - m) * rsqrtf(var + 1e-5f) * g[c] + b[c];
}

// ---------------------------------------------------------------- windowed block-sparse attention
// qkv: [B,N,768] (q|k|v).  out: [B,N,256]
__global__ __launch_bounds__(256) void attn_kernel(
    const float* __restrict__ qkv, float* __restrict__ out) {
    int i = blockIdx.x;   // query block 0..15
    int h = blockIdx.y;   // head
    int b = blockIdx.z;   // batch
    int tid = threadIdx.x;
    __shared__ float qs[BS_][DH_ + 1];
    __shared__ float ks[BAND_][DH_ + 1];     // reused for V in PV phase
    __shared__ float ss[BS_][BAND_ + 1];
    __shared__ float red[BS_][8];
    __shared__ float rowsum[BS_];
    __shared__ float rowmax[BS_];

    // load Q block
    for (int e = tid; e < BS_ * DH_; e += 256) {
        int r = e >> 5, d = e & 31;
        qs[r][d] = qkv[((size_t)(b * N_ + i * BS_ + r)) * 768 + h * DH_ + d];
    }
    // load K band
    for (int e = tid; e < BAND_ * DH_; e += 256) {
        int c = e >> 5, d = e & 31;
        int jb = i - 2 + (c >> 5);
        float v = 0.f;
        if (jb >= 0 && jb < NBLK_)
            v = qkv[((size_t)(b * N_ + jb * BS_ + (c & 31))) * 768 + 256 + h * DH_ + d];
        ks[c][d] = v;
    }
    __syncthreads();

    const float scale = 0.17677669529663687f;   // 1/sqrt(32)
    for (int e = tid; e < BS_ * BAND_; e += 256) {
        int r = e / BAND_, c = e % BAND_;
        int jb = i - 2 + (c >> 5);
        float s;
        if (jb >= 0 && jb < NBLK_) {
            float acc = 0.f;
#pragma unroll
            for (int d = 0; d < DH_; d++) acc += qs[r][d] * ks[c][d];
            s = acc * scale;
        } else s = -1e9f;
        ss[r][c] = s;
    }
    __syncthreads();

    // softmax per row: 8 threads per row
    int r = tid >> 3, lane = tid & 7;
    float mx = -1e30f;
    for (int c = lane; c < BAND_; c += 8) mx = fmaxf(mx, ss[r][c]);
    red[r][lane] = mx; __syncthreads();
    if (lane == 0) {
        float m = red[r][0];
#pragma unroll
        for (int t = 1; t < 8; t++) m = fmaxf(m, red[r][t]);
        rowmax[r] = m;
    }
    __syncthreads();
    float m = rowmax[r];
    float sum = 0.f;
    for (int c = lane; c < BAND_; c += 8) {
        float e_ = expf(ss[r][c] - m);
        ss[r][c] = e_;
        sum += e_;
    }
    red[r][lane] = sum; __syncthreads();
    if (lane == 0) {
        float s_ = 0.f;
#pragma unroll
        for (int t = 0; t < 8; t++) s_ += red[r][t];
        rowsum[r] = s_;
    }
    __syncthreads();

    // reload band with V (reuse ks)
    for (int e = tid; e < BAND_ * DH_; e += 256) {
        int c = e >> 5, d = e & 31;
        int jb = i - 2 + (c >> 5);
        float v = 0.f;
        if (jb >= 0 && jb < NBLK_)
            v = qkv[((size_t)(b * N_ + jb * BS_ + (c & 31))) * 768 + 512 + h * DH_ + d];
        ks[c][d] = v;
    }
    __syncthreads();

    // PV
    for (int e = tid; e < BS_ * DH_; e += 256) {
        int qr = e >> 5, d = e & 31;
        float acc = 0.f;
        for (int c = 0; c < BAND_; c++) acc += ss[qr][c] * ks[c][d];
        out[((size_t)(b * N_ + i * BS_ + qr)) * D_ + h * DH_ + d] = acc / rowsum[qr];
    }
}

// ---------------------------------------------------------------- pyramid scatter
// P: [8192,128] (= X@pyr_W[l] + pyr_b[l]) -> flat[b, (l*128+c)*512 + n]
__global__ __launch_bounds__(256) void pyr_scatter_kernel(
    const float* __restrict__ P, float* __restrict__ flat, int level) {
    int idx = blockIdx.x * 256 + threadIdx.x;   // 8192*128
    int bn = idx >> 7, c = idx & 127;
    int b = bn >> 9, n = bn & 511;
    flat[(size_t)b * (LEVELS_ * PYOUT_ * N_) + (size_t)(level * PYOUT_ + c) * N_ + n] = P[idx];
}

// ---------------------------------------------------------------- fcl: add = flat @ fcl_W + fcl_b
// stage 1: 256 chunks of K=1280, partial[chunk][b][j]
__global__ __launch_bounds__(128) void fcl_partial_kernel(
    const float* __restrict__ flat, const float* __restrict__ W,
    float* __restrict__ partial) {
    int chunk = blockIdx.x;
    int j = threadIdx.x;
    int k0 = chunk * 1280;
    float acc[16];
#pragma unroll
    for (int b = 0; b < 16; b++) acc[b] = 0.f;
    for (int k = k0; k < k0 + 1280; k++) {
        float w = W[(size_t)k * 128 + j];
#pragma unroll
        for (int b = 0; b < 16; b++) acc[b] += flat[(size_t)b * 327680 + k] * w;
    }
#pragma unroll
    for (int b = 0; b < 16; b++)
        partial[((size_t)chunk * 16 + b) * 128 + j] = acc[b];
}

__global__ __launch_bounds__(256) void fcl_reduce_kernel(
    const float* __restrict__ partial, const float* __restrict__ fcl_b,
    float* __restrict__ add) {
    int idx = blockIdx.x * 256 + threadIdx.x;   // 2048
    int b = idx >> 7, j = idx & 127;
    float s = fcl_b[j];
    for (int c = 0; c < 256; c++) s += partial[((size_t)c * 16 + b) * 128 + j];
    add[idx] = s;
}

// ---------------------------------------------------------------- add BN (over B, per 128 channels)
__global__ __launch_bounds__(128) void addbn_kernel(
    const float* __restrict__ add, const float* __restrict__ g,
    const float* __restrict__ bb, float* __restrict__ a2) {
    int j = threadIdx.x;
    float m = 0.f;
#pragma unroll
    for (int b = 0; b < 16; b++) m += add[b * 128 + j];
    m *= (1.f / 16.f);
    float v = 0.f;
#pragma unroll
    for (int b = 0; b < 16; b++) { float d = add[b * 128 + j] - m; v += d * d; }
    v *= (1.f / 16.f);
    float sc = rsqrtf(v + 1e-5f) * g[j];
#pragma unroll
    for (int b = 0; b < 16; b++) a2[b * 128 + j] = (add[b * 128 + j] - m) * sc + bb[j];
}

// ---------------------------------------------------------------- tiny GEMM (heads)
template <int ACT>   // 0 none, 2 relu
__global__ void sgemm_kernel(const float* __restrict__ A, const float* __restrict__ W,
                             const float* __restrict__ bias, float* __restrict__ C,
                             int M, int K, int Nn) {
    int idx = blockIdx.x * blockDim.x + threadIdx.x;
    if (idx >= M * Nn) return;
    int m = idx / Nn, c = idx % Nn;
    float acc = bias[c];
    for (int k = 0; k < K; k++) acc += A[(size_t)m * K + k] * W[(size_t)k * Nn + c];
    if (ACT == 2) acc = fmaxf(acc, 0.f);
    C[idx] = acc;
}

// ---------------------------------------------------------------- finalize: softmax(cls,45) + concat box
__global__ __launch_bounds__(128) void finalize_kernel(
    const float* __restrict__ cls, const float* __restrict__ box,
    float* __restrict__ out) {
    int b = blockIdx.x;
    int t = threadIdx.x;
    __shared__ float sm[45];
    __shared__ float ssum;
    if (t < 45) sm[t] = cls[b * 45 + t];
    __syncthreads();
    if (t == 0) {
        float m = -1e30f;
        for (int i = 0; i < 45; i++) m = fmaxf(m, sm[i]);
        float s = 0.f;
        for (int i = 0; i < 45; i++) { sm[i] = expf(sm[i] - m); s += sm[i]; }
        ssum = s;
    }
    __syncthreads();
    if (t < 81) {
        int a = t / 9, c = t % 9;
        float v;
        if (c < 5) v = sm[a * 5 + c] / ssum;
        else       v = box[b * 36 + a * 4 + (c - 5)];
        out[b * 81 + t] = v;
    }
}

// ================================================================ launcher
extern "C" void kernel_launch(void* const* d_in, const int* in_sizes, int n_in,
                              void* d_out, int out_size, void* d_ws, size_t ws_size,
                              hipStream_t stream) {
    const float* x_in    = (const float*)d_in[0];
    const float* patch_W = (const float*)d_in[1];
    const float* patch_b = (const float*)d_in[2];
    const float* ln_g    = (const float*)d_in[3];
    const float* ln_b    = (const float*)d_in[4];
    const float* ff_W1   = (const float*)d_in[5];
    const float* ff_b1   = (const float*)d_in[6];
    const float* ff_W2   = (const float*)d_in[7];
    const float* ff_b2   = (const float*)d_in[8];
    const float* Wqkv    = (const float*)d_in[9];
    const float* bqkv    = (const float*)d_in[10];
    const float* Wo      = (const float*)d_in[11];
    const float* bo      = (const float*)d_in[12];
    const float* bn1_g   = (const float*)d_in[13];
    const float* bn1_b   = (const float*)d_in[14];
    const float* bn2_g   = (const float*)d_in[15];
    const float* bn2_b   = (const float*)d_in[16];
    const float* pyr_W   = (const float*)d_in[17];
    const float* pyr_b   = (const float*)d_in[18];
    const float* fcl_W   = (const float*)d_in[19];
    const float* fcl_b   = (const float*)d_in[20];
    const float* addbn_g = (const float*)d_in[21];
    const float* addbn_b = (const float*)d_in[22];
    const float* cls_W1  = (const float*)d_in[23];
    const float* cls_b1  = (const float*)d_in[24];
    const float* cls_W2  = (const float*)d_in[25];
    const float* cls_b2  = (const float*)d_in[26];
    const float* box_W1  = (const float*)d_in[27];
    const float* box_b1  = (const float*)d_in[28];
    const float* box_W2  = (const float*)d_in[29];
    const float* box_b2  = (const float*)d_in[30];
    float* out = (float*)d_out;

    float* ws = (float*)d_ws;
    size_t off = 0;
    float* POS  = ws + off; off += (size_t)N_ * D_;          // 131072
    float* X    = ws + off; off += (size_t)ROWS_ * D_;       // 2097152
    float* H    = ws + off; off += (size_t)ROWS_ * D_;
    float* T    = ws + off; off += (size_t)ROWS_ * D_;
    float* AT   = ws + off; off += (size_t)ROWS_ * D_;
    float* BIG  = ws + off; off += (size_t)ROWS_ * HIDEF_;   // 8388608 (mid / qkv)
    float* FLAT = ws + off; off += (size_t)B_ * LEVELS_ * PYOUT_ * N_;  // 5242880
    float* STATS= ws + off; off += 2 * D_;
    float* PART = ws + off; off += (size_t)256 * 16 * 128;
    float* ADD  = ws + off; off += 2048;
    float* A2   = ws + off; off += 2048;
    float* CM   = ws + off; off += 16 * 256;
    float* CLS  = ws + off; off += 16 * 45;
    float* BMID = ws + off; off += 16 * 128;
    float* BOX  = ws + off; off += 16 * 36;

    pos_kernel<<<(N_ * D_ + 255) / 256, 256, 0, stream>>>(POS);

    for (int it = 0; it < 5; it++) {
        const float* xin = (it == 0) ? x_in : X;
        // patch embed
        gemm_kernel<0><<<dim3(D_ / 64, ROWS_ / 64), 256, 0, stream>>>(
            xin, patch_W, patch_b, nullptr, T, ROWS_, D_, D_);
        // LN + pos
        ln_pos_kernel<<<ROWS_, 256, 0, stream>>>(T, ln_g, ln_b, POS, H);
        // FF #1
        gemm_kernel<1><<<dim3(HIDEF_ / 64, ROWS_ / 64), 256, 0, stream>>>(
            H, ff_W1, ff_b1, nullptr, BIG, ROWS_, D_, HIDEF_);
        gemm_kernel<0><<<dim3(D_ / 64, ROWS_ / 64), 256, 0, stream>>>(
            BIG, ff_W2, ff_b2, nullptr, T, ROWS_, HIDEF_, D_);
        // qkv
        gemm_kernel<0><<<dim3(768 / 64, ROWS_ / 64), 256, 0, stream>>>(
            T, Wqkv, bqkv, nullptr, BIG, ROWS_, D_, 768);
        // attention
        attn_kernel<<<dim3(NBLK_, HEADS_, B_), 256, 0, stream>>>(BIG, AT);
        // out proj + residual (idt = H)
        gemm_kernel<0><<<dim3(D_ / 64, ROWS_ / 64), 256, 0, stream>>>(
            AT, Wo, bo, H, T, ROWS_, D_, D_);
        // BN1 -> H (new idt)
        bn_stats_kernel<<<D_, 256, 0, stream>>>(T, STATS);
        bn_apply_kernel<<<ROWS_, 256, 0, stream>>>(T, STATS, bn1_g, bn1_b, H);
        // FF #2 + residual
        gemm_kernel<1><<<dim3(HIDEF_ / 64, ROWS_ / 64), 256, 0, stream>>>(
            H, ff_W1, ff_b1, nullptr, BIG, ROWS_, D_, HIDEF_);
        gemm_kernel<0><<<dim3(D_ / 64, ROWS_ / 64), 256, 0, stream>>>(
            BIG, ff_W2, ff_b2, H, T, ROWS_, HIDEF_, D_);
        // BN2 -> X (next iter input)
        bn_stats_kernel<<<D_, 256, 0, stream>>>(T, STATS);
        bn_apply_kernel<<<ROWS_, 256, 0, stream>>>(T, STATS, bn2_g, bn2_b, X);
        // pyramid level it: P = X @ pyr_W[it] + pyr_b[it]  (reuse AT)
        gemm_kernel<0><<<dim3(PYOUT_ / 64, ROWS_ / 64), 256, 0, stream>>>(
            X, pyr_W + (size_t)it * D_ * PYOUT_, pyr_b + it * PYOUT_, nullptr,
            AT, ROWS_, D_, PYOUT_);
        pyr_scatter_kernel<<<(ROWS_ * PYOUT_) / 256, 256, 0, stream>>>(AT, FLAT, it);
    }

    // fcl
    fcl_partial_kernel<<<256, 128, 0, stream>>>(FLAT, fcl_W, PART);
    fcl_reduce_kernel<<<8, 256, 0, stream>>>(PART, fcl_b, ADD);
    // add BN
    addbn_kernel<<<1, 128, 0, stream>>>(ADD, addbn_g, addbn_b, A2);
    // heads
    sgemm_kernel<2><<<(16 * 256 + 255) / 256, 256, 0, stream>>>(A2, cls_W1, cls_b1, CM, 16, 128, 256);
    sgemm_kernel<0><<<(16 * 45 + 255) / 256, 256, 0, stream>>>(CM, cls_W2, cls_b2, CLS, 16, 256, 45);
    sgemm_kernel<2><<<(16 * 128 + 255) / 256, 256, 0, stream>>>(A2, box_W1, box_b1, BMID, 16, 128, 128);
    sgemm_kernel<0><<<(16 * 36 + 255) / 256, 256, 0, stream>>>(BMID, box_W2, box_b2, BOX, 16, 128, 36);
    finalize_kernel<<<B_, 128, 0, stream>>>(CLS, BOX, out);
    (void)in_sizes; (void)n_in; (void)out_size; (void)ws_size;
}

// Round 2
// 2074.149 us; speedup vs baseline: 2.2374x; 2.2374x over previous
//
#include <hip/hip_runtime.h>
#include <hip/hip_bf16.h>
#include <math.h>

#define B_ 16
#define N_ 512
#define D_ 256
#define HEADS_ 8
#define DH_ 32
#define DHP_ 36
#define HIDEF_ 1024
#define NBLK_ 16
#define BS_ 32
#define BAND_ 160
#define LEVELS_ 5
#define PYOUT_ 128
#define ROWS_ (B_ * N_)   // 8192
#define FCL_K 327680
#define FCL_CHUNKS 1280

typedef __attribute__((ext_vector_type(8))) short short8;
typedef __attribute__((ext_vector_type(4))) float f32x4;

// ---------------------------------------------------------------- position
__global__ void pos_kernel(float* __restrict__ pos) {
    int idx = blockIdx.x * 256 + threadIdx.x;
    if (idx >= N_ * D_) return;
    int n = idx >> 8, i = idx & 255;
    double angle = (double)n / pow(10000.0, (double)(2 * (i >> 1)) / 256.0);
    pos[idx] = (float)((i & 1) ? cos(angle) : sin(angle));
}

__device__ __forceinline__ float gelu_f(float x) {
    float x3 = x * x * x;
    return 0.5f * x * (1.f + tanhf(0.7978845608028654f * (x + 0.044715f * x3)));
}

// ---------------------------------------------------------------- converts
__global__ void tobf16_kernel(const float* __restrict__ x, __hip_bfloat16* __restrict__ y, int n) {
    int i = blockIdx.x * 256 + threadIdx.x;
    if (i < n) y[i] = __float2bfloat16(x[i]);
}

// W [K,N] (z-batched) -> Wt [N,K] bf16
__global__ __launch_bounds__(256) void wconv_kernel(const float* __restrict__ W,
                                                    __hip_bfloat16* __restrict__ Wt,
                                                    int K, int N) {
    int z = blockIdx.z;
    const float* Wz = W + (size_t)z * K * N;
    __hip_bfloat16* Wtz = Wt + (size_t)z * K * N;
    __shared__ float t[32][33];
    int bx = blockIdx.x * 32, by = blockIdx.y * 32;
    int tx = threadIdx.x, ty = threadIdx.y;
#pragma unroll
    for (int i = 0; i < 32; i += 8)
        t[ty + i][tx] = Wz[(size_t)(by + ty + i) * N + bx + tx];
    __syncthreads();
#pragma unroll
    for (int i = 0; i < 32; i += 8)
        Wtz[(size_t)(bx + ty + i) * K + by + tx] = __float2bfloat16(t[tx][ty + i]);
}

// ---------------------------------------------------------------- bf16 MFMA GEMM
// C[M,Nn] = act(A[M,K]bf16 @ Wt[Nn,K]bf16^T + bias) (+resid fp32)
// 128x128 tile, BK=32, 4 waves (2x2 of 64x64), global_load_lds w16, XOR swizzle
template <int ACT, bool OUTF, bool OUTB>
__global__ __launch_bounds__(256) void bgemm_kernel(
    const __hip_bfloat16* __restrict__ A, const __hip_bfloat16* __restrict__ Wt,
    const float* __restrict__ bias, const float* __restrict__ resid,
    float* __restrict__ C, __hip_bfloat16* __restrict__ Cb, int M, int Nn, int K) {
    __shared__ __hip_bfloat16 Alds[128 * 32];
    __shared__ __hip_bfloat16 Blds[128 * 32];
    int tid = threadIdx.x;
    int wid = tid >> 6, lane = tid & 63;
    int row0 = blockIdx.y * 128, col0 = blockIdx.x * 128;
    int wr = wid >> 1, wc = wid & 1;
    int r16 = lane & 15, kq = lane >> 4;
    int swz = (r16 >> 1) & 3;                 // (row>>1)&3, row = mult8 + r16
    int rdoff = kq ^ swz;                     // chunk to read

    f32x4 acc[4][4];
#pragma unroll
    for (int m = 0; m < 4; m++)
#pragma unroll
        for (int n = 0; n < 4; n++) acc[m][n] = (f32x4){0.f, 0.f, 0.f, 0.f};

    for (int k0 = 0; k0 < K; k0 += 32) {
#pragma unroll
        for (int i = 0; i < 2; i++) {
            int slot = i * 256 + tid;
            int row = slot >> 2, qp = slot & 3;
            int q = qp ^ ((row >> 1) & 3);
            const __hip_bfloat16* ga = A + (size_t)(row0 + row) * K + k0 + q * 8;
            const __hip_bfloat16* gb = Wt + (size_t)(col0 + row) * K + k0 + q * 8;
            __builtin_amdgcn_global_load_lds(
                (const __attribute__((address_space(1))) void*)ga,
                (__attribute__((address_space(3))) void*)((char*)Alds + i * 4096 + wid * 1024),
                16, 0, 0);
            __builtin_amdgcn_global_load_lds(
                (const __attribute__((address_space(1))) void*)gb,
                (__attribute__((address_space(3))) void*)((char*)Blds + i * 4096 + wid * 1024),
                16, 0, 0);
        }
        __syncthreads();
        short8 af[4], bf[4];
#pragma unroll
        for (int m = 0; m < 4; m++) {
            int row = wr * 64 + m * 16 + r16;
            af[m] = *reinterpret_cast<const short8*>(
                reinterpret_cast<const char*>(Alds) + row * 64 + rdoff * 16);
        }
#pragma unroll
        for (int n = 0; n < 4; n++) {
            int row = wc * 64 + n * 16 + r16;
            bf[n] = *reinterpret_cast<const short8*>(
                reinterpret_cast<const char*>(Blds) + row * 64 + rdoff * 16);
        }
#pragma unroll
        for (int m = 0; m < 4; m++)
#pragma unroll
            for (int n = 0; n < 4; n++)
                acc[m][n] = __builtin_amdgcn_mfma_f32_16x16x32_bf16(af[m], bf[n], acc[m][n], 0, 0, 0);
        __syncthreads();
    }

    int rg = lane >> 4;
#pragma unroll
    for (int n = 0; n < 4; n++) {
        int cc = col0 + wc * 64 + n * 16 + r16;
        float bv = bias[cc];
#pragma unroll
        for (int m = 0; m < 4; m++) {
            int rb = row0 + wr * 64 + m * 16 + rg * 4;
#pragma unroll
            for (int j = 0; j < 4; j++) {
                int r = rb + j;
                float v = acc[m][n][j] + bv;
                if (resid) v += resid[(size_t)r * Nn + cc];
                if (ACT == 1) v = gelu_f(v);
                if (OUTF) C[(size_t)r * Nn + cc] = v;
                if (OUTB) Cb[(size_t)r * Nn + cc] = __float2bfloat16(v);
            }
        }
    }
}

// ---------------------------------------------------------------- LN + pos (fp32 + bf16 out)
__global__ __launch_bounds__(256) void ln_pos_kernel(
    const float* __restrict__ t, const float* __restrict__ g,
    const float* __restrict__ b, const float* __restrict__ pos,
    float* __restrict__ h, __hip_bfloat16* __restrict__ hb) {
    int row = blockIdx.x;
    int n = row & (N_ - 1);
    int d = threadIdx.x;
    float v = t[(size_t)row * D_ + d];
    __shared__ float red[256];
    red[d] = v; __syncthreads();
    for (int s = 128; s > 0; s >>= 1) { if (d < s) red[d] += red[d + s]; __syncthreads(); }
    float mean = red[0] / 256.f;
    __syncthreads();
    float dv = v - mean;
    red[d] = dv * dv; __syncthreads();
    for (int s = 128; s > 0; s >>= 1) { if (d < s) red[d] += red[d + s]; __syncthreads(); }
    float var = red[0] / 256.f;
    float o = dv * rsqrtf(var + 1e-5f) * g[d] + b[d] + pos[n * D_ + d];
    h[(size_t)row * D_ + d] = o;
    hb[(size_t)row * D_ + d] = __float2bfloat16(o);
}

// ---------------------------------------------------------------- BN (two-stage coalesced)
__global__ __launch_bounds__(256) void bn_part_kernel(
    const float* __restrict__ x, float* __restrict__ part) {
    int g = blockIdx.x;                 // 256 blocks, 32 rows each
    int t = threadIdx.x;
    int c4 = t & 63, rs = t >> 6;       // float4 col, row-subgroup
    const float4* xr = (const float4*)(x + (size_t)g * 32 * D_);
    float s[4] = {0.f, 0.f, 0.f, 0.f}, s2[4] = {0.f, 0.f, 0.f, 0.f};
    for (int r = rs; r < 32; r += 4) {
        float4 v = xr[r * 64 + c4];
        s[0] += v.x; s2[0] += v.x * v.x;
        s[1] += v.y; s2[1] += v.y * v.y;
        s[2] += v.z; s2[2] += v.z * v.z;
        s[3] += v.w; s2[3] += v.w * v.w;
    }
    __shared__ float ls[256][8];
#pragma unroll
    for (int i = 0; i < 4; i++) { ls[t][i] = s[i]; ls[t][4 + i] = s2[i]; }
    __syncthreads();
    if (rs == 0) {
#pragma unroll
        for (int i = 0; i < 4; i++) {
            float ss = 0.f, ss2 = 0.f;
#pragma unroll
            for (int q = 0; q < 4; q++) {
                ss += ls[q * 64 + c4][i];
                ss2 += ls[q * 64 + c4][4 + i];
            }
            int c = c4 * 4 + i;
            part[(size_t)g * 512 + c] = ss;
            part[(size_t)g * 512 + 256 + c] = ss2;
        }
    }
}

__global__ __launch_bounds__(256) void bn_finish_kernel(
    const float* __restrict__ part, float* __restrict__ stats) {
    int c = threadIdx.x;
    float s = 0.f, s2 = 0.f;
    for (int g = 0; g < 256; g++) {
        s += part[(size_t)g * 512 + c];
        s2 += part[(size_t)g * 512 + 256 + c];
    }
    float m = s * (1.f / 8192.f);
    stats[c] = m;
    stats[D_ + c] = s2 * (1.f / 8192.f) - m * m;
}

__global__ __launch_bounds__(256) void bn_apply_kernel(
    const float* __restrict__ x, const float* __restrict__ stats,
    const float* __restrict__ g, const float* __restrict__ b,
    float* __restrict__ y, __hip_bfloat16* __restrict__ yb) {
    int row = blockIdx.x;
    int c = threadIdx.x;
    float m = stats[c], var = stats[D_ + c];
    float v = (x[(size_t)row * D_ + c] - m) * rsqrtf(var + 1e-5f) * g[c] + b[c];
    if (y) y[(size_t)row * D_ + c] = v;
    if (yb) yb[(size_t)row * D_ + c] = __float2bfloat16(v);
}

// ---------------------------------------------------------------- attention
__global__ __launch_bounds__(256) void attn_kernel(
    const float* __restrict__ qkv, __hip_bfloat16* __restrict__ outb) {
    int i = blockIdx.x, h = blockIdx.y, b = blockIdx.z;
    int tid = threadIdx.x;
    __shared__ float qs[BS_][DHP_];
    __shared__ float ks[BAND_][DHP_];
    __shared__ float ss[BS_][BAND_ + 1];
    __shared__ float red[BS_][8];
    __shared__ float rowsum[BS_], rowmax[BS_];

    for (int e = tid; e < BS_ * DH_; e += 256) {
        int r = e >> 5, d = e & 31;
        qs[r][d] = qkv[((size_t)(b * N_ + i * BS_ + r)) * 768 + h * DH_ + d];
    }
    for (int e = tid; e < BAND_ * DH_; e += 256) {
        int c = e >> 5, d = e & 31;
        int jb = i - 2 + (c >> 5);
        ks[c][d] = (jb >= 0 && jb < NBLK_)
            ? qkv[((size_t)(b * N_ + jb * BS_ + (c & 31))) * 768 + 256 + h * DH_ + d] : 0.f;
    }
    __syncthreads();

    int r = tid >> 3, lane = tid & 7;
    float4 qreg[8];
#pragma unroll
    for (int d4 = 0; d4 < 8; d4++) qreg[d4] = *(const float4*)&qs[r][d4 * 4];

    const float scale = 0.17677669529663687f;
    for (int c = lane; c < BAND_; c += 8) {
        int jb = i - 2 + (c >> 5);
        float s_;
        if (jb >= 0 && jb < NBLK_) {
            float a = 0.f;
#pragma unroll
            for (int d4 = 0; d4 < 8; d4++) {
                float4 kv = *(const float4*)&ks[c][d4 * 4];
                float4 qv = qreg[d4];
                a += qv.x * kv.x + qv.y * kv.y + qv.z * kv.z + qv.w * kv.w;
            }
            s_ = a * scale;
        } else s_ = -1e9f;
        ss[r][c] = s_;
    }
    __syncthreads();

    float mx = -1e30f;
    for (int c = lane; c < BAND_; c += 8) mx = fmaxf(mx, ss[r][c]);
    red[r][lane] = mx; __syncthreads();
    if (lane == 0) {
        float m = red[r][0];
#pragma unroll
        for (int t = 1; t < 8; t++) m = fmaxf(m, red[r][t]);
        rowmax[r] = m;
    }
    __syncthreads();
    float m = rowmax[r];
    float sum = 0.f;
    for (int c = lane; c < BAND_; c += 8) {
        float e_ = __expf(ss[r][c] - m);
        ss[r][c] = e_;
        sum += e_;
    }
    red[r][lane] = sum; __syncthreads();
    if (lane == 0) {
        float s_ = 0.f;
#pragma unroll
        for (int t = 0; t < 8; t++) s_ += red[r][t];
        rowsum[r] = s_;
    }
    __syncthreads();

    // reload band with V
    for (int e = tid; e < BAND_ * DH_; e += 256) {
        int c = e >> 5, d = e & 31;
        int jb = i - 2 + (c >> 5);
        ks[c][d] = (jb >= 0 && jb < NBLK_)
            ? qkv[((size_t)(b * N_ + jb * BS_ + (c & 31))) * 768 + 512 + h * DH_ + d] : 0.f;
    }
    __syncthreads();

    // PV: thread (r, d-quad = lane)
    float4 o = {0.f, 0.f, 0.f, 0.f};
    for (int c = 0; c < BAND_; c++) {
        float p = ss[r][c];
        float4 v4 = *(const float4*)&ks[c][lane * 4];
        o.x += p * v4.x; o.y += p * v4.y; o.z += p * v4.z; o.w += p * v4.w;
    }
    float inv = 1.f / rowsum[r];
    size_t ob = ((size_t)(b * N_ + i * BS_ + r)) * D_ + h * DH_ + lane * 4;
    outb[ob + 0] = __float2bfloat16(o.x * inv);
    outb[ob + 1] = __float2bfloat16(o.y * inv);
    outb[ob + 2] = __float2bfloat16(o.z * inv);
    outb[ob + 3] = __float2bfloat16(o.w * inv);
}

// ---------------------------------------------------------------- pyramid scatter
__global__ __launch_bounds__(256) void pyr_scatter_kernel(
    const float* __restrict__ P, float* __restrict__ flat, int level) {
    int idx = blockIdx.x * 256 + threadIdx.x;
    int bn = idx >> 7, c = idx & 127;
    int b = bn >> 9, n = bn & 511;
    flat[(size_t)b * (LEVELS_ * PYOUT_ * N_) + (size_t)(level * PYOUT_ + c) * N_ + n] = P[idx];
}

// ---------------------------------------------------------------- fcl
__global__ __launch_bounds__(128) void fcl_partial_kernel(
    const float* __restrict__ flat, const float* __restrict__ W,
    float* __restrict__ partial) {
    int chunk = blockIdx.x;   // 0..1279
    int j = threadIdx.x;
    int k0 = chunk * 256;
    float acc[16];
#pragma unroll
    for (int b = 0; b < 16; b++) acc[b] = 0.f;
#pragma unroll 4
    for (int kk = 0; kk < 256; kk++) {
        int k = k0 + kk;
        float w = W[(size_t)k * 128 + j];
#pragma unroll
        for (int b = 0; b < 16; b++) acc[b] += flat[(size_t)b * FCL_K + k] * w;
    }
#pragma unroll
    for (int b = 0; b < 16; b++)
        partial[(size_t)chunk * 2048 + b * 128 + j] = acc[b];
}

__global__ __launch_bounds__(256) void fcl_reduce_kernel(
    const float* __restrict__ partial, const float* __restrict__ fcl_b,
    float* __restrict__ add) {
    int c0 = blockIdx.x * 32;   // 64 blocks
    int t = threadIdx.x;
    int ry = t >> 5, cx = t & 31;
    float s = 0.f;
    for (int r = ry; r < FCL_CHUNKS; r += 8)
        s += partial[(size_t)r * 2048 + c0 + cx];
    __shared__ float red[8][32];
    red[ry][cx] = s; __syncthreads();
    if (ry == 0) {
        float tot = 0.f;
#pragma unroll
        for (int q = 0; q < 8; q++) tot += red[q][cx];
        int col = c0 + cx;
        add[col] = tot + fcl_b[col & 127];
    }
}

// ---------------------------------------------------------------- addBN + heads + finalize
__global__ __launch_bounds__(128) void addbn_kernel(
    const float* __restrict__ add, const float* __restrict__ g,
    const float* __restrict__ bb, float* __restrict__ a2) {
    int j = threadIdx.x;
    float m = 0.f;
#pragma unroll
    for (int b = 0; b < 16; b++) m += add[b * 128 + j];
    m *= (1.f / 16.f);
    float v = 0.f;
#pragma unroll
    for (int b = 0; b < 16; b++) { float d = add[b * 128 + j] - m; v += d * d; }
    v *= (1.f / 16.f);
    float sc = rsqrtf(v + 1e-5f) * g[j];
#pragma unroll
    for (int b = 0; b < 16; b++) a2[b * 128 + j] = (add[b * 128 + j] - m) * sc + bb[j];
}

template <int ACT>
__global__ void sgemm_kernel(const float* __restrict__ A, const float* __restrict__ W,
                             const float* __restrict__ bias, float* __restrict__ C,
                             int M, int K, int Nn) {
    int idx = blockIdx.x * blockDim.x + threadIdx.x;
    if (idx >= M * Nn) return;
    int m = idx / Nn, c = idx % Nn;
    float acc = bias[c];
    for (int k = 0; k < K; k++) acc += A[(size_t)m * K + k] * W[(size_t)k * Nn + c];
    if (ACT == 2) acc = fmaxf(acc, 0.f);
    C[idx] = acc;
}

__global__ __launch_bounds__(128) void finalize_kernel(
    const float* __restrict__ cls, const float* __restrict__ box,
    float* __restrict__ out) {
    int b = blockIdx.x;
    int t = threadIdx.x;
    __shared__ float sm[45];
    __shared__ float ssum;
    if (t < 45) sm[t] = cls[b * 45 + t];
    __syncthreads();
    if (t == 0) {
        float m = -1e30f;
        for (int i = 0; i < 45; i++) m = fmaxf(m, sm[i]);
        float s = 0.f;
        for (int i = 0; i < 45; i++) { sm[i] = expf(sm[i] - m); s += sm[i]; }
        ssum = s;
    }
    __syncthreads();
    if (t < 81) {
        int a = t / 9, c = t % 9;
        float v;
        if (c < 5) v = sm[a * 5 + c] / ssum;
        else       v = box[b * 36 + a * 4 + (c - 5)];
        out[b * 81 + t] = v;
    }
}

// ================================================================ launcher
extern "C" void kernel_launch(void* const* d_in, const int* in_sizes, int n_in,
                              void* d_out, int out_size, void* d_ws, size_t ws_size,
                              hipStream_t stream) {
    const float* x_in    = (const float*)d_in[0];
    const float* patch_W = (const float*)d_in[1];
    const float* patch_b = (const float*)d_in[2];
    const float* ln_g    = (const float*)d_in[3];
    const float* ln_b    = (const float*)d_in[4];
    const float* ff_W1   = (const float*)d_in[5];
    const float* ff_b1   = (const float*)d_in[6];
    const float* ff_W2   = (const float*)d_in[7];
    const float* ff_b2   = (const float*)d_in[8];
    const float* Wqkv    = (const float*)d_in[9];
    const float* bqkv    = (const float*)d_in[10];
    const float* Wo      = (const float*)d_in[11];
    const float* bo      = (const float*)d_in[12];
    const float* bn1_g   = (const float*)d_in[13];
    const float* bn1_b   = (const float*)d_in[14];
    const float* bn2_g   = (const float*)d_in[15];
    const float* bn2_b   = (const float*)d_in[16];
    const float* pyr_W   = (const float*)d_in[17];
    const float* pyr_b   = (const float*)d_in[18];
    const float* fcl_W   = (const float*)d_in[19];
    const float* fcl_b   = (const float*)d_in[20];
    const float* addbn_g = (const float*)d_in[21];
    const float* addbn_b = (const float*)d_in[22];
    const float* cls_W1  = (const float*)d_in[23];
    const float* cls_b1  = (const float*)d_in[24];
    const float* cls_W2  = (const float*)d_in[25];
    const float* cls_b2  = (const float*)d_in[26];
    const float* box_W1  = (const float*)d_in[27];
    const float* box_b1  = (const float*)d_in[28];
    const float* box_W2  = (const float*)d_in[29];
    const float* box_b2  = (const float*)d_in[30];
    float* out = (float*)d_out;

    float* ws = (float*)d_ws;
    size_t off = 0;
    float* POS   = ws + off; off += 131072;
    float* H     = ws + off; off += 2097152;
    float* T     = ws + off; off += 2097152;
    float* ATf   = ws + off; off += 1048576;              // [8192,128] pyr out
    float* UNION = ws + off; off += 6291456;              // qkv fp32 / FF-mid bf16
    float* FLAT  = ws + off; off += 5242880;
    float* PART  = ws + off; off += (size_t)FCL_CHUNKS * 2048;
    float* STATS = ws + off; off += 512;
    float* BNP   = ws + off; off += 131072;
    float* ADD   = ws + off; off += 2048;
    float* A2    = ws + off; off += 2048;
    float* CM    = ws + off; off += 4096;
    float* CLS   = ws + off; off += 720;
    float* BMID  = ws + off; off += 2048;
    float* BOX   = ws + off; off += 576;
    __hip_bfloat16* Hb   = (__hip_bfloat16*)(ws + off); off += 1048576;
    __hip_bfloat16* Tb   = (__hip_bfloat16*)(ws + off); off += 1048576;
    __hip_bfloat16* Xb   = (__hip_bfloat16*)(ws + off); off += 1048576;
    __hip_bfloat16* ATb  = (__hip_bfloat16*)(ws + off); off += 1048576;
    __hip_bfloat16* patchWt = (__hip_bfloat16*)(ws + off); off += 32768;
    __hip_bfloat16* qkvWt   = (__hip_bfloat16*)(ws + off); off += 98304;
    __hip_bfloat16* WoWt    = (__hip_bfloat16*)(ws + off); off += 32768;
    __hip_bfloat16* W1t     = (__hip_bfloat16*)(ws + off); off += 131072;
    __hip_bfloat16* W2t     = (__hip_bfloat16*)(ws + off); off += 131072;
    __hip_bfloat16* pyrWt   = (__hip_bfloat16*)(ws + off); off += 81920;
    __hip_bfloat16* MIDb = (__hip_bfloat16*)UNION;
    float* QKV = UNION;

    pos_kernel<<<(N_ * D_ + 255) / 256, 256, 0, stream>>>(POS);
    // weight prep
    wconv_kernel<<<dim3(D_ / 32, D_ / 32, 1), dim3(32, 8), 0, stream>>>(patch_W, patchWt, D_, D_);
    wconv_kernel<<<dim3(768 / 32, D_ / 32, 1), dim3(32, 8), 0, stream>>>(Wqkv, qkvWt, D_, 768);
    wconv_kernel<<<dim3(D_ / 32, D_ / 32, 1), dim3(32, 8), 0, stream>>>(Wo, WoWt, D_, D_);
    wconv_kernel<<<dim3(HIDEF_ / 32, D_ / 32, 1), dim3(32, 8), 0, stream>>>(ff_W1, W1t, D_, HIDEF_);
    wconv_kernel<<<dim3(D_ / 32, HIDEF_ / 32, 1), dim3(32, 8), 0, stream>>>(ff_W2, W2t, HIDEF_, D_);
    wconv_kernel<<<dim3(PYOUT_ / 32, D_ / 32, LEVELS_), dim3(32, 8), 0, stream>>>(pyr_W, pyrWt, D_, PYOUT_);
    tobf16_kernel<<<(ROWS_ * D_ + 255) / 256, 256, 0, stream>>>(x_in, Xb, ROWS_ * D_);

    for (int it = 0; it < 5; it++) {
        // patch embed: T = Xb @ patch_W + b
        bgemm_kernel<0, true, false><<<dim3(2, 64), 256, 0, stream>>>(
            Xb, patchWt, patch_b, nullptr, T, nullptr, ROWS_, D_, D_);
        ln_pos_kernel<<<ROWS_, 256, 0, stream>>>(T, ln_g, ln_b, POS, H, Hb);
        // FF1: MIDb = gelu(Hb @ W1 + b1)
        bgemm_kernel<1, false, true><<<dim3(8, 64), 256, 0, stream>>>(
            Hb, W1t, ff_b1, nullptr, nullptr, MIDb, ROWS_, HIDEF_, D_);
        // FF2: Tb = MIDb @ W2 + b2
        bgemm_kernel<0, false, true><<<dim3(2, 64), 256, 0, stream>>>(
            MIDb, W2t, ff_b2, nullptr, nullptr, Tb, ROWS_, D_, HIDEF_);
        // qkv: QKV = Tb @ Wqkv + bqkv
        bgemm_kernel<0, true, false><<<dim3(6, 64), 256, 0, stream>>>(
            Tb, qkvWt, bqkv, nullptr, QKV, nullptr, ROWS_, 768, D_);
        attn_kernel<<<dim3(NBLK_, HEADS_, B_), 256, 0, stream>>>(QKV, ATb);
        // proj + resid(H): T
        bgemm_kernel<0, true, false><<<dim3(2, 64), 256, 0, stream>>>(
            ATb, WoWt, bo, H, T, nullptr, ROWS_, D_, D_);
        // BN1 -> H(f32) + Hb
        bn_part_kernel<<<256, 256, 0, stream>>>(T, BNP);
        bn_finish_kernel<<<1, 256, 0, stream>>>(BNP, STATS);
        bn_apply_kernel<<<ROWS_, 256, 0, stream>>>(T, STATS, bn1_g, bn1_b, H, Hb);
        // FF1b / FF2b (+resid H)
        bgemm_kernel<1, false, true><<<dim3(8, 64), 256, 0, stream>>>(
            Hb, W1t, ff_b1, nullptr, nullptr, MIDb, ROWS_, HIDEF_, D_);
        bgemm_kernel<0, true, false><<<dim3(2, 64), 256, 0, stream>>>(
            MIDb, W2t, ff_b2, H, T, nullptr, ROWS_, D_, HIDEF_);
        // BN2 -> Xb only
        bn_part_kernel<<<256, 256, 0, stream>>>(T, BNP);
        bn_finish_kernel<<<1, 256, 0, stream>>>(BNP, STATS);
        bn_apply_kernel<<<ROWS_, 256, 0, stream>>>(T, STATS, bn2_g, bn2_b, nullptr, Xb);
        // pyramid level
        bgemm_kernel<0, true, false><<<dim3(1, 64), 256, 0, stream>>>(
            Xb, pyrWt + (size_t)it * D_ * PYOUT_, pyr_b + it * PYOUT_, nullptr,
            ATf, nullptr, ROWS_, PYOUT_, D_);
        pyr_scatter_kernel<<<(ROWS_ * PYOUT_) / 256, 256, 0, stream>>>(ATf, FLAT, it);
    }

    fcl_partial_kernel<<<FCL_CHUNKS, 128, 0, stream>>>(FLAT, fcl_W, PART);
    fcl_reduce_kernel<<<64, 256, 0, stream>>>(PART, fcl_b, ADD);
    addbn_kernel<<<1, 128, 0, stream>>>(ADD, addbn_g, addbn_b, A2);
    sgemm_kernel<2><<<(16 * 256 + 255) / 256, 256, 0, stream>>>(A2, cls_W1, cls_b1, CM, 16, 128, 256);
    sgemm_kernel<0><<<(16 * 45 + 255) / 256, 256, 0, stream>>>(CM, cls_W2, cls_b2, CLS, 16, 256, 45);
    sgemm_kernel<2><<<(16 * 128 + 255) / 256, 256, 0, stream>>>(A2, box_W1, box_b1, BMID, 16, 128, 128);
    sgemm_kernel<0><<<(16 * 36 + 255) / 256, 256, 0, stream>>>(BMID, box_W2, box_b2, BOX, 16, 128, 36);
    finalize_kernel<<<B_, 128, 0, stream>>>(CLS, BOX, out);
    (void)in_sizes; (void)n_in; (void)out_size; (void)ws_size;
}

// Round 4
// 1413.155 us; speedup vs baseline: 3.2839x; 1.4677x over previous
//
#include <hip/hip_runtime.h>
#include <hip/hip_bf16.h>
#include <math.h>

#define B_ 16
#define N_ 512
#define D_ 256
#define HEADS_ 8
#define DH_ 32
#define HIDEF_ 1024
#define NBLK_ 16
#define BS_ 32
#define BAND_ 160
#define LEVELS_ 5
#define PYOUT_ 128
#define ROWS_ (B_ * N_)   // 8192
#define FCL_K 327680
#define FCL_KB 256
#define FCL_CHUNKS 1280   // FCL_K / FCL_KB

typedef __attribute__((ext_vector_type(8))) short short8;
typedef __attribute__((ext_vector_type(4))) short short4v;
typedef __attribute__((ext_vector_type(4))) unsigned short ushort4v;
typedef __attribute__((ext_vector_type(4))) float f32x4;

__device__ __forceinline__ float bf2f(short u) {
    return __uint_as_float(((unsigned int)(unsigned short)u) << 16);
}
__device__ __forceinline__ unsigned short f2bf(float x) {
    __hip_bfloat16 h = __float2bfloat16(x);
    return *reinterpret_cast<unsigned short*>(&h);
}

// ---------------------------------------------------------------- position
__global__ void pos_kernel(float* __restrict__ pos) {
    int idx = blockIdx.x * 256 + threadIdx.x;
    if (idx >= N_ * D_) return;
    int n = idx >> 8, i = idx & 255;
    double angle = (double)n / pow(10000.0, (double)(2 * (i >> 1)) / 256.0);
    pos[idx] = (float)((i & 1) ? cos(angle) : sin(angle));
}

__device__ __forceinline__ float gelu_f(float x) {
    float x3 = x * x * x;
    return 0.5f * x * (1.f + tanhf(0.7978845608028654f * (x + 0.044715f * x3)));
}

// ---------------------------------------------------------------- converts
__global__ void tobf16_kernel(const float* __restrict__ x, __hip_bfloat16* __restrict__ y, int n) {
    int i = blockIdx.x * 256 + threadIdx.x;
    if (i < n) y[i] = __float2bfloat16(x[i]);
}

// W [K,N] (z-batched) -> Wt [N,K] bf16
__global__ __launch_bounds__(256) void wconv_kernel(const float* __restrict__ W,
                                                    __hip_bfloat16* __restrict__ Wt,
                                                    int K, int N) {
    int z = blockIdx.z;
    const float* Wz = W + (size_t)z * K * N;
    __hip_bfloat16* Wtz = Wt + (size_t)z * K * N;
    __shared__ float t[32][33];
    int bx = blockIdx.x * 32, by = blockIdx.y * 32;
    int tx = threadIdx.x, ty = threadIdx.y;
#pragma unroll
    for (int i = 0; i < 32; i += 8)
        t[ty + i][tx] = Wz[(size_t)(by + ty + i) * N + bx + tx];
    __syncthreads();
#pragma unroll
    for (int i = 0; i < 32; i += 8)
        Wtz[(size_t)(bx + ty + i) * K + by + tx] = __float2bfloat16(t[tx][ty + i]);
}

// ---------------------------------------------------------------- bf16 MFMA GEMM
// 128x128 tile, BK=32, 4 waves (2x2 of 64x64), global_load_lds w16, XOR swizzle
template <int ACT, bool OUTF, bool OUTB, bool SCAT>
__global__ __launch_bounds__(256) void bgemm_kernel(
    const __hip_bfloat16* __restrict__ A, const __hip_bfloat16* __restrict__ Wt,
    const float* __restrict__ bias, const float* __restrict__ resid,
    float* __restrict__ C, __hip_bfloat16* __restrict__ Cb, int M, int Nn, int K,
    int level) {
    __shared__ __hip_bfloat16 Alds[128 * 32];
    __shared__ __hip_bfloat16 Blds[128 * 32];
    int tid = threadIdx.x;
    int wid = tid >> 6, lane = tid & 63;
    int row0 = blockIdx.y * 128, col0 = blockIdx.x * 128;
    int wr = wid >> 1, wc = wid & 1;
    int r16 = lane & 15, kq = lane >> 4;
    int swz = (r16 >> 1) & 3;
    int rdoff = kq ^ swz;

    f32x4 acc[4][4];
#pragma unroll
    for (int m = 0; m < 4; m++)
#pragma unroll
        for (int n = 0; n < 4; n++) acc[m][n] = (f32x4){0.f, 0.f, 0.f, 0.f};

    for (int k0 = 0; k0 < K; k0 += 32) {
#pragma unroll
        for (int i = 0; i < 2; i++) {
            int slot = i * 256 + tid;
            int row = slot >> 2, qp = slot & 3;
            int q = qp ^ ((row >> 1) & 3);
            const __hip_bfloat16* ga = A + (size_t)(row0 + row) * K + k0 + q * 8;
            const __hip_bfloat16* gb = Wt + (size_t)(col0 + row) * K + k0 + q * 8;
            __builtin_amdgcn_global_load_lds(
                (const __attribute__((address_space(1))) void*)ga,
                (__attribute__((address_space(3))) void*)((char*)Alds + i * 4096 + wid * 1024),
                16, 0, 0);
            __builtin_amdgcn_global_load_lds(
                (const __attribute__((address_space(1))) void*)gb,
                (__attribute__((address_space(3))) void*)((char*)Blds + i * 4096 + wid * 1024),
                16, 0, 0);
        }
        __syncthreads();
        short8 af[4], bf[4];
#pragma unroll
        for (int m = 0; m < 4; m++) {
            int row = wr * 64 + m * 16 + r16;
            af[m] = *reinterpret_cast<const short8*>(
                reinterpret_cast<const char*>(Alds) + row * 64 + rdoff * 16);
        }
#pragma unroll
        for (int n = 0; n < 4; n++) {
            int row = wc * 64 + n * 16 + r16;
            bf[n] = *reinterpret_cast<const short8*>(
                reinterpret_cast<const char*>(Blds) + row * 64 + rdoff * 16);
        }
#pragma unroll
        for (int m = 0; m < 4; m++)
#pragma unroll
            for (int n = 0; n < 4; n++)
                acc[m][n] = __builtin_amdgcn_mfma_f32_16x16x32_bf16(af[m], bf[n], acc[m][n], 0, 0, 0);
        __syncthreads();
    }

    int rg = lane >> 4;
    if (SCAT) {
        // rows = channels (0..127), cols = (b,n) token index; coalesced in n
#pragma unroll
        for (int n = 0; n < 4; n++) {
            int cc = col0 + wc * 64 + n * 16 + r16;
            int bb = cc >> 9, nn = cc & 511;
            float* dst = C + (size_t)bb * (LEVELS_ * PYOUT_ * N_) +
                         (size_t)level * PYOUT_ * N_ + nn;
#pragma unroll
            for (int m = 0; m < 4; m++) {
                int rbase = wr * 64 + m * 16 + rg * 4;   // row0 == 0 for SCAT
#pragma unroll
                for (int j = 0; j < 4; j++) {
                    int ch = rbase + j;
                    dst[(size_t)ch * N_] = acc[m][n][j] + bias[ch];
                }
            }
        }
        return;
    }
#pragma unroll
    for (int n = 0; n < 4; n++) {
        int cc = col0 + wc * 64 + n * 16 + r16;
        float bv = bias[cc];
#pragma unroll
        for (int m = 0; m < 4; m++) {
            int rb = row0 + wr * 64 + m * 16 + rg * 4;
#pragma unroll
            for (int j = 0; j < 4; j++) {
                int r = rb + j;
                float v = acc[m][n][j] + bv;
                if (resid) v += resid[(size_t)r * Nn + cc];
                if (ACT == 1) v = gelu_f(v);
                if (OUTF) C[(size_t)r * Nn + cc] = v;
                if (OUTB) Cb[(size_t)r * Nn + cc] = __float2bfloat16(v);
            }
        }
    }
}

// ---------------------------------------------------------------- LN + pos (wave per row)
__global__ __launch_bounds__(256) void ln_pos_kernel(
    const float* __restrict__ t, const float* __restrict__ g,
    const float* __restrict__ b, const float* __restrict__ pos,
    float* __restrict__ h, __hip_bfloat16* __restrict__ hb) {
    int lane = threadIdx.x & 63;
    int row = blockIdx.x * 4 + (threadIdx.x >> 6);
    const float4* xr = (const float4*)(t + (size_t)row * D_);
    float4 v = xr[lane];
    float s = v.x + v.y + v.z + v.w;
#pragma unroll
    for (int mk = 32; mk; mk >>= 1) s += __shfl_xor(s, mk);
    float mean = s * (1.f / 256.f);
    float dx = v.x - mean, dy = v.y - mean, dz = v.z - mean, dw = v.w - mean;
    float q = dx * dx + dy * dy + dz * dz + dw * dw;
#pragma unroll
    for (int mk = 32; mk; mk >>= 1) q += __shfl_xor(q, mk);
    float rstd = rsqrtf(q * (1.f / 256.f) + 1e-5f);
    float4 g4 = ((const float4*)g)[lane];
    float4 b4 = ((const float4*)b)[lane];
    float4 p4 = ((const float4*)pos)[(size_t)(row & (N_ - 1)) * 64 + lane];
    float o0 = dx * rstd * g4.x + b4.x + p4.x;
    float o1 = dy * rstd * g4.y + b4.y + p4.y;
    float o2 = dz * rstd * g4.z + b4.z + p4.z;
    float o3 = dw * rstd * g4.w + b4.w + p4.w;
    ((float4*)(h + (size_t)row * D_))[lane] = (float4){o0, o1, o2, o3};
    ushort4v u = {f2bf(o0), f2bf(o1), f2bf(o2), f2bf(o3)};
    *((ushort4v*)(hb + (size_t)row * D_) + lane) = u;
}

// ---------------------------------------------------------------- BN (two-stage)
__global__ __launch_bounds__(256) void bn_part_kernel(
    const float* __restrict__ x, float* __restrict__ part) {
    int g = blockIdx.x;                 // 64 blocks, 128 rows each
    int t = threadIdx.x;
    int c4 = t & 63, rs = t >> 6;
    const float4* xr = (const float4*)(x + (size_t)g * 128 * D_);
    float s[4] = {0.f, 0.f, 0.f, 0.f}, s2[4] = {0.f, 0.f, 0.f, 0.f};
    for (int r = rs; r < 128; r += 4) {
        float4 v = xr[r * 64 + c4];
        s[0] += v.x; s2[0] += v.x * v.x;
        s[1] += v.y; s2[1] += v.y * v.y;
        s[2] += v.z; s2[2] += v.z * v.z;
        s[3] += v.w; s2[3] += v.w * v.w;
    }
    __shared__ float ls[256][8];
#pragma unroll
    for (int i = 0; i < 4; i++) { ls[t][i] = s[i]; ls[t][4 + i] = s2[i]; }
    __syncthreads();
    if (rs == 0) {
#pragma unroll
        for (int i = 0; i < 4; i++) {
            float ss = 0.f, ss2 = 0.f;
#pragma unroll
            for (int q = 0; q < 4; q++) {
                ss += ls[q * 64 + c4][i];
                ss2 += ls[q * 64 + c4][4 + i];
            }
            int c = c4 * 4 + i;
            part[(size_t)g * 512 + c] = ss;
            part[(size_t)g * 512 + 256 + c] = ss2;
        }
    }
}

__global__ __launch_bounds__(256) void bn_finish_kernel(
    const float* __restrict__ part, float* __restrict__ stats) {
    int c = threadIdx.x;
    float s = 0.f, s2 = 0.f;
#pragma unroll 4
    for (int g = 0; g < 64; g++) {
        s += part[(size_t)g * 512 + c];
        s2 += part[(size_t)g * 512 + 256 + c];
    }
    float m = s * (1.f / 8192.f);
    stats[c] = m;
    stats[D_ + c] = s2 * (1.f / 8192.f) - m * m;
}

__global__ __launch_bounds__(256) void bn_apply_kernel(
    const float* __restrict__ x, const float* __restrict__ stats,
    const float* __restrict__ g, const float* __restrict__ b,
    float* __restrict__ y, __hip_bfloat16* __restrict__ yb) {
    int lane = threadIdx.x & 63;
    int row = blockIdx.x * 4 + (threadIdx.x >> 6);
    float4 m4 = ((const float4*)stats)[lane];
    float4 v4 = ((const float4*)(stats + D_))[lane];
    float4 g4 = ((const float4*)g)[lane];
    float4 b4 = ((const float4*)b)[lane];
    float4 x4 = ((const float4*)(x + (size_t)row * D_))[lane];
    float o0 = (x4.x - m4.x) * rsqrtf(v4.x + 1e-5f) * g4.x + b4.x;
    float o1 = (x4.y - m4.y) * rsqrtf(v4.y + 1e-5f) * g4.y + b4.y;
    float o2 = (x4.z - m4.z) * rsqrtf(v4.z + 1e-5f) * g4.z + b4.z;
    float o3 = (x4.w - m4.w) * rsqrtf(v4.w + 1e-5f) * g4.w + b4.w;
    if (y) ((float4*)(y + (size_t)row * D_))[lane] = (float4){o0, o1, o2, o3};
    if (yb) {
        ushort4v u = {f2bf(o0), f2bf(o1), f2bf(o2), f2bf(o3)};
        *((ushort4v*)(yb + (size_t)row * D_) + lane) = u;
    }
}

// ---------------------------------------------------------------- attention (bf16 in/out)
__global__ __launch_bounds__(256) void attn_kernel(
    const __hip_bfloat16* __restrict__ qkv, __hip_bfloat16* __restrict__ outb) {
    int i = blockIdx.x, h = blockIdx.y, b = blockIdx.z;
    int tid = threadIdx.x;
    __shared__ __hip_bfloat16 ks[BAND_ * 40];        // 80B rows
    __shared__ float ss[BS_][BAND_ + 4];
    __shared__ float red[BS_][8];
    int r = tid >> 3, lane8 = tid & 7;

    // Q row -> regs (8 lanes of a row load redundantly; L1-served)
    float qf[32];
    const short* qrow = (const short*)qkv + ((size_t)(b * N_ + i * BS_ + r)) * 768 + h * 32;
#pragma unroll
    for (int u = 0; u < 4; u++) {
        short8 qv = *(const short8*)(qrow + u * 8);
#pragma unroll
        for (int e = 0; e < 8; e++) qf[u * 8 + e] = bf2f(qv[e]);
    }
    // K band stage
    for (int e = tid; e < BAND_ * 4; e += 256) {
        int c = e >> 2, d8 = e & 3;
        int jb = i - 2 + (c >> 5);
        short8 v = (short8)0;
        if (jb >= 0 && jb < NBLK_)
            v = *(const short8*)((const short*)qkv +
                  ((size_t)(b * N_ + jb * BS_ + (c & 31))) * 768 + 256 + h * 32 + d8 * 8);
        *(short8*)((char*)ks + c * 80 + d8 * 16) = v;
    }
    __syncthreads();

    const float scale = 0.17677669529663687f;
    float p[20];
#pragma unroll
    for (int ci = 0; ci < 20; ci++) {
        int c = lane8 + ci * 8;
        int jb = i - 2 + (c >> 5);
        float s_ = -1e9f;
        if (jb >= 0 && jb < NBLK_) {
            float a = 0.f;
#pragma unroll
            for (int d8 = 0; d8 < 4; d8++) {
                short8 kv = *(const short8*)((const char*)ks + c * 80 + d8 * 16);
#pragma unroll
                for (int e = 0; e < 8; e++) a += bf2f(kv[e]) * qf[d8 * 8 + e];
            }
            s_ = a * scale;
        }
        p[ci] = s_;
    }
    // row max (per-thread then 8-lane via LDS)
    float mx = p[0];
#pragma unroll
    for (int ci = 1; ci < 20; ci++) mx = fmaxf(mx, p[ci]);
    red[r][lane8] = mx;
    __syncthreads();
    float m = red[r][0];
#pragma unroll
    for (int t2 = 1; t2 < 8; t2++) m = fmaxf(m, red[r][t2]);
    float sum = 0.f;
#pragma unroll
    for (int ci = 0; ci < 20; ci++) { p[ci] = __expf(p[ci] - m); sum += p[ci]; }
#pragma unroll
    for (int ci = 0; ci < 20; ci++) ss[r][lane8 + ci * 8] = p[ci];
    __syncthreads();                       // WAR on red + ss visibility
    red[r][lane8] = sum;
    // V band stage (overwrite ks; all QK^T reads completed before prior barrier)
    for (int e = tid; e < BAND_ * 4; e += 256) {
        int c = e >> 2, d8 = e & 3;
        int jb = i - 2 + (c >> 5);
        short8 v = (short8)0;
        if (jb >= 0 && jb < NBLK_)
            v = *(const short8*)((const short*)qkv +
                  ((size_t)(b * N_ + jb * BS_ + (c & 31))) * 768 + 512 + h * 32 + d8 * 8);
        *(short8*)((char*)ks + c * 80 + d8 * 16) = v;
    }
    __syncthreads();
    float tot = red[r][0];
#pragma unroll
    for (int t2 = 1; t2 < 8; t2++) tot += red[r][t2];

    // PV: thread (r, d-quad lane8)
    float4 o = {0.f, 0.f, 0.f, 0.f};
    int d0 = lane8 * 4;
    for (int c4 = 0; c4 < 40; c4++) {
        float4 sp = *(const float4*)&ss[r][c4 * 4];
        short4v v0 = *(const short4v*)((const char*)ks + (c4 * 4 + 0) * 80 + d0 * 2);
        short4v v1 = *(const short4v*)((const char*)ks + (c4 * 4 + 1) * 80 + d0 * 2);
        short4v v2 = *(const short4v*)((const char*)ks + (c4 * 4 + 2) * 80 + d0 * 2);
        short4v v3 = *(const short4v*)((const char*)ks + (c4 * 4 + 3) * 80 + d0 * 2);
        o.x += sp.x * bf2f(v0[0]) + sp.y * bf2f(v1[0]) + sp.z * bf2f(v2[0]) + sp.w * bf2f(v3[0]);
        o.y += sp.x * bf2f(v0[1]) + sp.y * bf2f(v1[1]) + sp.z * bf2f(v2[1]) + sp.w * bf2f(v3[1]);
        o.z += sp.x * bf2f(v0[2]) + sp.y * bf2f(v1[2]) + sp.z * bf2f(v2[2]) + sp.w * bf2f(v3[2]);
        o.w += sp.x * bf2f(v0[3]) + sp.y * bf2f(v1[3]) + sp.z * bf2f(v2[3]) + sp.w * bf2f(v3[3]);
    }
    float inv = 1.f / tot;
    ushort4v u = {f2bf(o.x * inv), f2bf(o.y * inv), f2bf(o.z * inv), f2bf(o.w * inv)};
    *(ushort4v*)((short*)outb + ((size_t)(b * N_ + i * BS_ + r)) * D_ + h * DH_ + d0) = u;
}

// ---------------------------------------------------------------- fcl
// RACE-FIXED: each thread owns (bg -> batches {2bg,2bg+1}) x (jq -> cols 4jq..4jq+3),
// loops over ALL 256 k of the chunk. No cross-thread accumulation.
__global__ __launch_bounds__(256) void fcl_partial_kernel(
    const float* __restrict__ flat, const float* __restrict__ W,
    float* __restrict__ partial) {
    int chunk = blockIdx.x;             // 1280
    int t = threadIdx.x;
    int k0 = chunk * FCL_KB;
    __shared__ float fl[FCL_KB][18];    // [k][b], padded (even stride for float2)
#pragma unroll
    for (int b = 0; b < 16; b++)
        fl[t][b] = flat[(size_t)b * FCL_K + k0 + t];
    __syncthreads();
    int jq = t & 31, bg = t >> 5;       // bg in 0..7
    f32x4 acc0 = (f32x4){0.f, 0.f, 0.f, 0.f};
    f32x4 acc1 = (f32x4){0.f, 0.f, 0.f, 0.f};
    const f32x4* W4 = (const f32x4*)W;
#pragma unroll 8
    for (int k = 0; k < FCL_KB; k++) {
        f32x4 wv = W4[(size_t)(k0 + k) * 32 + jq];
        float2 f2 = *(const float2*)&fl[k][bg * 2];
        acc0 += wv * f2.x;
        acc1 += wv * f2.y;
    }
    *(f32x4*)&partial[((size_t)chunk * 16 + bg * 2 + 0) * 128 + jq * 4] = acc0;
    *(f32x4*)&partial[((size_t)chunk * 16 + bg * 2 + 1) * 128 + jq * 4] = acc1;
}

__global__ __launch_bounds__(256) void fcl_reduce_kernel(
    const float* __restrict__ partial, const float* __restrict__ fcl_b,
    float* __restrict__ add) {
    int c0 = blockIdx.x * 32;   // 64 blocks
    int t = threadIdx.x;
    int ry = t >> 5, cx = t & 31;
    float s = 0.f;
    for (int r = ry; r < FCL_CHUNKS; r += 8)
        s += partial[(size_t)r * 2048 + c0 + cx];
    __shared__ float red[8][32];
    red[ry][cx] = s; __syncthreads();
    if (ry == 0) {
        float tot = 0.f;
#pragma unroll
        for (int q = 0; q < 8; q++) tot += red[q][cx];
        int col = c0 + cx;
        add[col] = tot + fcl_b[col & 127];
    }
}

// ---------------------------------------------------------------- fused head
__global__ __launch_bounds__(256) void head_kernel(
    const float* __restrict__ add, const float* __restrict__ abg, const float* __restrict__ abb,
    const float* __restrict__ cls_W1, const float* __restrict__ cls_b1,
    const float* __restrict__ cls_W2, const float* __restrict__ cls_b2,
    const float* __restrict__ box_W1, const float* __restrict__ box_b1,
    const float* __restrict__ box_W2, const float* __restrict__ box_b2,
    float* __restrict__ out) {
    __shared__ float a2[16][128];
    __shared__ float cm[16][256];
    __shared__ float cls[16][45];
    __shared__ float bmid[16][128];
    __shared__ float smden[16];
    int t = threadIdx.x;
    if (t < 128) {
        float m = 0.f;
#pragma unroll
        for (int b = 0; b < 16; b++) m += add[b * 128 + t];
        m *= (1.f / 16.f);
        float v = 0.f;
#pragma unroll
        for (int b = 0; b < 16; b++) { float d = add[b * 128 + t] - m; v += d * d; }
        v *= (1.f / 16.f);
        float sc = rsqrtf(v + 1e-5f) * abg[t];
#pragma unroll
        for (int b = 0; b < 16; b++) a2[b][t] = (add[b * 128 + t] - m) * sc + abb[t];
    }
    __syncthreads();
    for (int idx = t; idx < 4096; idx += 256) {
        int m = idx >> 8, c = idx & 255;
        float a = cls_b1[c];
        for (int k = 0; k < 128; k++) a += a2[m][k] * cls_W1[k * 256 + c];
        cm[m][c] = fmaxf(a, 0.f);
    }
    for (int idx = t; idx < 2048; idx += 256) {
        int m = idx >> 7, c = idx & 127;
        float a = box_b1[c];
        for (int k = 0; k < 128; k++) a += a2[m][k] * box_W1[k * 128 + c];
        bmid[m][c] = fmaxf(a, 0.f);
    }
    __syncthreads();
    for (int idx = t; idx < 720; idx += 256) {
        int m = idx / 45, c = idx % 45;
        float a = cls_b2[c];
        for (int k = 0; k < 256; k++) a += cm[m][k] * cls_W2[k * 45 + c];
        cls[m][c] = a;
    }
    __syncthreads();
    if (t < 16) {
        float mx = -1e30f;
        for (int c = 0; c < 45; c++) mx = fmaxf(mx, cls[t][c]);
        float s = 0.f;
        for (int c = 0; c < 45; c++) { float e = expf(cls[t][c] - mx); cls[t][c] = e; s += e; }
        smden[t] = s;
    }
    for (int idx = t; idx < 576; idx += 256) {
        int m = idx / 36, c = idx % 36;
        float a = box_b2[c];
        for (int k = 0; k < 128; k++) a += bmid[m][k] * box_W2[k * 36 + c];
        out[m * 81 + (c >> 2) * 9 + 5 + (c & 3)] = a;
    }
    __syncthreads();
    for (int idx = t; idx < 720; idx += 256) {
        int m = idx / 45, c = idx % 45;
        out[m * 81 + (c / 5) * 9 + (c % 5)] = cls[m][c] / smden[m];
    }
}

// ================================================================ launcher
extern "C" void kernel_launch(void* const* d_in, const int* in_sizes, int n_in,
                              void* d_out, int out_size, void* d_ws, size_t ws_size,
                              hipStream_t stream) {
    const float* x_in    = (const float*)d_in[0];
    const float* patch_W = (const float*)d_in[1];
    const float* patch_b = (const float*)d_in[2];
    const float* ln_g    = (const float*)d_in[3];
    const float* ln_b    = (const float*)d_in[4];
    const float* ff_W1   = (const float*)d_in[5];
    const float* ff_b1   = (const float*)d_in[6];
    const float* ff_W2   = (const float*)d_in[7];
    const float* ff_b2   = (const float*)d_in[8];
    const float* Wqkv    = (const float*)d_in[9];
    const float* bqkv    = (const float*)d_in[10];
    const float* Wo      = (const float*)d_in[11];
    const float* bo      = (const float*)d_in[12];
    const float* bn1_g   = (const float*)d_in[13];
    const float* bn1_b   = (const float*)d_in[14];
    const float* bn2_g   = (const float*)d_in[15];
    const float* bn2_b   = (const float*)d_in[16];
    const float* pyr_W   = (const float*)d_in[17];
    const float* pyr_b   = (const float*)d_in[18];
    const float* fcl_W   = (const float*)d_in[19];
    const float* fcl_b   = (const float*)d_in[20];
    const float* addbn_g = (const float*)d_in[21];
    const float* addbn_b = (const float*)d_in[22];
    const float* cls_W1  = (const float*)d_in[23];
    const float* cls_b1  = (const float*)d_in[24];
    const float* cls_W2  = (const float*)d_in[25];
    const float* cls_b2  = (const float*)d_in[26];
    const float* box_W1  = (const float*)d_in[27];
    const float* box_b1  = (const float*)d_in[28];
    const float* box_W2  = (const float*)d_in[29];
    const float* box_b2  = (const float*)d_in[30];
    float* out = (float*)d_out;

    float* ws = (float*)d_ws;
    size_t off = 0;
    float* POS   = ws + off; off += 131072;
    float* H     = ws + off; off += 2097152;
    float* T     = ws + off; off += 2097152;
    float* UNION = ws + off; off += 4194304;   // MIDb bf16 [8192][1024] / QKVb bf16 [8192][768]
    float* FLAT  = ws + off; off += 5242880;
    float* PART  = ws + off; off += (size_t)FCL_CHUNKS * 2048;
    float* STATS = ws + off; off += 512;
    float* BNP   = ws + off; off += 64 * 512;
    float* ADD   = ws + off; off += 2048;
    __hip_bfloat16* Hb   = (__hip_bfloat16*)(ws + off); off += 1048576;
    __hip_bfloat16* Tb   = (__hip_bfloat16*)(ws + off); off += 1048576;
    __hip_bfloat16* Xb   = (__hip_bfloat16*)(ws + off); off += 1048576;
    __hip_bfloat16* ATb  = (__hip_bfloat16*)(ws + off); off += 1048576;
    __hip_bfloat16* patchWt = (__hip_bfloat16*)(ws + off); off += 32768;
    __hip_bfloat16* qkvWt   = (__hip_bfloat16*)(ws + off); off += 98304;
    __hip_bfloat16* WoWt    = (__hip_bfloat16*)(ws + off); off += 32768;
    __hip_bfloat16* W1t     = (__hip_bfloat16*)(ws + off); off += 131072;
    __hip_bfloat16* W2t     = (__hip_bfloat16*)(ws + off); off += 131072;
    __hip_bfloat16* pyrWt   = (__hip_bfloat16*)(ws + off); off += 81920;
    __hip_bfloat16* MIDb = (__hip_bfloat16*)UNION;
    __hip_bfloat16* QKVb = (__hip_bfloat16*)UNION;

    pos_kernel<<<(N_ * D_ + 255) / 256, 256, 0, stream>>>(POS);
    wconv_kernel<<<dim3(D_ / 32, D_ / 32, 1), dim3(32, 8), 0, stream>>>(patch_W, patchWt, D_, D_);
    wconv_kernel<<<dim3(768 / 32, D_ / 32, 1), dim3(32, 8), 0, stream>>>(Wqkv, qkvWt, D_, 768);
    wconv_kernel<<<dim3(D_ / 32, D_ / 32, 1), dim3(32, 8), 0, stream>>>(Wo, WoWt, D_, D_);
    wconv_kernel<<<dim3(HIDEF_ / 32, D_ / 32, 1), dim3(32, 8), 0, stream>>>(ff_W1, W1t, D_, HIDEF_);
    wconv_kernel<<<dim3(D_ / 32, HIDEF_ / 32, 1), dim3(32, 8), 0, stream>>>(ff_W2, W2t, HIDEF_, D_);
    wconv_kernel<<<dim3(PYOUT_ / 32, D_ / 32, LEVELS_), dim3(32, 8), 0, stream>>>(pyr_W, pyrWt, D_, PYOUT_);
    tobf16_kernel<<<(ROWS_ * D_ + 255) / 256, 256, 0, stream>>>(x_in, Xb, ROWS_ * D_);

    for (int it = 0; it < 5; it++) {
        bgemm_kernel<0, true, false, false><<<dim3(2, 64), 256, 0, stream>>>(
            Xb, patchWt, patch_b, nullptr, T, nullptr, ROWS_, D_, D_, 0);
        ln_pos_kernel<<<ROWS_ / 4, 256, 0, stream>>>(T, ln_g, ln_b, POS, H, Hb);
        bgemm_kernel<1, false, true, false><<<dim3(8, 64), 256, 0, stream>>>(
            Hb, W1t, ff_b1, nullptr, nullptr, MIDb, ROWS_, HIDEF_, D_, 0);
        bgemm_kernel<0, false, true, false><<<dim3(2, 64), 256, 0, stream>>>(
            MIDb, W2t, ff_b2, nullptr, nullptr, Tb, ROWS_, D_, HIDEF_, 0);
        bgemm_kernel<0, false, true, false><<<dim3(6, 64), 256, 0, stream>>>(
            Tb, qkvWt, bqkv, nullptr, nullptr, QKVb, ROWS_, 768, D_, 0);
        attn_kernel<<<dim3(NBLK_, HEADS_, B_), 256, 0, stream>>>(QKVb, ATb);
        bgemm_kernel<0, true, false, false><<<dim3(2, 64), 256, 0, stream>>>(
            ATb, WoWt, bo, H, T, nullptr, ROWS_, D_, D_, 0);
        bn_part_kernel<<<64, 256, 0, stream>>>(T, BNP);
        bn_finish_kernel<<<1, 256, 0, stream>>>(BNP, STATS);
        bn_apply_kernel<<<ROWS_ / 4, 256, 0, stream>>>(T, STATS, bn1_g, bn1_b, H, Hb);
        bgemm_kernel<1, false, true, false><<<dim3(8, 64), 256, 0, stream>>>(
            Hb, W1t, ff_b1, nullptr, nullptr, MIDb, ROWS_, HIDEF_, D_, 0);
        bgemm_kernel<0, true, false, false><<<dim3(2, 64), 256, 0, stream>>>(
            MIDb, W2t, ff_b2, H, T, nullptr, ROWS_, D_, HIDEF_, 0);
        bn_part_kernel<<<64, 256, 0, stream>>>(T, BNP);
        bn_finish_kernel<<<1, 256, 0, stream>>>(BNP, STATS);
        bn_apply_kernel<<<ROWS_ / 4, 256, 0, stream>>>(T, STATS, bn2_g, bn2_b, nullptr, Xb);
        // pyramid level: transposed GEMM, fused coalesced scatter into FLAT
        bgemm_kernel<0, false, false, true><<<dim3(64, 1), 256, 0, stream>>>(
            pyrWt + (size_t)it * D_ * PYOUT_, Xb, pyr_b + it * PYOUT_, nullptr,
            FLAT, nullptr, PYOUT_, ROWS_, D_, it);
    }

    fcl_partial_kernel<<<FCL_CHUNKS, 256, 0, stream>>>(FLAT, fcl_W, PART);
    fcl_reduce_kernel<<<64, 256, 0, stream>>>(PART, fcl_b, ADD);
    head_kernel<<<1, 256, 0, stream>>>(ADD, addbn_g, addbn_b,
        cls_W1, cls_b1, cls_W2, cls_b2, box_W1, box_b1, box_W2, box_b2, out);
    (void)in_sizes; (void)n_in; (void)out_size; (void)ws_size;
}

// Round 5
// 1034.891 us; speedup vs baseline: 4.4842x; 1.3655x over previous
//
#include <hip/hip_runtime.h>
#include <hip/hip_bf16.h>
#include <math.h>

#define B_ 16
#define N_ 512
#define D_ 256
#define HEADS_ 8
#define DH_ 32
#define HIDEF_ 1024
#define NBLK_ 16
#define BS_ 32
#define LEVELS_ 5
#define PYOUT_ 128
#define ROWS_ (B_ * N_)   // 8192
#define FCL_K 327680
#define FCL_KB 256
#define FCL_CHUNKS 1280

typedef __attribute__((ext_vector_type(8))) short short8;
typedef __attribute__((ext_vector_type(4))) short short4v;
typedef __attribute__((ext_vector_type(4))) unsigned short ushort4v;
typedef __attribute__((ext_vector_type(4))) float f32x4;

__device__ __forceinline__ float bf2f(short u) {
    return __uint_as_float(((unsigned int)(unsigned short)u) << 16);
}
__device__ __forceinline__ unsigned short f2bf(float x) {
    __hip_bfloat16 h = __float2bfloat16(x);
    return *reinterpret_cast<unsigned short*>(&h);
}

// ---------------------------------------------------------------- position
__global__ void pos_kernel(float* __restrict__ pos) {
    int idx = blockIdx.x * 256 + threadIdx.x;
    if (idx >= N_ * D_) return;
    int n = idx >> 8, i = idx & 255;
    double angle = (double)n / pow(10000.0, (double)(2 * (i >> 1)) / 256.0);
    pos[idx] = (float)((i & 1) ? cos(angle) : sin(angle));
}

__device__ __forceinline__ float gelu_f(float x) {
    float x3 = x * x * x;
    return 0.5f * x * (1.f + tanhf(0.7978845608028654f * (x + 0.044715f * x3)));
}

// ---------------------------------------------------------------- converts
__global__ void tobf16_kernel(const float* __restrict__ x, __hip_bfloat16* __restrict__ y, int n) {
    int i = blockIdx.x * 256 + threadIdx.x;
    if (i < n) y[i] = __float2bfloat16(x[i]);
}

__global__ __launch_bounds__(256) void wconv_kernel(const float* __restrict__ W,
                                                    __hip_bfloat16* __restrict__ Wt,
                                                    int K, int N) {
    int z = blockIdx.z;
    const float* Wz = W + (size_t)z * K * N;
    __hip_bfloat16* Wtz = Wt + (size_t)z * K * N;
    __shared__ float t[32][33];
    int bx = blockIdx.x * 32, by = blockIdx.y * 32;
    int tx = threadIdx.x, ty = threadIdx.y;
#pragma unroll
    for (int i = 0; i < 32; i += 8)
        t[ty + i][tx] = Wz[(size_t)(by + ty + i) * N + bx + tx];
    __syncthreads();
#pragma unroll
    for (int i = 0; i < 32; i += 8)
        Wtz[(size_t)(bx + ty + i) * K + by + tx] = __float2bfloat16(t[tx][ty + i]);
}

// ---------------------------------------------------------------- bf16 MFMA GEMM
// BM=128, BK=32, BN in {64,128}. 4 waves. global_load_lds w16, chunk-XOR swizzle.
// STATS: per-block column sum/sumsq partials -> bnp[64][256] (+16384 for sq)
template <int ACT, bool OUTF, bool OUTB, bool SCAT, bool STATS, int BN>
__global__ __launch_bounds__(256) void bgemm_kernel(
    const __hip_bfloat16* __restrict__ A, const __hip_bfloat16* __restrict__ Wt,
    const float* __restrict__ bias, const float* __restrict__ resid,
    float* __restrict__ C, __hip_bfloat16* __restrict__ Cb, int M, int Nn, int K,
    int level, float* __restrict__ bnp) {
    __shared__ __hip_bfloat16 Alds[128 * 32];
    __shared__ __hip_bfloat16 Blds[BN * 32];
    constexpr int MW = (BN == 128) ? 4 : 2;   // m-frags per wave
    constexpr int WH = (BN == 128) ? 64 : 32; // wave row height
    constexpr int BR = BN / 64;               // B staging rounds
    int tid = threadIdx.x;
    int wid = tid >> 6, lane = tid & 63;
    int row0 = blockIdx.y * 128, col0 = blockIdx.x * BN;
    int wr = (BN == 128) ? (wid >> 1) : wid;
    int wc = (BN == 128) ? (wid & 1) : 0;
    int r16 = lane & 15, kq = lane >> 4;
    int rdoff = kq ^ ((r16 >> 1) & 3);

    f32x4 acc[MW][4];
#pragma unroll
    for (int m = 0; m < MW; m++)
#pragma unroll
        for (int n = 0; n < 4; n++) acc[m][n] = (f32x4){0.f, 0.f, 0.f, 0.f};

    for (int k0 = 0; k0 < K; k0 += 32) {
#pragma unroll
        for (int i = 0; i < 2; i++) {
            int slot = i * 256 + tid;
            int row = slot >> 2, qp = slot & 3;
            int q = qp ^ ((row >> 1) & 3);
            const __hip_bfloat16* ga = A + (size_t)(row0 + row) * K + k0 + q * 8;
            __builtin_amdgcn_global_load_lds(
                (const __attribute__((address_space(1))) void*)ga,
                (__attribute__((address_space(3))) void*)((char*)Alds + i * 4096 + wid * 1024),
                16, 0, 0);
        }
#pragma unroll
        for (int i = 0; i < BR; i++) {
            int slot = i * 256 + tid;
            int row = slot >> 2, qp = slot & 3;
            int q = qp ^ ((row >> 1) & 3);
            const __hip_bfloat16* gb = Wt + (size_t)(col0 + row) * K + k0 + q * 8;
            __builtin_amdgcn_global_load_lds(
                (const __attribute__((address_space(1))) void*)gb,
                (__attribute__((address_space(3))) void*)((char*)Blds + i * 4096 + wid * 1024),
                16, 0, 0);
        }
        __syncthreads();
        short8 af[MW], bf[4];
#pragma unroll
        for (int m = 0; m < MW; m++) {
            int row = wr * WH + m * 16 + r16;
            af[m] = *reinterpret_cast<const short8*>(
                reinterpret_cast<const char*>(Alds) + row * 64 + rdoff * 16);
        }
#pragma unroll
        for (int n = 0; n < 4; n++) {
            int row = wc * 64 + n * 16 + r16;
            bf[n] = *reinterpret_cast<const short8*>(
                reinterpret_cast<const char*>(Blds) + row * 64 + rdoff * 16);
        }
#pragma unroll
        for (int m = 0; m < MW; m++)
#pragma unroll
            for (int n = 0; n < 4; n++)
                acc[m][n] = __builtin_amdgcn_mfma_f32_16x16x32_bf16(af[m], bf[n], acc[m][n], 0, 0, 0);
        __syncthreads();
    }

    int rg = lane >> 4;
    float s1a[4] = {0.f, 0.f, 0.f, 0.f}, s2a[4] = {0.f, 0.f, 0.f, 0.f};
    if (SCAT) {
#pragma unroll
        for (int n = 0; n < 4; n++) {
            int cc = col0 + wc * 64 + n * 16 + r16;
            int bb = cc >> 9, nn = cc & 511;
            float* dst = C + (size_t)bb * (LEVELS_ * PYOUT_ * N_) +
                         (size_t)level * PYOUT_ * N_ + nn;
#pragma unroll
            for (int m = 0; m < MW; m++) {
                int rbase = wr * WH + m * 16 + rg * 4;
#pragma unroll
                for (int j = 0; j < 4; j++) {
                    int ch = rbase + j;
                    dst[(size_t)ch * N_] = acc[m][n][j] + bias[ch];
                }
            }
        }
    } else {
#pragma unroll
        for (int n = 0; n < 4; n++) {
            int cc = col0 + wc * 64 + n * 16 + r16;
            float bv = bias[cc];
#pragma unroll
            for (int m = 0; m < MW; m++) {
                int rb = row0 + wr * WH + m * 16 + rg * 4;
#pragma unroll
                for (int j = 0; j < 4; j++) {
                    int r = rb + j;
                    float v = acc[m][n][j] + bv;
                    if (resid) v += resid[(size_t)r * Nn + cc];
                    if (ACT == 1) v = gelu_f(v);
                    if (OUTF) C[(size_t)r * Nn + cc] = v;
                    if (OUTB) Cb[(size_t)r * Nn + cc] = __float2bfloat16(v);
                    if (STATS) { s1a[n] += v; s2a[n] += v * v; }
                }
            }
        }
    }
    if (STATS) {
        // reuse Alds (8 KB = 2048 floats) as scratch; all LDS reads done (loop-final barrier)
        float* sc = (float*)Alds;
        int part = wid * 4 + rg;
#pragma unroll
        for (int n = 0; n < 4; n++) {
            int c = wc * 64 + n * 16 + r16;   // 0..BN-1
            sc[c * 16 + part] = s1a[n];
            sc[1024 + c * 16 + part] = s2a[n];
        }
        __syncthreads();
        if (tid < BN) {
            float a = 0.f, b2 = 0.f;
#pragma unroll
            for (int p = 0; p < 16; p++) {
                a += sc[tid * 16 + p];
                b2 += sc[1024 + tid * 16 + p];
            }
            bnp[blockIdx.y * 256 + col0 + tid] = a;
            bnp[16384 + blockIdx.y * 256 + col0 + tid] = b2;
        }
    }
}

// ---------------------------------------------------------------- LN + pos (wave per row)
__global__ __launch_bounds__(256) void ln_pos_kernel(
    const float* __restrict__ t, const float* __restrict__ g,
    const float* __restrict__ b, const float* __restrict__ pos,
    float* __restrict__ h, __hip_bfloat16* __restrict__ hb) {
    int lane = threadIdx.x & 63;
    int row = blockIdx.x * 4 + (threadIdx.x >> 6);
    const float4* xr = (const float4*)(t + (size_t)row * D_);
    float4 v = xr[lane];
    float s = v.x + v.y + v.z + v.w;
#pragma unroll
    for (int mk = 32; mk; mk >>= 1) s += __shfl_xor(s, mk);
    float mean = s * (1.f / 256.f);
    float dx = v.x - mean, dy = v.y - mean, dz = v.z - mean, dw = v.w - mean;
    float q = dx * dx + dy * dy + dz * dz + dw * dw;
#pragma unroll
    for (int mk = 32; mk; mk >>= 1) q += __shfl_xor(q, mk);
    float rstd = rsqrtf(q * (1.f / 256.f) + 1e-5f);
    float4 g4 = ((const float4*)g)[lane];
    float4 b4 = ((const float4*)b)[lane];
    float4 p4 = ((const float4*)pos)[(size_t)(row & (N_ - 1)) * 64 + lane];
    float o0 = dx * rstd * g4.x + b4.x + p4.x;
    float o1 = dy * rstd * g4.y + b4.y + p4.y;
    float o2 = dz * rstd * g4.z + b4.z + p4.z;
    float o3 = dw * rstd * g4.w + b4.w + p4.w;
    ((float4*)(h + (size_t)row * D_))[lane] = (float4){o0, o1, o2, o3};
    ushort4v u = {f2bf(o0), f2bf(o1), f2bf(o2), f2bf(o3)};
    *((ushort4v*)(hb + (size_t)row * D_) + lane) = u;
}

// ---------------------------------------------------------------- BN finish + apply
__global__ __launch_bounds__(256) void bn_finish_kernel(
    const float* __restrict__ bnp, float* __restrict__ stats) {
    int c = threadIdx.x;
    float s = 0.f, s2 = 0.f;
#pragma unroll 4
    for (int y = 0; y < 64; y++) {
        s += bnp[y * 256 + c];
        s2 += bnp[16384 + y * 256 + c];
    }
    float m = s * (1.f / 8192.f);
    stats[c] = m;
    stats[D_ + c] = s2 * (1.f / 8192.f) - m * m;
}

__global__ __launch_bounds__(256) void bn_apply_kernel(
    const float* __restrict__ x, const float* __restrict__ stats,
    const float* __restrict__ g, const float* __restrict__ b,
    float* __restrict__ y, __hip_bfloat16* __restrict__ yb) {
    int lane = threadIdx.x & 63;
    int row = blockIdx.x * 4 + (threadIdx.x >> 6);
    float4 m4 = ((const float4*)stats)[lane];
    float4 v4 = ((const float4*)(stats + D_))[lane];
    float4 g4 = ((const float4*)g)[lane];
    float4 b4 = ((const float4*)b)[lane];
    float4 x4 = ((const float4*)(x + (size_t)row * D_))[lane];
    float o0 = (x4.x - m4.x) * rsqrtf(v4.x + 1e-5f) * g4.x + b4.x;
    float o1 = (x4.y - m4.y) * rsqrtf(v4.y + 1e-5f) * g4.y + b4.y;
    float o2 = (x4.z - m4.z) * rsqrtf(v4.z + 1e-5f) * g4.z + b4.z;
    float o3 = (x4.w - m4.w) * rsqrtf(v4.w + 1e-5f) * g4.w + b4.w;
    if (y) ((float4*)(y + (size_t)row * D_))[lane] = (float4){o0, o1, o2, o3};
    if (yb) {
        ushort4v u = {f2bf(o0), f2bf(o1), f2bf(o2), f2bf(o3)};
        *((ushort4v*)(yb + (size_t)row * D_) + lane) = u;
    }
}

// ---------------------------------------------------------------- MFMA attention
// Block = (igroup, h, b). 4 waves; wave w handles query block i = bx*4+w.
// S^T = mfma(K_frag, Q_frag): C-layout (col=q=l&15, key=(l>>4)*4+j) feeds PV's
// A-operand directly (zero-padded K=32 MFMA). V reg-transposed to Vt[32][264].
__global__ __launch_bounds__(256) void attn_kernel(
    const __hip_bfloat16* __restrict__ qkv, __hip_bfloat16* __restrict__ outb) {
    int bx = blockIdx.x, h = blockIdx.y, b = blockIdx.z;
    int tid = threadIdx.x;
    int wid = tid >> 6, lane = tid & 63;
    __shared__ __hip_bfloat16 Klds[256 * 32];   // 256 keys x 64B rows, XOR-chunked
    __shared__ __hip_bfloat16 Vt[32 * 264];     // [dh][key] transposed, padded
    const short* q16 = (const short*)qkv;

    // stage K (8 key-blocks bx*4-2 .. bx*4+5, clamped)
#pragma unroll
    for (int r = 0; r < 4; r++) {
        int slot = r * 256 + tid;
        int row = slot >> 2, qp = slot & 3;
        int ql = qp ^ ((row >> 1) & 3);
        int jb = bx * 4 - 2 + (row >> 5);
        jb = jb < 0 ? 0 : (jb > 15 ? 15 : jb);
        const short* ga = q16 + ((size_t)(b * N_ + jb * 32 + (row & 31))) * 768 + 256 + h * 32 + ql * 8;
        __builtin_amdgcn_global_load_lds(
            (const __attribute__((address_space(1))) void*)ga,
            (__attribute__((address_space(3))) void*)((char*)Klds + r * 4096 + wid * 1024),
            16, 0, 0);
    }
    // stage V transposed: thread t <-> staged key t
    {
        int row = tid;
        int jb = bx * 4 - 2 + (row >> 5);
        jb = jb < 0 ? 0 : (jb > 15 ? 15 : jb);
        const short* gv = q16 + ((size_t)(b * N_ + jb * 32 + (row & 31))) * 768 + 512 + h * 32;
        short8 v0 = *(const short8*)(gv);
        short8 v1 = *(const short8*)(gv + 8);
        short8 v2 = *(const short8*)(gv + 16);
        short8 v3 = *(const short8*)(gv + 24);
        short* vt = (short*)Vt;
#pragma unroll
        for (int e = 0; e < 8; e++) {
            vt[(e) * 264 + row] = v0[e];
            vt[(8 + e) * 264 + row] = v1[e];
            vt[(16 + e) * 264 + row] = v2[e];
            vt[(24 + e) * 264 + row] = v3[e];
        }
    }
    __syncthreads();

    int i = bx * 4 + wid;
    int c = lane & 15, g = lane >> 4;
    const float scale = 0.17677669529663687f;

#pragma unroll
    for (int qt = 0; qt < 2; qt++) {
        // Q B-fragment direct from global
        const short* qa = q16 + ((size_t)(b * N_ + i * 32 + qt * 16 + c)) * 768 + h * 32 + g * 8;
        short8 bq = *(const short8*)qa;
        f32x4 st[10];
        // S^T tiles
#pragma unroll
        for (int t = 0; t < 10; t++) {
            int jb = i - 2 + (t >> 1);
            if (jb >= 0 && jb < NBLK_) {
                int row = wid * 32 + t * 16 + c;
                int phys = g ^ ((row >> 1) & 3);
                short8 ak = *(const short8*)((const char*)Klds + row * 64 + phys * 16);
                st[t] = __builtin_amdgcn_mfma_f32_16x16x32_bf16(
                    ak, bq, (f32x4){0.f, 0.f, 0.f, 0.f}, 0, 0, 0);
            }
        }
        // softmax in-register (lane owns q = qt*16+c, keys (l>>4)*4+j per tile)
        float mx = -1e30f;
#pragma unroll
        for (int t = 0; t < 10; t++) {
            int jb = i - 2 + (t >> 1);
            if (jb >= 0 && jb < NBLK_) {
#pragma unroll
                for (int j = 0; j < 4; j++) {
                    st[t][j] *= scale;
                    mx = fmaxf(mx, st[t][j]);
                }
            }
        }
        mx = fmaxf(mx, __shfl_xor(mx, 16));
        mx = fmaxf(mx, __shfl_xor(mx, 32));
        float sum = 0.f;
#pragma unroll
        for (int t = 0; t < 10; t++) {
            int jb = i - 2 + (t >> 1);
            if (jb >= 0 && jb < NBLK_) {
#pragma unroll
                for (int j = 0; j < 4; j++) {
                    float e = __expf(st[t][j] - mx);
                    st[t][j] = e;
                    sum += e;
                }
            }
        }
        sum += __shfl_xor(sum, 16);
        sum += __shfl_xor(sum, 32);
        float inv = 1.f / sum;
        // PV: O[q][dh] accumulate over tiles
        f32x4 o0 = (f32x4){0.f, 0.f, 0.f, 0.f};
        f32x4 o1 = (f32x4){0.f, 0.f, 0.f, 0.f};
        const short* vt = (const short*)Vt;
#pragma unroll
        for (int t = 0; t < 10; t++) {
            int jb = i - 2 + (t >> 1);
            if (jb >= 0 && jb < NBLK_) {
                short8 pa = (short8)0;
#pragma unroll
                for (int j = 0; j < 4; j++) pa[j] = (short)f2bf(st[t][j] * inv);
                int kb = wid * 32 + t * 16 + g * 4;
                short4v vb0 = *(const short4v*)(vt + (0 * 16 + c) * 264 + kb);
                short4v vb1 = *(const short4v*)(vt + (1 * 16 + c) * 264 + kb);
                short8 b0 = (short8)0, b1 = (short8)0;
#pragma unroll
                for (int e = 0; e < 4; e++) { b0[e] = vb0[e]; b1[e] = vb1[e]; }
                o0 = __builtin_amdgcn_mfma_f32_16x16x32_bf16(pa, b0, o0, 0, 0, 0);
                o1 = __builtin_amdgcn_mfma_f32_16x16x32_bf16(pa, b1, o1, 0, 0, 0);
            }
        }
        // store: row q = (l>>4)*4+j, col dh = n*16 + c
#pragma unroll
        for (int j = 0; j < 4; j++) {
            size_t rbase = ((size_t)(b * N_ + i * 32 + qt * 16 + g * 4 + j)) * D_ + h * DH_;
            outb[rbase + c] = __float2bfloat16(o0[j]);
            outb[rbase + 16 + c] = __float2bfloat16(o1[j]);
        }
    }
}

// ---------------------------------------------------------------- fcl
__global__ __launch_bounds__(256) void fcl_partial_kernel(
    const float* __restrict__ flat, const float* __restrict__ W,
    float* __restrict__ partial) {
    int chunk = blockIdx.x;             // 1280
    int t = threadIdx.x;
    int k0 = chunk * FCL_KB;
    __shared__ float fl[FCL_KB][18];
#pragma unroll
    for (int b = 0; b < 16; b++)
        fl[t][b] = flat[(size_t)b * FCL_K + k0 + t];
    __syncthreads();
    int jq = t & 31, bg = t >> 5;
    f32x4 acc0 = (f32x4){0.f, 0.f, 0.f, 0.f};
    f32x4 acc1 = (f32x4){0.f, 0.f, 0.f, 0.f};
    const f32x4* W4 = (const f32x4*)W;
#pragma unroll 8
    for (int k = 0; k < FCL_KB; k++) {
        f32x4 wv = W4[(size_t)(k0 + k) * 32 + jq];
        float2 f2 = *(const float2*)&fl[k][bg * 2];
        acc0 += wv * f2.x;
        acc1 += wv * f2.y;
    }
    *(f32x4*)&partial[((size_t)chunk * 16 + bg * 2 + 0) * 128 + jq * 4] = acc0;
    *(f32x4*)&partial[((size_t)chunk * 16 + bg * 2 + 1) * 128 + jq * 4] = acc1;
}

__global__ __launch_bounds__(256) void fcl_reduce_kernel(
    const float* __restrict__ partial, const float* __restrict__ fcl_b,
    float* __restrict__ add) {
    int c0 = blockIdx.x * 32;
    int t = threadIdx.x;
    int ry = t >> 5, cx = t & 31;
    float s = 0.f;
    for (int r = ry; r < FCL_CHUNKS; r += 8)
        s += partial[(size_t)r * 2048 + c0 + cx];
    __shared__ float red[8][32];
    red[ry][cx] = s; __syncthreads();
    if (ry == 0) {
        float tot = 0.f;
#pragma unroll
        for (int q = 0; q < 8; q++) tot += red[q][cx];
        int col = c0 + cx;
        add[col] = tot + fcl_b[col & 127];
    }
}

// ---------------------------------------------------------------- fused head
__global__ __launch_bounds__(256) void head_kernel(
    const float* __restrict__ add, const float* __restrict__ abg, const float* __restrict__ abb,
    const float* __restrict__ cls_W1, const float* __restrict__ cls_b1,
    const float* __restrict__ cls_W2, const float* __restrict__ cls_b2,
    const float* __restrict__ box_W1, const float* __restrict__ box_b1,
    const float* __restrict__ box_W2, const float* __restrict__ box_b2,
    float* __restrict__ out) {
    __shared__ float a2[16][128];
    __shared__ float cm[16][256];
    __shared__ float cls[16][45];
    __shared__ float bmid[16][128];
    __shared__ float smden[16];
    int t = threadIdx.x;
    if (t < 128) {
        float m = 0.f;
#pragma unroll
        for (int b = 0; b < 16; b++) m += add[b * 128 + t];
        m *= (1.f / 16.f);
        float v = 0.f;
#pragma unroll
        for (int b = 0; b < 16; b++) { float d = add[b * 128 + t] - m; v += d * d; }
        v *= (1.f / 16.f);
        float sc = rsqrtf(v + 1e-5f) * abg[t];
#pragma unroll
        for (int b = 0; b < 16; b++) a2[b][t] = (add[b * 128 + t] - m) * sc + abb[t];
    }
    __syncthreads();
    for (int idx = t; idx < 4096; idx += 256) {
        int m = idx >> 8, c = idx & 255;
        float a = cls_b1[c];
        for (int k = 0; k < 128; k++) a += a2[m][k] * cls_W1[k * 256 + c];
        cm[m][c] = fmaxf(a, 0.f);
    }
    for (int idx = t; idx < 2048; idx += 256) {
        int m = idx >> 7, c = idx & 127;
        float a = box_b1[c];
        for (int k = 0; k < 128; k++) a += a2[m][k] * box_W1[k * 128 + c];
        bmid[m][c] = fmaxf(a, 0.f);
    }
    __syncthreads();
    for (int idx = t; idx < 720; idx += 256) {
        int m = idx / 45, c = idx % 45;
        float a = cls_b2[c];
        for (int k = 0; k < 256; k++) a += cm[m][k] * cls_W2[k * 45 + c];
        cls[m][c] = a;
    }
    __syncthreads();
    if (t < 16) {
        float mx = -1e30f;
        for (int c = 0; c < 45; c++) mx = fmaxf(mx, cls[t][c]);
        float s = 0.f;
        for (int c = 0; c < 45; c++) { float e = expf(cls[t][c] - mx); cls[t][c] = e; s += e; }
        smden[t] = s;
    }
    for (int idx = t; idx < 576; idx += 256) {
        int m = idx / 36, c = idx % 36;
        float a = box_b2[c];
        for (int k = 0; k < 128; k++) a += bmid[m][k] * box_W2[k * 36 + c];
        out[m * 81 + (c >> 2) * 9 + 5 + (c & 3)] = a;
    }
    __syncthreads();
    for (int idx = t; idx < 720; idx += 256) {
        int m = idx / 45, c = idx % 45;
        out[m * 81 + (c / 5) * 9 + (c % 5)] = cls[m][c] / smden[m];
    }
}

// ================================================================ launcher
extern "C" void kernel_launch(void* const* d_in, const int* in_sizes, int n_in,
                              void* d_out, int out_size, void* d_ws, size_t ws_size,
                              hipStream_t stream) {
    const float* x_in    = (const float*)d_in[0];
    const float* patch_W = (const float*)d_in[1];
    const float* patch_b = (const float*)d_in[2];
    const float* ln_g    = (const float*)d_in[3];
    const float* ln_b    = (const float*)d_in[4];
    const float* ff_W1   = (const float*)d_in[5];
    const float* ff_b1   = (const float*)d_in[6];
    const float* ff_W2   = (const float*)d_in[7];
    const float* ff_b2   = (const float*)d_in[8];
    const float* Wqkv    = (const float*)d_in[9];
    const float* bqkv    = (const float*)d_in[10];
    const float* Wo      = (const float*)d_in[11];
    const float* bo      = (const float*)d_in[12];
    const float* bn1_g   = (const float*)d_in[13];
    const float* bn1_b   = (const float*)d_in[14];
    const float* bn2_g   = (const float*)d_in[15];
    const float* bn2_b   = (const float*)d_in[16];
    const float* pyr_W   = (const float*)d_in[17];
    const float* pyr_b   = (const float*)d_in[18];
    const float* fcl_W   = (const float*)d_in[19];
    const float* fcl_b   = (const float*)d_in[20];
    const float* addbn_g = (const float*)d_in[21];
    const float* addbn_b = (const float*)d_in[22];
    const float* cls_W1  = (const float*)d_in[23];
    const float* cls_b1  = (const float*)d_in[24];
    const float* cls_W2  = (const float*)d_in[25];
    const float* cls_b2  = (const float*)d_in[26];
    const float* box_W1  = (const float*)d_in[27];
    const float* box_b1  = (const float*)d_in[28];
    const float* box_W2  = (const float*)d_in[29];
    const float* box_b2  = (const float*)d_in[30];
    float* out = (float*)d_out;

    float* ws = (float*)d_ws;
    size_t off = 0;
    float* POS   = ws + off; off += 131072;
    float* H     = ws + off; off += 2097152;
    float* T     = ws + off; off += 2097152;
    float* UNION = ws + off; off += 4194304;   // MIDb bf16 / QKVb bf16
    float* FLAT  = ws + off; off += 5242880;
    float* PART  = ws + off; off += (size_t)FCL_CHUNKS * 2048;
    float* STATS = ws + off; off += 512;
    float* BNP   = ws + off; off += 2 * 64 * 256;
    float* ADD   = ws + off; off += 2048;
    __hip_bfloat16* Hb   = (__hip_bfloat16*)(ws + off); off += 1048576;
    __hip_bfloat16* Tb   = (__hip_bfloat16*)(ws + off); off += 1048576;
    __hip_bfloat16* Xb   = (__hip_bfloat16*)(ws + off); off += 1048576;
    __hip_bfloat16* ATb  = (__hip_bfloat16*)(ws + off); off += 1048576;
    __hip_bfloat16* patchWt = (__hip_bfloat16*)(ws + off); off += 32768;
    __hip_bfloat16* qkvWt   = (__hip_bfloat16*)(ws + off); off += 98304;
    __hip_bfloat16* WoWt    = (__hip_bfloat16*)(ws + off); off += 32768;
    __hip_bfloat16* W1t     = (__hip_bfloat16*)(ws + off); off += 131072;
    __hip_bfloat16* W2t     = (__hip_bfloat16*)(ws + off); off += 131072;
    __hip_bfloat16* pyrWt   = (__hip_bfloat16*)(ws + off); off += 81920;
    __hip_bfloat16* MIDb = (__hip_bfloat16*)UNION;
    __hip_bfloat16* QKVb = (__hip_bfloat16*)UNION;

    pos_kernel<<<(N_ * D_ + 255) / 256, 256, 0, stream>>>(POS);
    wconv_kernel<<<dim3(D_ / 32, D_ / 32, 1), dim3(32, 8), 0, stream>>>(patch_W, patchWt, D_, D_);
    wconv_kernel<<<dim3(768 / 32, D_ / 32, 1), dim3(32, 8), 0, stream>>>(Wqkv, qkvWt, D_, 768);
    wconv_kernel<<<dim3(D_ / 32, D_ / 32, 1), dim3(32, 8), 0, stream>>>(Wo, WoWt, D_, D_);
    wconv_kernel<<<dim3(HIDEF_ / 32, D_ / 32, 1), dim3(32, 8), 0, stream>>>(ff_W1, W1t, D_, HIDEF_);
    wconv_kernel<<<dim3(D_ / 32, HIDEF_ / 32, 1), dim3(32, 8), 0, stream>>>(ff_W2, W2t, HIDEF_, D_);
    wconv_kernel<<<dim3(PYOUT_ / 32, D_ / 32, LEVELS_), dim3(32, 8), 0, stream>>>(pyr_W, pyrWt, D_, PYOUT_);
    tobf16_kernel<<<(ROWS_ * D_ + 255) / 256, 256, 0, stream>>>(x_in, Xb, ROWS_ * D_);

    for (int it = 0; it < 5; it++) {
        bgemm_kernel<0, true, false, false, false, 64><<<dim3(4, 64), 256, 0, stream>>>(
            Xb, patchWt, patch_b, nullptr, T, nullptr, ROWS_, D_, D_, 0, nullptr);
        ln_pos_kernel<<<ROWS_ / 4, 256, 0, stream>>>(T, ln_g, ln_b, POS, H, Hb);
        bgemm_kernel<1, false, true, false, false, 128><<<dim3(8, 64), 256, 0, stream>>>(
            Hb, W1t, ff_b1, nullptr, nullptr, MIDb, ROWS_, HIDEF_, D_, 0, nullptr);
        bgemm_kernel<0, false, true, false, false, 64><<<dim3(4, 64), 256, 0, stream>>>(
            MIDb, W2t, ff_b2, nullptr, nullptr, Tb, ROWS_, D_, HIDEF_, 0, nullptr);
        bgemm_kernel<0, false, true, false, false, 128><<<dim3(6, 64), 256, 0, stream>>>(
            Tb, qkvWt, bqkv, nullptr, nullptr, QKVb, ROWS_, 768, D_, 0, nullptr);
        attn_kernel<<<dim3(4, HEADS_, B_), 256, 0, stream>>>(QKVb, ATb);
        bgemm_kernel<0, true, false, false, true, 64><<<dim3(4, 64), 256, 0, stream>>>(
            ATb, WoWt, bo, H, T, nullptr, ROWS_, D_, D_, 0, BNP);
        bn_finish_kernel<<<1, 256, 0, stream>>>(BNP, STATS);
        bn_apply_kernel<<<ROWS_ / 4, 256, 0, stream>>>(T, STATS, bn1_g, bn1_b, H, Hb);
        bgemm_kernel<1, false, true, false, false, 128><<<dim3(8, 64), 256, 0, stream>>>(
            Hb, W1t, ff_b1, nullptr, nullptr, MIDb, ROWS_, HIDEF_, D_, 0, nullptr);
        bgemm_kernel<0, true, false, false, true, 64><<<dim3(4, 64), 256, 0, stream>>>(
            MIDb, W2t, ff_b2, H, T, nullptr, ROWS_, D_, HIDEF_, 0, BNP);
        bn_finish_kernel<<<1, 256, 0, stream>>>(BNP, STATS);
        bn_apply_kernel<<<ROWS_ / 4, 256, 0, stream>>>(T, STATS, bn2_g, bn2_b, nullptr, Xb);
        bgemm_kernel<0, false, false, true, false, 64><<<dim3(128, 1), 256, 0, stream>>>(
            pyrWt + (size_t)it * D_ * PYOUT_, Xb, pyr_b + it * PYOUT_, nullptr,
            FLAT, nullptr, PYOUT_, ROWS_, D_, it, nullptr);
    }

    fcl_partial_kernel<<<FCL_CHUNKS, 256, 0, stream>>>(FLAT, fcl_W, PART);
    fcl_reduce_kernel<<<64, 256, 0, stream>>>(PART, fcl_b, ADD);
    head_kernel<<<1, 256, 0, stream>>>(ADD, addbn_g, addbn_b,
        cls_W1, cls_b1, cls_W2, cls_b2, box_W1, box_b1, box_W2, box_b2, out);
    (void)in_sizes; (void)n_in; (void)out_size; (void)ws_size;
}

// Round 6
// 1003.621 us; speedup vs baseline: 4.6239x; 1.0312x over previous
//
#include <hip/hip_runtime.h>
#include <hip/hip_bf16.h>
#include <math.h>

#define B_ 16
#define N_ 512
#define D_ 256
#define HEADS_ 8
#define DH_ 32
#define HIDEF_ 1024
#define NBLK_ 16
#define BS_ 32
#define LEVELS_ 5
#define PYOUT_ 128
#define ROWS_ (B_ * N_)   // 8192
#define FCL_K 327680
#define FCL_KB 256
#define FCL_CHUNKS 1280

typedef __attribute__((ext_vector_type(8))) short short8;
typedef __attribute__((ext_vector_type(4))) short short4v;
typedef __attribute__((ext_vector_type(4))) unsigned short ushort4v;
typedef __attribute__((ext_vector_type(4))) float f32x4;

__device__ __forceinline__ float bf2f(short u) {
    return __uint_as_float(((unsigned int)(unsigned short)u) << 16);
}
__device__ __forceinline__ unsigned short f2bf(float x) {
    __hip_bfloat16 h = __float2bfloat16(x);
    return *reinterpret_cast<unsigned short*>(&h);
}

// ---------------------------------------------------------------- position
__global__ void pos_kernel(float* __restrict__ pos) {
    int idx = blockIdx.x * 256 + threadIdx.x;
    if (idx >= N_ * D_) return;
    int n = idx >> 8, i = idx & 255;
    double angle = (double)n / pow(10000.0, (double)(2 * (i >> 1)) / 256.0);
    pos[idx] = (float)((i & 1) ? cos(angle) : sin(angle));
}

__device__ __forceinline__ float gelu_f(float x) {
    float x3 = x * x * x;
    return 0.5f * x * (1.f + tanhf(0.7978845608028654f * (x + 0.044715f * x3)));
}

// ---------------------------------------------------------------- converts
__global__ void tobf16_kernel(const float* __restrict__ x, __hip_bfloat16* __restrict__ y, int n) {
    int i = blockIdx.x * 256 + threadIdx.x;
    if (i < n) y[i] = __float2bfloat16(x[i]);
}

__global__ __launch_bounds__(256) void wconv_kernel(const float* __restrict__ W,
                                                    __hip_bfloat16* __restrict__ Wt,
                                                    int K, int N) {
    int z = blockIdx.z;
    const float* Wz = W + (size_t)z * K * N;
    __hip_bfloat16* Wtz = Wt + (size_t)z * K * N;
    __shared__ float t[32][33];
    int bx = blockIdx.x * 32, by = blockIdx.y * 32;
    int tx = threadIdx.x, ty = threadIdx.y;
#pragma unroll
    for (int i = 0; i < 32; i += 8)
        t[ty + i][tx] = Wz[(size_t)(by + ty + i) * N + bx + tx];
    __syncthreads();
#pragma unroll
    for (int i = 0; i < 32; i += 8)
        Wtz[(size_t)(bx + ty + i) * K + by + tx] = __float2bfloat16(t[tx][ty + i]);
}

// ---------------------------------------------------------------- bf16 MFMA GEMM
// BM=128, BK=32, BN in {64,128}. 4 waves. global_load_lds w16, chunk-XOR swizzle.
template <int ACT, bool OUTF, bool OUTB, bool SCAT, bool STATS, int BN>
__global__ __launch_bounds__(256) void bgemm_kernel(
    const __hip_bfloat16* __restrict__ A, const __hip_bfloat16* __restrict__ Wt,
    const float* __restrict__ bias, const float* __restrict__ resid,
    float* __restrict__ C, __hip_bfloat16* __restrict__ Cb, int M, int Nn, int K,
    int level, float* __restrict__ bnp) {
    __shared__ __hip_bfloat16 Alds[128 * 32];
    __shared__ __hip_bfloat16 Blds[BN * 32];
    constexpr int MW = (BN == 128) ? 4 : 2;
    constexpr int WH = (BN == 128) ? 64 : 32;
    constexpr int BR = BN / 64;
    int tid = threadIdx.x;
    int wid = tid >> 6, lane = tid & 63;
    int row0 = blockIdx.y * 128, col0 = blockIdx.x * BN;
    int wr = (BN == 128) ? (wid >> 1) : wid;
    int wc = (BN == 128) ? (wid & 1) : 0;
    int r16 = lane & 15, kq = lane >> 4;
    int rdoff = kq ^ ((r16 >> 1) & 3);

    f32x4 acc[MW][4];
#pragma unroll
    for (int m = 0; m < MW; m++)
#pragma unroll
        for (int n = 0; n < 4; n++) acc[m][n] = (f32x4){0.f, 0.f, 0.f, 0.f};

    for (int k0 = 0; k0 < K; k0 += 32) {
#pragma unroll
        for (int i = 0; i < 2; i++) {
            int slot = i * 256 + tid;
            int row = slot >> 2, qp = slot & 3;
            int q = qp ^ ((row >> 1) & 3);
            const __hip_bfloat16* ga = A + (size_t)(row0 + row) * K + k0 + q * 8;
            __builtin_amdgcn_global_load_lds(
                (const __attribute__((address_space(1))) void*)ga,
                (__attribute__((address_space(3))) void*)((char*)Alds + i * 4096 + wid * 1024),
                16, 0, 0);
        }
#pragma unroll
        for (int i = 0; i < BR; i++) {
            int slot = i * 256 + tid;
            int row = slot >> 2, qp = slot & 3;
            int q = qp ^ ((row >> 1) & 3);
            const __hip_bfloat16* gb = Wt + (size_t)(col0 + row) * K + k0 + q * 8;
            __builtin_amdgcn_global_load_lds(
                (const __attribute__((address_space(1))) void*)gb,
                (__attribute__((address_space(3))) void*)((char*)Blds + i * 4096 + wid * 1024),
                16, 0, 0);
        }
        __syncthreads();
        short8 af[MW], bf[4];
#pragma unroll
        for (int m = 0; m < MW; m++) {
            int row = wr * WH + m * 16 + r16;
            af[m] = *reinterpret_cast<const short8*>(
                reinterpret_cast<const char*>(Alds) + row * 64 + rdoff * 16);
        }
#pragma unroll
        for (int n = 0; n < 4; n++) {
            int row = wc * 64 + n * 16 + r16;
            bf[n] = *reinterpret_cast<const short8*>(
                reinterpret_cast<const char*>(Blds) + row * 64 + rdoff * 16);
        }
#pragma unroll
        for (int m = 0; m < MW; m++)
#pragma unroll
            for (int n = 0; n < 4; n++)
                acc[m][n] = __builtin_amdgcn_mfma_f32_16x16x32_bf16(af[m], bf[n], acc[m][n], 0, 0, 0);
        __syncthreads();
    }

    int rg = lane >> 4;
    float s1a[4] = {0.f, 0.f, 0.f, 0.f}, s2a[4] = {0.f, 0.f, 0.f, 0.f};
    if (SCAT) {
#pragma unroll
        for (int n = 0; n < 4; n++) {
            int cc = col0 + wc * 64 + n * 16 + r16;
            int bb = cc >> 9, nn = cc & 511;
            float* dst = C + (size_t)bb * (LEVELS_ * PYOUT_ * N_) +
                         (size_t)level * PYOUT_ * N_ + nn;
#pragma unroll
            for (int m = 0; m < MW; m++) {
                int rbase = wr * WH + m * 16 + rg * 4;
#pragma unroll
                for (int j = 0; j < 4; j++) {
                    int ch = rbase + j;
                    dst[(size_t)ch * N_] = acc[m][n][j] + bias[ch];
                }
            }
        }
    } else {
#pragma unroll
        for (int n = 0; n < 4; n++) {
            int cc = col0 + wc * 64 + n * 16 + r16;
            float bv = bias[cc];
#pragma unroll
            for (int m = 0; m < MW; m++) {
                int rb = row0 + wr * WH + m * 16 + rg * 4;
#pragma unroll
                for (int j = 0; j < 4; j++) {
                    int r = rb + j;
                    float v = acc[m][n][j] + bv;
                    if (resid) v += resid[(size_t)r * Nn + cc];
                    if (ACT == 1) v = gelu_f(v);
                    if (OUTF) C[(size_t)r * Nn + cc] = v;
                    if (OUTB) Cb[(size_t)r * Nn + cc] = __float2bfloat16(v);
                    if (STATS) { s1a[n] += v; s2a[n] += v * v; }
                }
            }
        }
    }
    if (STATS) {
        float* sc = (float*)Alds;
        int part = wid * 4 + rg;
#pragma unroll
        for (int n = 0; n < 4; n++) {
            int c = wc * 64 + n * 16 + r16;
            sc[c * 16 + part] = s1a[n];
            sc[1024 + c * 16 + part] = s2a[n];
        }
        __syncthreads();
        if (tid < BN) {
            float a = 0.f, b2 = 0.f;
#pragma unroll
            for (int p = 0; p < 16; p++) {
                a += sc[tid * 16 + p];
                b2 += sc[1024 + tid * 16 + p];
            }
            bnp[blockIdx.y * 256 + col0 + tid] = a;
            bnp[16384 + blockIdx.y * 256 + col0 + tid] = b2;
        }
    }
}

// ---------------------------------------------------------------- fused patch GEMM + LN + pos
// Block = 32 rows x full 256 cols, K=256. 4 waves (wave = 64-col group).
__global__ __launch_bounds__(256) void patchln_kernel(
    const __hip_bfloat16* __restrict__ A, const __hip_bfloat16* __restrict__ Wt,
    const float* __restrict__ bias, const float* __restrict__ lng,
    const float* __restrict__ lnb, const float* __restrict__ pos,
    float* __restrict__ H, __hip_bfloat16* __restrict__ Hb) {
    __shared__ char __attribute__((aligned(16))) smem[33280];   // Cls[32][260] f32
    __hip_bfloat16* Alds = (__hip_bfloat16*)smem;               // 2 KB
    __hip_bfloat16* Blds = (__hip_bfloat16*)(smem + 2048);      // 16 KB
    float (*Cls)[260] = (float(*)[260])smem;
    int tid = threadIdx.x;
    int wid = tid >> 6, lane = tid & 63;
    int row0 = blockIdx.x * 32;
    int r16 = lane & 15, kq = lane >> 4, g = lane >> 4;
    int rdoff = kq ^ ((r16 >> 1) & 3);

    f32x4 acc[2][4];
#pragma unroll
    for (int m = 0; m < 2; m++)
#pragma unroll
        for (int n = 0; n < 4; n++) acc[m][n] = (f32x4){0.f, 0.f, 0.f, 0.f};

    for (int k0 = 0; k0 < 256; k0 += 32) {
        if (tid < 128) {       // A: 32x32 bf16 = 2 KB, waves 0-1
            int row = tid >> 2, qp = tid & 3;
            int q = qp ^ ((row >> 1) & 3);
            const __hip_bfloat16* ga = A + (size_t)(row0 + row) * 256 + k0 + q * 8;
            __builtin_amdgcn_global_load_lds(
                (const __attribute__((address_space(1))) void*)ga,
                (__attribute__((address_space(3))) void*)((char*)Alds + wid * 1024),
                16, 0, 0);
        }
#pragma unroll
        for (int i = 0; i < 4; i++) {  // B: 256x32 = 16 KB
            int slot = i * 256 + tid;
            int row = slot >> 2, qp = slot & 3;
            int q = qp ^ ((row >> 1) & 3);
            const __hip_bfloat16* gb = Wt + (size_t)row * 256 + k0 + q * 8;
            __builtin_amdgcn_global_load_lds(
                (const __attribute__((address_space(1))) void*)gb,
                (__attribute__((address_space(3))) void*)((char*)Blds + i * 4096 + wid * 1024),
                16, 0, 0);
        }
        __syncthreads();
        short8 af[2], bf[4];
#pragma unroll
        for (int m = 0; m < 2; m++) {
            int row = m * 16 + r16;
            af[m] = *reinterpret_cast<const short8*>(
                reinterpret_cast<const char*>(Alds) + row * 64 + rdoff * 16);
        }
#pragma unroll
        for (int n = 0; n < 4; n++) {
            int row = wid * 64 + n * 16 + r16;
            bf[n] = *reinterpret_cast<const short8*>(
                reinterpret_cast<const char*>(Blds) + row * 64 + rdoff * 16);
        }
#pragma unroll
        for (int m = 0; m < 2; m++)
#pragma unroll
            for (int n = 0; n < 4; n++)
                acc[m][n] = __builtin_amdgcn_mfma_f32_16x16x32_bf16(af[m], bf[n], acc[m][n], 0, 0, 0);
        __syncthreads();
    }
    // write C tile (+bias) to LDS (staging buffers dead now)
#pragma unroll
    for (int n = 0; n < 4; n++) {
        int col = wid * 64 + n * 16 + r16;
        float bv = bias[col];
#pragma unroll
        for (int m = 0; m < 2; m++)
#pragma unroll
            for (int j = 0; j < 4; j++)
                Cls[m * 16 + g * 4 + j][col] = acc[m][n][j] + bv;
    }
    __syncthreads();
    // LN + pos: wave wid handles rows wid*8 .. wid*8+7
    float4 g4 = ((const float4*)lng)[lane];
    float4 b4 = ((const float4*)lnb)[lane];
#pragma unroll
    for (int rr = 0; rr < 8; rr++) {
        int r = wid * 8 + rr;
        float4 v = *(const float4*)&Cls[r][lane * 4];
        float s = v.x + v.y + v.z + v.w;
#pragma unroll
        for (int mk = 32; mk; mk >>= 1) s += __shfl_xor(s, mk);
        float mean = s * (1.f / 256.f);
        float dx = v.x - mean, dy = v.y - mean, dz = v.z - mean, dw = v.w - mean;
        float q = dx * dx + dy * dy + dz * dz + dw * dw;
#pragma unroll
        for (int mk = 32; mk; mk >>= 1) q += __shfl_xor(q, mk);
        float rstd = rsqrtf(q * (1.f / 256.f) + 1e-5f);
        int grow = row0 + r;
        float4 p4 = ((const float4*)pos)[(size_t)(grow & (N_ - 1)) * 64 + lane];
        float o0 = dx * rstd * g4.x + b4.x + p4.x;
        float o1 = dy * rstd * g4.y + b4.y + p4.y;
        float o2 = dz * rstd * g4.z + b4.z + p4.z;
        float o3 = dw * rstd * g4.w + b4.w + p4.w;
        ((float4*)(H + (size_t)grow * D_))[lane] = (float4){o0, o1, o2, o3};
        ushort4v u = {f2bf(o0), f2bf(o1), f2bf(o2), f2bf(o3)};
        *((ushort4v*)(Hb + (size_t)grow * D_) + lane) = u;
    }
}

// ---------------------------------------------------------------- BN finish+apply merged
__global__ __launch_bounds__(256) void bn_applyfin_kernel(
    const float* __restrict__ x, const float* __restrict__ bnp,
    const float* __restrict__ g, const float* __restrict__ b,
    float* __restrict__ y, __hip_bfloat16* __restrict__ yb) {
    int tid = threadIdx.x;
    __shared__ float sm[256], sv[256];
    {
        float s = 0.f, s2 = 0.f;
#pragma unroll 4
        for (int yy = 0; yy < 64; yy++) {
            s += bnp[yy * 256 + tid];
            s2 += bnp[16384 + yy * 256 + tid];
        }
        float m = s * (1.f / 8192.f);
        sm[tid] = m;
        sv[tid] = rsqrtf(s2 * (1.f / 8192.f) - m * m + 1e-5f);
    }
    __syncthreads();
    int lane = tid & 63, w = tid >> 6;
    int row0 = blockIdx.x * 32;
    float4 m4 = *(const float4*)&sm[lane * 4];
    float4 r4 = *(const float4*)&sv[lane * 4];
    float4 g4 = ((const float4*)g)[lane];
    float4 b4 = ((const float4*)b)[lane];
#pragma unroll
    for (int rr = 0; rr < 8; rr++) {
        int row = row0 + w * 8 + rr;
        float4 x4 = ((const float4*)(x + (size_t)row * D_))[lane];
        float o0 = (x4.x - m4.x) * r4.x * g4.x + b4.x;
        float o1 = (x4.y - m4.y) * r4.y * g4.y + b4.y;
        float o2 = (x4.z - m4.z) * r4.z * g4.z + b4.z;
        float o3 = (x4.w - m4.w) * r4.w * g4.w + b4.w;
        if (y) ((float4*)(y + (size_t)row * D_))[lane] = (float4){o0, o1, o2, o3};
        if (yb) {
            ushort4v u = {f2bf(o0), f2bf(o1), f2bf(o2), f2bf(o3)};
            *((ushort4v*)(yb + (size_t)row * D_) + lane) = u;
        }
    }
}

// ---------------------------------------------------------------- MFMA attention
__global__ __launch_bounds__(256) void attn_kernel(
    const __hip_bfloat16* __restrict__ qkv, __hip_bfloat16* __restrict__ outb) {
    int bx = blockIdx.x, h = blockIdx.y, b = blockIdx.z;
    int tid = threadIdx.x;
    int wid = tid >> 6, lane = tid & 63;
    __shared__ __hip_bfloat16 Klds[256 * 32];
    __shared__ __hip_bfloat16 Vt[32 * 264];
    const short* q16 = (const short*)qkv;

#pragma unroll
    for (int r = 0; r < 4; r++) {
        int slot = r * 256 + tid;
        int row = slot >> 2, qp = slot & 3;
        int ql = qp ^ ((row >> 1) & 3);
        int jb = bx * 4 - 2 + (row >> 5);
        jb = jb < 0 ? 0 : (jb > 15 ? 15 : jb);
        const short* ga = q16 + ((size_t)(b * N_ + jb * 32 + (row & 31))) * 768 + 256 + h * 32 + ql * 8;
        __builtin_amdgcn_global_load_lds(
            (const __attribute__((address_space(1))) void*)ga,
            (__attribute__((address_space(3))) void*)((char*)Klds + r * 4096 + wid * 1024),
            16, 0, 0);
    }
    {
        int row = tid;
        int jb = bx * 4 - 2 + (row >> 5);
        jb = jb < 0 ? 0 : (jb > 15 ? 15 : jb);
        const short* gv = q16 + ((size_t)(b * N_ + jb * 32 + (row & 31))) * 768 + 512 + h * 32;
        short8 v0 = *(const short8*)(gv);
        short8 v1 = *(const short8*)(gv + 8);
        short8 v2 = *(const short8*)(gv + 16);
        short8 v3 = *(const short8*)(gv + 24);
        short* vt = (short*)Vt;
#pragma unroll
        for (int e = 0; e < 8; e++) {
            vt[(e) * 264 + row] = v0[e];
            vt[(8 + e) * 264 + row] = v1[e];
            vt[(16 + e) * 264 + row] = v2[e];
            vt[(24 + e) * 264 + row] = v3[e];
        }
    }
    __syncthreads();

    int i = bx * 4 + wid;
    int c = lane & 15, g = lane >> 4;
    const float scale = 0.17677669529663687f;

#pragma unroll
    for (int qt = 0; qt < 2; qt++) {
        const short* qa = q16 + ((size_t)(b * N_ + i * 32 + qt * 16 + c)) * 768 + h * 32 + g * 8;
        short8 bq = *(const short8*)qa;
        f32x4 st[10];
#pragma unroll
        for (int t = 0; t < 10; t++) {
            int jb = i - 2 + (t >> 1);
            if (jb >= 0 && jb < NBLK_) {
                int row = wid * 32 + t * 16 + c;
                int phys = g ^ ((row >> 1) & 3);
                short8 ak = *(const short8*)((const char*)Klds + row * 64 + phys * 16);
                st[t] = __builtin_amdgcn_mfma_f32_16x16x32_bf16(
                    ak, bq, (f32x4){0.f, 0.f, 0.f, 0.f}, 0, 0, 0);
            }
        }
        float mx = -1e30f;
#pragma unroll
        for (int t = 0; t < 10; t++) {
            int jb = i - 2 + (t >> 1);
            if (jb >= 0 && jb < NBLK_) {
#pragma unroll
                for (int j = 0; j < 4; j++) {
                    st[t][j] *= scale;
                    mx = fmaxf(mx, st[t][j]);
                }
            }
        }
        mx = fmaxf(mx, __shfl_xor(mx, 16));
        mx = fmaxf(mx, __shfl_xor(mx, 32));
        float sum = 0.f;
#pragma unroll
        for (int t = 0; t < 10; t++) {
            int jb = i - 2 + (t >> 1);
            if (jb >= 0 && jb < NBLK_) {
#pragma unroll
                for (int j = 0; j < 4; j++) {
                    float e = __expf(st[t][j] - mx);
                    st[t][j] = e;
                    sum += e;
                }
            }
        }
        sum += __shfl_xor(sum, 16);
        sum += __shfl_xor(sum, 32);
        float inv = 1.f / sum;
        f32x4 o0 = (f32x4){0.f, 0.f, 0.f, 0.f};
        f32x4 o1 = (f32x4){0.f, 0.f, 0.f, 0.f};
        const short* vt = (const short*)Vt;
#pragma unroll
        for (int t = 0; t < 10; t++) {
            int jb = i - 2 + (t >> 1);
            if (jb >= 0 && jb < NBLK_) {
                short8 pa = (short8)0;
#pragma unroll
                for (int j = 0; j < 4; j++) pa[j] = (short)f2bf(st[t][j] * inv);
                int kb = wid * 32 + t * 16 + g * 4;
                short4v vb0 = *(const short4v*)(vt + (0 * 16 + c) * 264 + kb);
                short4v vb1 = *(const short4v*)(vt + (1 * 16 + c) * 264 + kb);
                short8 b0 = (short8)0, b1 = (short8)0;
#pragma unroll
                for (int e = 0; e < 4; e++) { b0[e] = vb0[e]; b1[e] = vb1[e]; }
                o0 = __builtin_amdgcn_mfma_f32_16x16x32_bf16(pa, b0, o0, 0, 0, 0);
                o1 = __builtin_amdgcn_mfma_f32_16x16x32_bf16(pa, b1, o1, 0, 0, 0);
            }
        }
#pragma unroll
        for (int j = 0; j < 4; j++) {
            size_t rbase = ((size_t)(b * N_ + i * 32 + qt * 16 + g * 4 + j)) * D_ + h * DH_;
            outb[rbase + c] = __float2bfloat16(o0[j]);
            outb[rbase + 16 + c] = __float2bfloat16(o1[j]);
        }
    }
}

// ---------------------------------------------------------------- fcl
// thread = (j = tid&127, bg = tid>>7 -> batches bg*8..bg*8+7); scalar W loads,
// wave-uniform LDS broadcasts; W re-read 2x (L1/L2-served).
__global__ __launch_bounds__(256) void fcl_partial_kernel(
    const float* __restrict__ flat, const float* __restrict__ W,
    float* __restrict__ partial) {
    int chunk = blockIdx.x;             // 1280
    int t = threadIdx.x;
    int k0 = chunk * FCL_KB;
    __shared__ float fl[FCL_KB][20];    // [k][b], 16-aligned rows
#pragma unroll
    for (int b = 0; b < 16; b++)
        fl[t][b] = flat[(size_t)b * FCL_K + k0 + t];
    __syncthreads();
    int j = t & 127, bg = t >> 7;
    f32x4 a0 = (f32x4){0.f, 0.f, 0.f, 0.f};
    f32x4 a1 = (f32x4){0.f, 0.f, 0.f, 0.f};
#pragma unroll 8
    for (int k = 0; k < FCL_KB; k++) {
        float w = W[(size_t)(k0 + k) * 128 + j];
        f32x4 f0 = *(const f32x4*)&fl[k][bg * 8];
        f32x4 f1 = *(const f32x4*)&fl[k][bg * 8 + 4];
        a0 += f0 * w;
        a1 += f1 * w;
    }
#pragma unroll
    for (int bi = 0; bi < 4; bi++) {
        partial[((size_t)chunk * 16 + bg * 8 + bi) * 128 + j] = a0[bi];
        partial[((size_t)chunk * 16 + bg * 8 + 4 + bi) * 128 + j] = a1[bi];
    }
}

__global__ __launch_bounds__(256) void fcl_reduce_kernel(
    const float* __restrict__ partial, const float* __restrict__ fcl_b,
    float* __restrict__ add) {
    int c0 = blockIdx.x * 32;
    int t = threadIdx.x;
    int ry = t >> 5, cx = t & 31;
    float s = 0.f;
    for (int r = ry; r < FCL_CHUNKS; r += 8)
        s += partial[(size_t)r * 2048 + c0 + cx];
    __shared__ float red[8][32];
    red[ry][cx] = s; __syncthreads();
    if (ry == 0) {
        float tot = 0.f;
#pragma unroll
        for (int q = 0; q < 8; q++) tot += red[q][cx];
        int col = c0 + cx;
        add[col] = tot + fcl_b[col & 127];
    }
}

// ---------------------------------------------------------------- fused head
__global__ __launch_bounds__(256) void head_kernel(
    const float* __restrict__ add, const float* __restrict__ abg, const float* __restrict__ abb,
    const float* __restrict__ cls_W1, const float* __restrict__ cls_b1,
    const float* __restrict__ cls_W2, const float* __restrict__ cls_b2,
    const float* __restrict__ box_W1, const float* __restrict__ box_b1,
    const float* __restrict__ box_W2, const float* __restrict__ box_b2,
    float* __restrict__ out) {
    __shared__ float a2[16][128];
    __shared__ float cm[16][256];
    __shared__ float cls[16][45];
    __shared__ float bmid[16][128];
    __shared__ float smden[16];
    int t = threadIdx.x;
    if (t < 128) {
        float m = 0.f;
#pragma unroll
        for (int b = 0; b < 16; b++) m += add[b * 128 + t];
        m *= (1.f / 16.f);
        float v = 0.f;
#pragma unroll
        for (int b = 0; b < 16; b++) { float d = add[b * 128 + t] - m; v += d * d; }
        v *= (1.f / 16.f);
        float sc = rsqrtf(v + 1e-5f) * abg[t];
#pragma unroll
        for (int b = 0; b < 16; b++) a2[b][t] = (add[b * 128 + t] - m) * sc + abb[t];
    }
    __syncthreads();
    for (int idx = t; idx < 4096; idx += 256) {
        int m = idx >> 8, c = idx & 255;
        float a = cls_b1[c];
        for (int k = 0; k < 128; k++) a += a2[m][k] * cls_W1[k * 256 + c];
        cm[m][c] = fmaxf(a, 0.f);
    }
    for (int idx = t; idx < 2048; idx += 256) {
        int m = idx >> 7, c = idx & 127;
        float a = box_b1[c];
        for (int k = 0; k < 128; k++) a += a2[m][k] * box_W1[k * 128 + c];
        bmid[m][c] = fmaxf(a, 0.f);
    }
    __syncthreads();
    for (int idx = t; idx < 720; idx += 256) {
        int m = idx / 45, c = idx % 45;
        float a = cls_b2[c];
        for (int k = 0; k < 256; k++) a += cm[m][k] * cls_W2[k * 45 + c];
        cls[m][c] = a;
    }
    __syncthreads();
    if (t < 16) {
        float mx = -1e30f;
        for (int c = 0; c < 45; c++) mx = fmaxf(mx, cls[t][c]);
        float s = 0.f;
        for (int c = 0; c < 45; c++) { float e = expf(cls[t][c] - mx); cls[t][c] = e; s += e; }
        smden[t] = s;
    }
    for (int idx = t; idx < 576; idx += 256) {
        int m = idx / 36, c = idx % 36;
        float a = box_b2[c];
        for (int k = 0; k < 128; k++) a += bmid[m][k] * box_W2[k * 36 + c];
        out[m * 81 + (c >> 2) * 9 + 5 + (c & 3)] = a;
    }
    __syncthreads();
    for (int idx = t; idx < 720; idx += 256) {
        int m = idx / 45, c = idx % 45;
        out[m * 81 + (c / 5) * 9 + (c % 5)] = cls[m][c] / smden[m];
    }
}

// ================================================================ launcher
extern "C" void kernel_launch(void* const* d_in, const int* in_sizes, int n_in,
                              void* d_out, int out_size, void* d_ws, size_t ws_size,
                              hipStream_t stream) {
    const float* x_in    = (const float*)d_in[0];
    const float* patch_W = (const float*)d_in[1];
    const float* patch_b = (const float*)d_in[2];
    const float* ln_g    = (const float*)d_in[3];
    const float* ln_b    = (const float*)d_in[4];
    const float* ff_W1   = (const float*)d_in[5];
    const float* ff_b1   = (const float*)d_in[6];
    const float* ff_W2   = (const float*)d_in[7];
    const float* ff_b2   = (const float*)d_in[8];
    const float* Wqkv    = (const float*)d_in[9];
    const float* bqkv    = (const float*)d_in[10];
    const float* Wo      = (const float*)d_in[11];
    const float* bo      = (const float*)d_in[12];
    const float* bn1_g   = (const float*)d_in[13];
    const float* bn1_b   = (const float*)d_in[14];
    const float* bn2_g   = (const float*)d_in[15];
    const float* bn2_b   = (const float*)d_in[16];
    const float* pyr_W   = (const float*)d_in[17];
    const float* pyr_b   = (const float*)d_in[18];
    const float* fcl_W   = (const float*)d_in[19];
    const float* fcl_b   = (const float*)d_in[20];
    const float* addbn_g = (const float*)d_in[21];
    const float* addbn_b = (const float*)d_in[22];
    const float* cls_W1  = (const float*)d_in[23];
    const float* cls_b1  = (const float*)d_in[24];
    const float* cls_W2  = (const float*)d_in[25];
    const float* cls_b2  = (const float*)d_in[26];
    const float* box_W1  = (const float*)d_in[27];
    const float* box_b1  = (const float*)d_in[28];
    const float* box_W2  = (const float*)d_in[29];
    const float* box_b2  = (const float*)d_in[30];
    float* out = (float*)d_out;

    float* ws = (float*)d_ws;
    size_t off = 0;
    float* POS   = ws + off; off += 131072;
    float* H     = ws + off; off += 2097152;
    float* T     = ws + off; off += 2097152;
    float* UNION = ws + off; off += 4194304;   // MIDb bf16 / QKVb bf16
    float* FLAT  = ws + off; off += 5242880;
    float* PART  = ws + off; off += (size_t)FCL_CHUNKS * 2048;
    float* STATS = ws + off; off += 512;
    float* BNP   = ws + off; off += 2 * 64 * 256;
    float* ADD   = ws + off; off += 2048;
    __hip_bfloat16* Hb   = (__hip_bfloat16*)(ws + off); off += 1048576;
    __hip_bfloat16* Tb   = (__hip_bfloat16*)(ws + off); off += 1048576;
    __hip_bfloat16* Xb   = (__hip_bfloat16*)(ws + off); off += 1048576;
    __hip_bfloat16* ATb  = (__hip_bfloat16*)(ws + off); off += 1048576;
    __hip_bfloat16* patchWt = (__hip_bfloat16*)(ws + off); off += 32768;
    __hip_bfloat16* qkvWt   = (__hip_bfloat16*)(ws + off); off += 98304;
    __hip_bfloat16* WoWt    = (__hip_bfloat16*)(ws + off); off += 32768;
    __hip_bfloat16* W1t     = (__hip_bfloat16*)(ws + off); off += 131072;
    __hip_bfloat16* W2t     = (__hip_bfloat16*)(ws + off); off += 131072;
    __hip_bfloat16* pyrWt   = (__hip_bfloat16*)(ws + off); off += 81920;
    __hip_bfloat16* MIDb = (__hip_bfloat16*)UNION;
    __hip_bfloat16* QKVb = (__hip_bfloat16*)UNION;
    (void)STATS;

    pos_kernel<<<(N_ * D_ + 255) / 256, 256, 0, stream>>>(POS);
    wconv_kernel<<<dim3(D_ / 32, D_ / 32, 1), dim3(32, 8), 0, stream>>>(patch_W, patchWt, D_, D_);
    wconv_kernel<<<dim3(768 / 32, D_ / 32, 1), dim3(32, 8), 0, stream>>>(Wqkv, qkvWt, D_, 768);
    wconv_kernel<<<dim3(D_ / 32, D_ / 32, 1), dim3(32, 8), 0, stream>>>(Wo, WoWt, D_, D_);
    wconv_kernel<<<dim3(HIDEF_ / 32, D_ / 32, 1), dim3(32, 8), 0, stream>>>(ff_W1, W1t, D_, HIDEF_);
    wconv_kernel<<<dim3(D_ / 32, HIDEF_ / 32, 1), dim3(32, 8), 0, stream>>>(ff_W2, W2t, HIDEF_, D_);
    wconv_kernel<<<dim3(PYOUT_ / 32, D_ / 32, LEVELS_), dim3(32, 8), 0, stream>>>(pyr_W, pyrWt, D_, PYOUT_);
    tobf16_kernel<<<(ROWS_ * D_ + 255) / 256, 256, 0, stream>>>(x_in, Xb, ROWS_ * D_);

    for (int it = 0; it < 5; it++) {
        patchln_kernel<<<256, 256, 0, stream>>>(Xb, patchWt, patch_b, ln_g, ln_b, POS, H, Hb);
        bgemm_kernel<1, false, true, false, false, 128><<<dim3(8, 64), 256, 0, stream>>>(
            Hb, W1t, ff_b1, nullptr, nullptr, MIDb, ROWS_, HIDEF_, D_, 0, nullptr);
        bgemm_kernel<0, false, true, false, false, 64><<<dim3(4, 64), 256, 0, stream>>>(
            MIDb, W2t, ff_b2, nullptr, nullptr, Tb, ROWS_, D_, HIDEF_, 0, nullptr);
        bgemm_kernel<0, false, true, false, false, 128><<<dim3(6, 64), 256, 0, stream>>>(
            Tb, qkvWt, bqkv, nullptr, nullptr, QKVb, ROWS_, 768, D_, 0, nullptr);
        attn_kernel<<<dim3(4, HEADS_, B_), 256, 0, stream>>>(QKVb, ATb);
        bgemm_kernel<0, true, false, false, true, 64><<<dim3(4, 64), 256, 0, stream>>>(
            ATb, WoWt, bo, H, T, nullptr, ROWS_, D_, D_, 0, BNP);
        bn_applyfin_kernel<<<256, 256, 0, stream>>>(T, BNP, bn1_g, bn1_b, H, Hb);
        bgemm_kernel<1, false, true, false, false, 128><<<dim3(8, 64), 256, 0, stream>>>(
            Hb, W1t, ff_b1, nullptr, nullptr, MIDb, ROWS_, HIDEF_, D_, 0, nullptr);
        bgemm_kernel<0, true, false, false, true, 64><<<dim3(4, 64), 256, 0, stream>>>(
            MIDb, W2t, ff_b2, H, T, nullptr, ROWS_, D_, HIDEF_, 0, BNP);
        bn_applyfin_kernel<<<256, 256, 0, stream>>>(T, BNP, bn2_g, bn2_b, nullptr, Xb);
        bgemm_kernel<0, false, false, true, false, 64><<<dim3(128, 1), 256, 0, stream>>>(
            pyrWt + (size_t)it * D_ * PYOUT_, Xb, pyr_b + it * PYOUT_, nullptr,
            FLAT, nullptr, PYOUT_, ROWS_, D_, it, nullptr);
    }

    fcl_partial_kernel<<<FCL_CHUNKS, 256, 0, stream>>>(FLAT, fcl_W, PART);
    fcl_reduce_kernel<<<64, 256, 0, stream>>>(PART, fcl_b, ADD);
    head_kernel<<<1, 256, 0, stream>>>(ADD, addbn_g, addbn_b,
        cls_W1, cls_b1, cls_W2, cls_b2, box_W1, box_b1, box_W2, box_b2, out);
    (void)in_sizes; (void)n_in; (void)out_size; (void)ws_size;
}

// Round 7
// 972.233 us; speedup vs baseline: 4.7732x; 1.0323x over previous
//
#include <hip/hip_runtime.h>
#include <hip/hip_bf16.h>
#include <math.h>

#define B_ 16
#define N_ 512
#define D_ 256
#define HEADS_ 8
#define DH_ 32
#define HIDEF_ 1024
#define NBLK_ 16
#define BS_ 32
#define LEVELS_ 5
#define PYOUT_ 128
#define ROWS_ (B_ * N_)   // 8192
#define FCL_K 327680
#define FCL_KB 256
#define FCL_CHUNKS 1280

typedef __attribute__((ext_vector_type(8))) short short8;
typedef __attribute__((ext_vector_type(4))) short short4v;
typedef __attribute__((ext_vector_type(4))) unsigned short ushort4v;
typedef __attribute__((ext_vector_type(4))) float f32x4;

__device__ __forceinline__ float bf2f(short u) {
    return __uint_as_float(((unsigned int)(unsigned short)u) << 16);
}
__device__ __forceinline__ unsigned short f2bf(float x) {
    __hip_bfloat16 h = __float2bfloat16(x);
    return *reinterpret_cast<unsigned short*>(&h);
}

__device__ __forceinline__ float gelu_f(float x) {
    float x3 = x * x * x;
    return 0.5f * x * (1.f + tanhf(0.7978845608028654f * (x + 0.044715f * x3)));
}

// ---------------------------------------------------------------- combined prep
// blocks: [0,64) patch | [64,256) qkv | [256,320) Wo | [320,576) W1 |
// [576,832) W2 | [832,992) pyr | [992,1504) pos | [1504,2528) x->bf16
__global__ __launch_bounds__(256) void prep_kernel(
    const float* __restrict__ patch_W, const float* __restrict__ Wqkv,
    const float* __restrict__ Wo, const float* __restrict__ ff_W1,
    const float* __restrict__ ff_W2, const float* __restrict__ pyr_W,
    const float* __restrict__ x_in,
    __hip_bfloat16* __restrict__ patchWt, __hip_bfloat16* __restrict__ qkvWt,
    __hip_bfloat16* __restrict__ WoWt, __hip_bfloat16* __restrict__ W1t,
    __hip_bfloat16* __restrict__ W2t, __hip_bfloat16* __restrict__ pyrWt,
    float* __restrict__ pos, __hip_bfloat16* __restrict__ Xb) {
    __shared__ float tt[32][33];
    int bid = blockIdx.x, t = threadIdx.x;
    if (bid >= 1504) {           // x -> bf16, 2048 elems/block
        int base = (bid - 1504) * 2048 + t * 8;
        float4 a = *(const float4*)&x_in[base];
        float4 b = *(const float4*)&x_in[base + 4];
        ushort4v u0 = {f2bf(a.x), f2bf(a.y), f2bf(a.z), f2bf(a.w)};
        ushort4v u1 = {f2bf(b.x), f2bf(b.y), f2bf(b.z), f2bf(b.w)};
        *(ushort4v*)((short*)Xb + base) = u0;
        *(ushort4v*)((short*)Xb + base + 4) = u1;
        return;
    }
    if (bid >= 992) {            // pos table
        int idx = (bid - 992) * 256 + t;
        int n = idx >> 8, i = idx & 255;
        double angle = (double)n / pow(10000.0, (double)(2 * (i >> 1)) / 256.0);
        pos[idx] = (float)((i & 1) ? cos(angle) : sin(angle));
        return;
    }
    const float* W; __hip_bfloat16* Wt; int K, N, bx, by;
    if (bid < 64)       { W = patch_W; Wt = patchWt; K = 256; N = 256; bx = bid % 8; by = bid / 8; }
    else if (bid < 256) { int l = bid - 64;  W = Wqkv;  Wt = qkvWt; K = 256; N = 768;  bx = l % 24; by = l / 24; }
    else if (bid < 320) { int l = bid - 256; W = Wo;    Wt = WoWt;  K = 256; N = 256;  bx = l % 8;  by = l / 8; }
    else if (bid < 576) { int l = bid - 320; W = ff_W1; Wt = W1t;   K = 256; N = 1024; bx = l % 32; by = l / 32; }
    else if (bid < 832) { int l = bid - 576; W = ff_W2; Wt = W2t;   K = 1024; N = 256; bx = l % 8;  by = l / 32 * 4 + (l / 8) % 4; }
    else                { int l = bid - 832; int z = l / 32; int r = l % 32;
                          W = pyr_W + (size_t)z * 256 * 128; Wt = pyrWt + (size_t)z * 256 * 128;
                          K = 256; N = 128; bx = r % 4; by = r / 4; }
    // W2 by-fix: need by in [0,32); recompute simply
    if (bid >= 576 && bid < 832) { int l = bid - 576; bx = l % 8; by = l / 8; }
    int bx32 = bx * 32, by32 = by * 32;
    int tx = t & 31, ty = t >> 5;
#pragma unroll
    for (int i = 0; i < 32; i += 8)
        tt[ty + i][tx] = W[(size_t)(by32 + ty + i) * N + bx32 + tx];
    __syncthreads();
#pragma unroll
    for (int i = 0; i < 32; i += 8)
        Wt[(size_t)(bx32 + ty + i) * K + by32 + tx] = __float2bfloat16(tt[tx][ty + i]);
}

// ---------------------------------------------------------------- bf16 MFMA GEMM
// BM=128, BK=64 (h-sub-loop, half the barriers), BN in {64,128}. 4 waves.
// global_load_lds w16, 8-chunk XOR swizzle (phys = c ^ ((row>>1)&7)).
template <int ACT, bool OUTF, bool OUTB, bool SCAT, bool STATS, int BN>
__global__ __launch_bounds__(256) void bgemm_kernel(
    const __hip_bfloat16* __restrict__ A, const __hip_bfloat16* __restrict__ Wt,
    const float* __restrict__ bias, const float* __restrict__ resid,
    float* __restrict__ C, __hip_bfloat16* __restrict__ Cb, int M, int Nn, int K,
    int level, float* __restrict__ bnp) {
    __shared__ __hip_bfloat16 Alds[128 * 64];
    __shared__ __hip_bfloat16 Blds[BN * 64];
    constexpr int MW = (BN == 128) ? 4 : 2;
    constexpr int WH = (BN == 128) ? 64 : 32;
    constexpr int BR = BN / 32;                 // B staging rounds (4KB each)
    int tid = threadIdx.x;
    int wid = tid >> 6, lane = tid & 63;
    int row0 = blockIdx.y * 128, col0 = blockIdx.x * BN;
    int wr = (BN == 128) ? (wid >> 1) : wid;
    int wc = (BN == 128) ? (wid & 1) : 0;
    int r16 = lane & 15, kq = lane >> 4;

    f32x4 acc[MW][4];
#pragma unroll
    for (int m = 0; m < MW; m++)
#pragma unroll
        for (int n = 0; n < 4; n++) acc[m][n] = (f32x4){0.f, 0.f, 0.f, 0.f};

    for (int k0 = 0; k0 < K; k0 += 64) {
#pragma unroll
        for (int i = 0; i < 4; i++) {           // A: 128x64 = 16 KB
            int slot = i * 256 + tid;
            int row = slot >> 3, qp = slot & 7;
            int q = qp ^ ((row >> 1) & 7);
            const __hip_bfloat16* ga = A + (size_t)(row0 + row) * K + k0 + q * 8;
            __builtin_amdgcn_global_load_lds(
                (const __attribute__((address_space(1))) void*)ga,
                (__attribute__((address_space(3))) void*)((char*)Alds + i * 4096 + wid * 1024),
                16, 0, 0);
        }
#pragma unroll
        for (int i = 0; i < BR; i++) {          // B: BNx64
            int slot = i * 256 + tid;
            int row = slot >> 3, qp = slot & 7;
            int q = qp ^ ((row >> 1) & 7);
            const __hip_bfloat16* gb = Wt + (size_t)(col0 + row) * K + k0 + q * 8;
            __builtin_amdgcn_global_load_lds(
                (const __attribute__((address_space(1))) void*)gb,
                (__attribute__((address_space(3))) void*)((char*)Blds + i * 4096 + wid * 1024),
                16, 0, 0);
        }
        __syncthreads();
#pragma unroll
        for (int h = 0; h < 2; h++) {
            short8 af[MW], bf4[4];
#pragma unroll
            for (int m = 0; m < MW; m++) {
                int row = wr * WH + m * 16 + r16;
                int phys = (h * 4 + kq) ^ ((row >> 1) & 7);
                af[m] = *reinterpret_cast<const short8*>(
                    reinterpret_cast<const char*>(Alds) + row * 128 + phys * 16);
            }
#pragma unroll
            for (int n = 0; n < 4; n++) {
                int row = wc * 64 + n * 16 + r16;
                int phys = (h * 4 + kq) ^ ((row >> 1) & 7);
                bf4[n] = *reinterpret_cast<const short8*>(
                    reinterpret_cast<const char*>(Blds) + row * 128 + phys * 16);
            }
#pragma unroll
            for (int m = 0; m < MW; m++)
#pragma unroll
                for (int n = 0; n < 4; n++)
                    acc[m][n] = __builtin_amdgcn_mfma_f32_16x16x32_bf16(af[m], bf4[n], acc[m][n], 0, 0, 0);
        }
        __syncthreads();
    }

    int rg = lane >> 4;
    float s1a[4] = {0.f, 0.f, 0.f, 0.f}, s2a[4] = {0.f, 0.f, 0.f, 0.f};
    if (SCAT) {
#pragma unroll
        for (int n = 0; n < 4; n++) {
            int cc = col0 + wc * 64 + n * 16 + r16;
            int bb = cc >> 9, nn = cc & 511;
            float* dst = C + (size_t)bb * (LEVELS_ * PYOUT_ * N_) +
                         (size_t)level * PYOUT_ * N_ + nn;
#pragma unroll
            for (int m = 0; m < MW; m++) {
                int rbase = wr * WH + m * 16 + rg * 4;
#pragma unroll
                for (int j = 0; j < 4; j++) {
                    int ch = rbase + j;
                    dst[(size_t)ch * N_] = acc[m][n][j] + bias[ch];
                }
            }
        }
    } else {
#pragma unroll
        for (int n = 0; n < 4; n++) {
            int cc = col0 + wc * 64 + n * 16 + r16;
            float bv = bias[cc];
#pragma unroll
            for (int m = 0; m < MW; m++) {
                int rb = row0 + wr * WH + m * 16 + rg * 4;
#pragma unroll
                for (int j = 0; j < 4; j++) {
                    int r = rb + j;
                    float v = acc[m][n][j] + bv;
                    if (resid) v += resid[(size_t)r * Nn + cc];
                    if (ACT == 1) v = gelu_f(v);
                    if (OUTF) C[(size_t)r * Nn + cc] = v;
                    if (OUTB) Cb[(size_t)r * Nn + cc] = __float2bfloat16(v);
                    if (STATS) { s1a[n] += v; s2a[n] += v * v; }
                }
            }
        }
    }
    if (STATS) {
        float* sc = (float*)Alds;
        int part = wid * 4 + rg;
#pragma unroll
        for (int n = 0; n < 4; n++) {
            int c = wc * 64 + n * 16 + r16;
            sc[c * 16 + part] = s1a[n];
            sc[BN * 16 + c * 16 + part] = s2a[n];
        }
        __syncthreads();
        if (tid < BN) {
            float a = 0.f, b2 = 0.f;
#pragma unroll
            for (int p = 0; p < 16; p++) {
                a += sc[tid * 16 + p];
                b2 += sc[BN * 16 + tid * 16 + p];
            }
            bnp[blockIdx.y * 256 + col0 + tid] = a;
            bnp[16384 + blockIdx.y * 256 + col0 + tid] = b2;
        }
    }
}

// ---------------------------------------------------------------- fused patch GEMM + LN + pos
// Block = 32 rows x 256 cols, K=256, BK=64. 4 waves (wave = 64-col group).
__global__ __launch_bounds__(256) void patchln_kernel(
    const __hip_bfloat16* __restrict__ A, const __hip_bfloat16* __restrict__ Wt,
    const float* __restrict__ bias, const float* __restrict__ lng,
    const float* __restrict__ lnb, const float* __restrict__ pos,
    float* __restrict__ H, __hip_bfloat16* __restrict__ Hb) {
    __shared__ char __attribute__((aligned(16))) smem[36864];   // A 4K | B 32K ; Cls overlay
    __hip_bfloat16* Alds = (__hip_bfloat16*)smem;
    __hip_bfloat16* Blds = (__hip_bfloat16*)(smem + 4096);
    float (*Cls)[260] = (float(*)[260])smem;                    // 32x260 f32 = 33280 B
    int tid = threadIdx.x;
    int wid = tid >> 6, lane = tid & 63;
    int row0 = blockIdx.x * 32;
    int r16 = lane & 15, kq = lane >> 4, g = lane >> 4;

    f32x4 acc[2][4];
#pragma unroll
    for (int m = 0; m < 2; m++)
#pragma unroll
        for (int n = 0; n < 4; n++) acc[m][n] = (f32x4){0.f, 0.f, 0.f, 0.f};

    for (int k0 = 0; k0 < 256; k0 += 64) {
        {   // A: 32x64 = 4 KB, one round
            int row = tid >> 3, qp = tid & 7;
            int q = qp ^ ((row >> 1) & 7);
            const __hip_bfloat16* ga = A + (size_t)(row0 + row) * 256 + k0 + q * 8;
            __builtin_amdgcn_global_load_lds(
                (const __attribute__((address_space(1))) void*)ga,
                (__attribute__((address_space(3))) void*)((char*)Alds + wid * 1024),
                16, 0, 0);
        }
#pragma unroll
        for (int i = 0; i < 8; i++) {   // B: 256x64 = 32 KB
            int slot = i * 256 + tid;
            int row = slot >> 3, qp = slot & 7;
            int q = qp ^ ((row >> 1) & 7);
            const __hip_bfloat16* gb = Wt + (size_t)row * 256 + k0 + q * 8;
            __builtin_amdgcn_global_load_lds(
                (const __attribute__((address_space(1))) void*)gb,
                (__attribute__((address_space(3))) void*)((char*)Blds + i * 4096 + wid * 1024),
                16, 0, 0);
        }
        __syncthreads();
#pragma unroll
        for (int h = 0; h < 2; h++) {
            short8 af[2], bf4[4];
#pragma unroll
            for (int m = 0; m < 2; m++) {
                int row = m * 16 + r16;
                int phys = (h * 4 + kq) ^ ((row >> 1) & 7);
                af[m] = *reinterpret_cast<const short8*>(
                    reinterpret_cast<const char*>(Alds) + row * 128 + phys * 16);
            }
#pragma unroll
            for (int n = 0; n < 4; n++) {
                int row = wid * 64 + n * 16 + r16;
                int phys = (h * 4 + kq) ^ ((row >> 1) & 7);
                bf4[n] = *reinterpret_cast<const short8*>(
                    reinterpret_cast<const char*>(Blds) + row * 128 + phys * 16);
            }
#pragma unroll
            for (int m = 0; m < 2; m++)
#pragma unroll
                for (int n = 0; n < 4; n++)
                    acc[m][n] = __builtin_amdgcn_mfma_f32_16x16x32_bf16(af[m], bf4[n], acc[m][n], 0, 0, 0);
        }
        __syncthreads();
    }
    // C tile (+bias) -> LDS overlay
#pragma unroll
    for (int n = 0; n < 4; n++) {
        int col = wid * 64 + n * 16 + r16;
        float bv = bias[col];
#pragma unroll
        for (int m = 0; m < 2; m++)
#pragma unroll
            for (int j = 0; j < 4; j++)
                Cls[m * 16 + g * 4 + j][col] = acc[m][n][j] + bv;
    }
    __syncthreads();
    float4 g4 = ((const float4*)lng)[lane];
    float4 b4 = ((const float4*)lnb)[lane];
#pragma unroll
    for (int rr = 0; rr < 8; rr++) {
        int r = wid * 8 + rr;
        float4 v = *(const float4*)&Cls[r][lane * 4];
        float s = v.x + v.y + v.z + v.w;
#pragma unroll
        for (int mk = 32; mk; mk >>= 1) s += __shfl_xor(s, mk);
        float mean = s * (1.f / 256.f);
        float dx = v.x - mean, dy = v.y - mean, dz = v.z - mean, dw = v.w - mean;
        float q = dx * dx + dy * dy + dz * dz + dw * dw;
#pragma unroll
        for (int mk = 32; mk; mk >>= 1) q += __shfl_xor(q, mk);
        float rstd = rsqrtf(q * (1.f / 256.f) + 1e-5f);
        int grow = row0 + r;
        float4 p4 = ((const float4*)pos)[(size_t)(grow & (N_ - 1)) * 64 + lane];
        float o0 = dx * rstd * g4.x + b4.x + p4.x;
        float o1 = dy * rstd * g4.y + b4.y + p4.y;
        float o2 = dz * rstd * g4.z + b4.z + p4.z;
        float o3 = dw * rstd * g4.w + b4.w + p4.w;
        ((float4*)(H + (size_t)grow * D_))[lane] = (float4){o0, o1, o2, o3};
        ushort4v u = {f2bf(o0), f2bf(o1), f2bf(o2), f2bf(o3)};
        *((ushort4v*)(Hb + (size_t)grow * D_) + lane) = u;
    }
}

// ---------------------------------------------------------------- BN finish+apply merged
__global__ __launch_bounds__(256) void bn_applyfin_kernel(
    const float* __restrict__ x, const float* __restrict__ bnp,
    const float* __restrict__ g, const float* __restrict__ b,
    float* __restrict__ y, __hip_bfloat16* __restrict__ yb) {
    int tid = threadIdx.x;
    __shared__ float sm[256], sv[256];
    {
        float s = 0.f, s2 = 0.f;
#pragma unroll 4
        for (int yy = 0; yy < 64; yy++) {
            s += bnp[yy * 256 + tid];
            s2 += bnp[16384 + yy * 256 + tid];
        }
        float m = s * (1.f / 8192.f);
        sm[tid] = m;
        sv[tid] = rsqrtf(s2 * (1.f / 8192.f) - m * m + 1e-5f);
    }
    __syncthreads();
    int lane = tid & 63, w = tid >> 6;
    int row0 = blockIdx.x * 32;
    float4 m4 = *(const float4*)&sm[lane * 4];
    float4 r4 = *(const float4*)&sv[lane * 4];
    float4 g4 = ((const float4*)g)[lane];
    float4 b4 = ((const float4*)b)[lane];
#pragma unroll
    for (int rr = 0; rr < 8; rr++) {
        int row = row0 + w * 8 + rr;
        float4 x4 = ((const float4*)(x + (size_t)row * D_))[lane];
        float o0 = (x4.x - m4.x) * r4.x * g4.x + b4.x;
        float o1 = (x4.y - m4.y) * r4.y * g4.y + b4.y;
        float o2 = (x4.z - m4.z) * r4.z * g4.z + b4.z;
        float o3 = (x4.w - m4.w) * r4.w * g4.w + b4.w;
        if (y) ((float4*)(y + (size_t)row * D_))[lane] = (float4){o0, o1, o2, o3};
        if (yb) {
            ushort4v u = {f2bf(o0), f2bf(o1), f2bf(o2), f2bf(o3)};
            *((ushort4v*)(yb + (size_t)row * D_) + lane) = u;
        }
    }
}

// ---------------------------------------------------------------- MFMA attention
__global__ __launch_bounds__(256) void attn_kernel(
    const __hip_bfloat16* __restrict__ qkv, __hip_bfloat16* __restrict__ outb) {
    int bx = blockIdx.x, h = blockIdx.y, b = blockIdx.z;
    int tid = threadIdx.x;
    int wid = tid >> 6, lane = tid & 63;
    __shared__ __hip_bfloat16 Klds[256 * 32];
    __shared__ __hip_bfloat16 Vt[32 * 264];
    const short* q16 = (const short*)qkv;

#pragma unroll
    for (int r = 0; r < 4; r++) {
        int slot = r * 256 + tid;
        int row = slot >> 2, qp = slot & 3;
        int ql = qp ^ ((row >> 1) & 3);
        int jb = bx * 4 - 2 + (row >> 5);
        jb = jb < 0 ? 0 : (jb > 15 ? 15 : jb);
        const short* ga = q16 + ((size_t)(b * N_ + jb * 32 + (row & 31))) * 768 + 256 + h * 32 + ql * 8;
        __builtin_amdgcn_global_load_lds(
            (const __attribute__((address_space(1))) void*)ga,
            (__attribute__((address_space(3))) void*)((char*)Klds + r * 4096 + wid * 1024),
            16, 0, 0);
    }
    {
        int row = tid;
        int jb = bx * 4 - 2 + (row >> 5);
        jb = jb < 0 ? 0 : (jb > 15 ? 15 : jb);
        const short* gv = q16 + ((size_t)(b * N_ + jb * 32 + (row & 31))) * 768 + 512 + h * 32;
        short8 v0 = *(const short8*)(gv);
        short8 v1 = *(const short8*)(gv + 8);
        short8 v2 = *(const short8*)(gv + 16);
        short8 v3 = *(const short8*)(gv + 24);
        short* vt = (short*)Vt;
#pragma unroll
        for (int e = 0; e < 8; e++) {
            vt[(e) * 264 + row] = v0[e];
            vt[(8 + e) * 264 + row] = v1[e];
            vt[(16 + e) * 264 + row] = v2[e];
            vt[(24 + e) * 264 + row] = v3[e];
        }
    }
    __syncthreads();

    int i = bx * 4 + wid;
    int c = lane & 15, g = lane >> 4;
    const float scale = 0.17677669529663687f;

#pragma unroll
    for (int qt = 0; qt < 2; qt++) {
        const short* qa = q16 + ((size_t)(b * N_ + i * 32 + qt * 16 + c)) * 768 + h * 32 + g * 8;
        short8 bq = *(const short8*)qa;
        f32x4 st[10];
#pragma unroll
        for (int t = 0; t < 10; t++) {
            int jb = i - 2 + (t >> 1);
            if (jb >= 0 && jb < NBLK_) {
                int row = wid * 32 + t * 16 + c;
                int phys = g ^ ((row >> 1) & 3);
                short8 ak = *(const short8*)((const char*)Klds + row * 64 + phys * 16);
                st[t] = __builtin_amdgcn_mfma_f32_16x16x32_bf16(
                    ak, bq, (f32x4){0.f, 0.f, 0.f, 0.f}, 0, 0, 0);
            }
        }
        float mx = -1e30f;
#pragma unroll
        for (int t = 0; t < 10; t++) {
            int jb = i - 2 + (t >> 1);
            if (jb >= 0 && jb < NBLK_) {
#pragma unroll
                for (int j = 0; j < 4; j++) {
                    st[t][j] *= scale;
                    mx = fmaxf(mx, st[t][j]);
                }
            }
        }
        mx = fmaxf(mx, __shfl_xor(mx, 16));
        mx = fmaxf(mx, __shfl_xor(mx, 32));
        float sum = 0.f;
#pragma unroll
        for (int t = 0; t < 10; t++) {
            int jb = i - 2 + (t >> 1);
            if (jb >= 0 && jb < NBLK_) {
#pragma unroll
                for (int j = 0; j < 4; j++) {
                    float e = __expf(st[t][j] - mx);
                    st[t][j] = e;
                    sum += e;
                }
            }
        }
        sum += __shfl_xor(sum, 16);
        sum += __shfl_xor(sum, 32);
        float inv = 1.f / sum;
        f32x4 o0 = (f32x4){0.f, 0.f, 0.f, 0.f};
        f32x4 o1 = (f32x4){0.f, 0.f, 0.f, 0.f};
        const short* vt = (const short*)Vt;
#pragma unroll
        for (int t = 0; t < 10; t++) {
            int jb = i - 2 + (t >> 1);
            if (jb >= 0 && jb < NBLK_) {
                short8 pa = (short8)0;
#pragma unroll
                for (int j = 0; j < 4; j++) pa[j] = (short)f2bf(st[t][j] * inv);
                int kb = wid * 32 + t * 16 + g * 4;
                short4v vb0 = *(const short4v*)(vt + (0 * 16 + c) * 264 + kb);
                short4v vb1 = *(const short4v*)(vt + (1 * 16 + c) * 264 + kb);
                short8 b0 = (short8)0, b1 = (short8)0;
#pragma unroll
                for (int e = 0; e < 4; e++) { b0[e] = vb0[e]; b1[e] = vb1[e]; }
                o0 = __builtin_amdgcn_mfma_f32_16x16x32_bf16(pa, b0, o0, 0, 0, 0);
                o1 = __builtin_amdgcn_mfma_f32_16x16x32_bf16(pa, b1, o1, 0, 0, 0);
            }
        }
#pragma unroll
        for (int j = 0; j < 4; j++) {
            size_t rbase = ((size_t)(b * N_ + i * 32 + qt * 16 + g * 4 + j)) * D_ + h * DH_;
            outb[rbase + c] = __float2bfloat16(o0[j]);
            outb[rbase + 16 + c] = __float2bfloat16(o1[j]);
        }
    }
}

// ---------------------------------------------------------------- fcl
__global__ __launch_bounds__(256) void fcl_partial_kernel(
    const float* __restrict__ flat, const float* __restrict__ W,
    float* __restrict__ partial) {
    int chunk = blockIdx.x;             // 1280
    int t = threadIdx.x;
    int k0 = chunk * FCL_KB;
    __shared__ float fl[FCL_KB][20];
#pragma unroll
    for (int b = 0; b < 16; b++)
        fl[t][b] = flat[(size_t)b * FCL_K + k0 + t];
    __syncthreads();
    int j = t & 127, bg = t >> 7;
    f32x4 a0 = (f32x4){0.f, 0.f, 0.f, 0.f};
    f32x4 a1 = (f32x4){0.f, 0.f, 0.f, 0.f};
#pragma unroll 8
    for (int k = 0; k < FCL_KB; k++) {
        float w = W[(size_t)(k0 + k) * 128 + j];
        f32x4 f0 = *(const f32x4*)&fl[k][bg * 8];
        f32x4 f1 = *(const f32x4*)&fl[k][bg * 8 + 4];
        a0 += f0 * w;
        a1 += f1 * w;
    }
#pragma unroll
    for (int bi = 0; bi < 4; bi++) {
        partial[((size_t)chunk * 16 + bg * 8 + bi) * 128 + j] = a0[bi];
        partial[((size_t)chunk * 16 + bg * 8 + 4 + bi) * 128 + j] = a1[bi];
    }
}

__global__ __launch_bounds__(256) void fcl_reduce_kernel(
    const float* __restrict__ partial, const float* __restrict__ fcl_b,
    float* __restrict__ add) {
    int c0 = blockIdx.x * 32;
    int t = threadIdx.x;
    int ry = t >> 5, cx = t & 31;
    float s = 0.f;
    for (int r = ry; r < FCL_CHUNKS; r += 8)
        s += partial[(size_t)r * 2048 + c0 + cx];
    __shared__ float red[8][32];
    red[ry][cx] = s; __syncthreads();
    if (ry == 0) {
        float tot = 0.f;
#pragma unroll
        for (int q = 0; q < 8; q++) tot += red[q][cx];
        int col = c0 + cx;
        add[col] = tot + fcl_b[col & 127];
    }
}

// ---------------------------------------------------------------- fused head
__global__ __launch_bounds__(256) void head_kernel(
    const float* __restrict__ add, const float* __restrict__ abg, const float* __restrict__ abb,
    const float* __restrict__ cls_W1, const float* __restrict__ cls_b1,
    const float* __restrict__ cls_W2, const float* __restrict__ cls_b2,
    const float* __restrict__ box_W1, const float* __restrict__ box_b1,
    const float* __restrict__ box_W2, const float* __restrict__ box_b2,
    float* __restrict__ out) {
    __shared__ float a2[16][128];
    __shared__ float cm[16][256];
    __shared__ float cls[16][45];
    __shared__ float bmid[16][128];
    __shared__ float smden[16];
    int t = threadIdx.x;
    if (t < 128) {
        float m = 0.f;
#pragma unroll
        for (int b = 0; b < 16; b++) m += add[b * 128 + t];
        m *= (1.f / 16.f);
        float v = 0.f;
#pragma unroll
        for (int b = 0; b < 16; b++) { float d = add[b * 128 + t] - m; v += d * d; }
        v *= (1.f / 16.f);
        float sc = rsqrtf(v + 1e-5f) * abg[t];
#pragma unroll
        for (int b = 0; b < 16; b++) a2[b][t] = (add[b * 128 + t] - m) * sc + abb[t];
    }
    __syncthreads();
    for (int idx = t; idx < 4096; idx += 256) {
        int m = idx >> 8, c = idx & 255;
        float a = cls_b1[c];
        for (int k = 0; k < 128; k++) a += a2[m][k] * cls_W1[k * 256 + c];
        cm[m][c] = fmaxf(a, 0.f);
    }
    for (int idx = t; idx < 2048; idx += 256) {
        int m = idx >> 7, c = idx & 127;
        float a = box_b1[c];
        for (int k = 0; k < 128; k++) a += a2[m][k] * box_W1[k * 128 + c];
        bmid[m][c] = fmaxf(a, 0.f);
    }
    __syncthreads();
    for (int idx = t; idx < 720; idx += 256) {
        int m = idx / 45, c = idx % 45;
        float a = cls_b2[c];
        for (int k = 0; k < 256; k++) a += cm[m][k] * cls_W2[k * 45 + c];
        cls[m][c] = a;
    }
    __syncthreads();
    if (t < 16) {
        float mx = -1e30f;
        for (int c = 0; c < 45; c++) mx = fmaxf(mx, cls[t][c]);
        float s = 0.f;
        for (int c = 0; c < 45; c++) { float e = expf(cls[t][c] - mx); cls[t][c] = e; s += e; }
        smden[t] = s;
    }
    for (int idx = t; idx < 576; idx += 256) {
        int m = idx / 36, c = idx % 36;
        float a = box_b2[c];
        for (int k = 0; k < 128; k++) a += bmid[m][k] * box_W2[k * 36 + c];
        out[m * 81 + (c >> 2) * 9 + 5 + (c & 3)] = a;
    }
    __syncthreads();
    for (int idx = t; idx < 720; idx += 256) {
        int m = idx / 45, c = idx % 45;
        out[m * 81 + (c / 5) * 9 + (c % 5)] = cls[m][c] / smden[m];
    }
}

// ================================================================ launcher
extern "C" void kernel_launch(void* const* d_in, const int* in_sizes, int n_in,
                              void* d_out, int out_size, void* d_ws, size_t ws_size,
                              hipStream_t stream) {
    const float* x_in    = (const float*)d_in[0];
    const float* patch_W = (const float*)d_in[1];
    const float* patch_b = (const float*)d_in[2];
    const float* ln_g    = (const float*)d_in[3];
    const float* ln_b    = (const float*)d_in[4];
    const float* ff_W1   = (const float*)d_in[5];
    const float* ff_b1   = (const float*)d_in[6];
    const float* ff_W2   = (const float*)d_in[7];
    const float* ff_b2   = (const float*)d_in[8];
    const float* Wqkv    = (const float*)d_in[9];
    const float* bqkv    = (const float*)d_in[10];
    const float* Wo      = (const float*)d_in[11];
    const float* bo      = (const float*)d_in[12];
    const float* bn1_g   = (const float*)d_in[13];
    const float* bn1_b   = (const float*)d_in[14];
    const float* bn2_g   = (const float*)d_in[15];
    const float* bn2_b   = (const float*)d_in[16];
    const float* pyr_W   = (const float*)d_in[17];
    const float* pyr_b   = (const float*)d_in[18];
    const float* fcl_W   = (const float*)d_in[19];
    const float* fcl_b   = (const float*)d_in[20];
    const float* addbn_g = (const float*)d_in[21];
    const float* addbn_b = (const float*)d_in[22];
    const float* cls_W1  = (const float*)d_in[23];
    const float* cls_b1  = (const float*)d_in[24];
    const float* cls_W2  = (const float*)d_in[25];
    const float* cls_b2  = (const float*)d_in[26];
    const float* box_W1  = (const float*)d_in[27];
    const float* box_b1  = (const float*)d_in[28];
    const float* box_W2  = (const float*)d_in[29];
    const float* box_b2  = (const float*)d_in[30];
    float* out = (float*)d_out;

    float* ws = (float*)d_ws;
    size_t off = 0;
    float* POS   = ws + off; off += 131072;
    float* H     = ws + off; off += 2097152;
    float* T     = ws + off; off += 2097152;
    float* UNION = ws + off; off += 4194304;   // MIDb bf16 / QKVb bf16
    float* FLAT  = ws + off; off += 5242880;
    float* PART  = ws + off; off += (size_t)FCL_CHUNKS * 2048;
    float* BNP   = ws + off; off += 2 * 64 * 256;
    float* ADD   = ws + off; off += 2048;
    __hip_bfloat16* Hb   = (__hip_bfloat16*)(ws + off); off += 1048576;
    __hip_bfloat16* Tb   = (__hip_bfloat16*)(ws + off); off += 1048576;
    __hip_bfloat16* Xb   = (__hip_bfloat16*)(ws + off); off += 1048576;
    __hip_bfloat16* ATb  = (__hip_bfloat16*)(ws + off); off += 1048576;
    __hip_bfloat16* patchWt = (__hip_bfloat16*)(ws + off); off += 32768;
    __hip_bfloat16* qkvWt   = (__hip_bfloat16*)(ws + off); off += 98304;
    __hip_bfloat16* WoWt    = (__hip_bfloat16*)(ws + off); off += 32768;
    __hip_bfloat16* W1t     = (__hip_bfloat16*)(ws + off); off += 131072;
    __hip_bfloat16* W2t     = (__hip_bfloat16*)(ws + off); off += 131072;
    __hip_bfloat16* pyrWt   = (__hip_bfloat16*)(ws + off); off += 81920;
    __hip_bfloat16* MIDb = (__hip_bfloat16*)UNION;
    __hip_bfloat16* QKVb = (__hip_bfloat16*)UNION;

    prep_kernel<<<2528, 256, 0, stream>>>(
        patch_W, Wqkv, Wo, ff_W1, ff_W2, pyr_W, x_in,
        patchWt, qkvWt, WoWt, W1t, W2t, pyrWt, POS, Xb);

    for (int it = 0; it < 5; it++) {
        patchln_kernel<<<256, 256, 0, stream>>>(Xb, patchWt, patch_b, ln_g, ln_b, POS, H, Hb);
        bgemm_kernel<1, false, true, false, false, 128><<<dim3(8, 64), 256, 0, stream>>>(
            Hb, W1t, ff_b1, nullptr, nullptr, MIDb, ROWS_, HIDEF_, D_, 0, nullptr);
        bgemm_kernel<0, false, true, false, false, 64><<<dim3(4, 64), 256, 0, stream>>>(
            MIDb, W2t, ff_b2, nullptr, nullptr, Tb, ROWS_, D_, HIDEF_, 0, nullptr);
        bgemm_kernel<0, false, true, false, false, 128><<<dim3(6, 64), 256, 0, stream>>>(
            Tb, qkvWt, bqkv, nullptr, nullptr, QKVb, ROWS_, 768, D_, 0, nullptr);
        attn_kernel<<<dim3(4, HEADS_, B_), 256, 0, stream>>>(QKVb, ATb);
        bgemm_kernel<0, true, false, false, true, 64><<<dim3(4, 64), 256, 0, stream>>>(
            ATb, WoWt, bo, H, T, nullptr, ROWS_, D_, D_, 0, BNP);
        bn_applyfin_kernel<<<256, 256, 0, stream>>>(T, BNP, bn1_g, bn1_b, H, Hb);
        bgemm_kernel<1, false, true, false, false, 128><<<dim3(8, 64), 256, 0, stream>>>(
            Hb, W1t, ff_b1, nullptr, nullptr, MIDb, ROWS_, HIDEF_, D_, 0, nullptr);
        bgemm_kernel<0, true, false, false, true, 64><<<dim3(4, 64), 256, 0, stream>>>(
            MIDb, W2t, ff_b2, H, T, nullptr, ROWS_, D_, HIDEF_, 0, BNP);
        bn_applyfin_kernel<<<256, 256, 0, stream>>>(T, BNP, bn2_g, bn2_b, nullptr, Xb);
        bgemm_kernel<0, false, false, true, false, 64><<<dim3(128, 1), 256, 0, stream>>>(
            pyrWt + (size_t)it * D_ * PYOUT_, Xb, pyr_b + it * PYOUT_, nullptr,
            FLAT, nullptr, PYOUT_, ROWS_, D_, it, nullptr);
    }

    fcl_partial_kernel<<<FCL_CHUNKS, 256, 0, stream>>>(FLAT, fcl_W, PART);
    fcl_reduce_kernel<<<64, 256, 0, stream>>>(PART, fcl_b, ADD);
    head_kernel<<<1, 256, 0, stream>>>(ADD, addbn_g, addbn_b,
        cls_W1, cls_b1, cls_W2, cls_b2, box_W1, box_b1, box_W2, box_b2, out);
    (void)in_sizes; (void)n_in; (void)out_size; (void)ws_size;
}

// Round 8
// 919.900 us; speedup vs baseline: 5.0447x; 1.0569x over previous
//
#include <hip/hip_runtime.h>
#include <hip/hip_bf16.h>
#include <math.h>

#define B_ 16
#define N_ 512
#define D_ 256
#define HEADS_ 8
#define DH_ 32
#define HIDEF_ 1024
#define NBLK_ 16
#define BS_ 32
#define LEVELS_ 5
#define PYOUT_ 128
#define ROWS_ (B_ * N_)   // 8192
#define FCL_K 327680
#define FCL_KB 256
#define FCL_CHUNKS 1280

typedef __attribute__((ext_vector_type(8))) short short8;
typedef __attribute__((ext_vector_type(4))) short short4v;
typedef __attribute__((ext_vector_type(4))) unsigned short ushort4v;
typedef __attribute__((ext_vector_type(4))) float f32x4;

__device__ __forceinline__ float bf2f(short u) {
    return __uint_as_float(((unsigned int)(unsigned short)u) << 16);
}
__device__ __forceinline__ unsigned short f2bf(float x) {
    __hip_bfloat16 h = __float2bfloat16(x);
    return *reinterpret_cast<unsigned short*>(&h);
}

__device__ __forceinline__ float gelu_f(float x) {
    float x3 = x * x * x;
    return 0.5f * x * (1.f + tanhf(0.7978845608028654f * (x + 0.044715f * x3)));
}

// ---------------------------------------------------------------- combined prep
__global__ __launch_bounds__(256) void prep_kernel(
    const float* __restrict__ patch_W, const float* __restrict__ Wqkv,
    const float* __restrict__ Wo, const float* __restrict__ ff_W1,
    const float* __restrict__ ff_W2, const float* __restrict__ pyr_W,
    const float* __restrict__ x_in,
    __hip_bfloat16* __restrict__ patchWt, __hip_bfloat16* __restrict__ qkvWt,
    __hip_bfloat16* __restrict__ WoWt, __hip_bfloat16* __restrict__ W1t,
    __hip_bfloat16* __restrict__ W2t, __hip_bfloat16* __restrict__ pyrWt,
    float* __restrict__ pos, __hip_bfloat16* __restrict__ Xb) {
    __shared__ float tt[32][33];
    int bid = blockIdx.x, t = threadIdx.x;
    if (bid >= 1504) {           // x -> bf16, 2048 elems/block
        int base = (bid - 1504) * 2048 + t * 8;
        float4 a = *(const float4*)&x_in[base];
        float4 b = *(const float4*)&x_in[base + 4];
        ushort4v u0 = {f2bf(a.x), f2bf(a.y), f2bf(a.z), f2bf(a.w)};
        ushort4v u1 = {f2bf(b.x), f2bf(b.y), f2bf(b.z), f2bf(b.w)};
        *(ushort4v*)((short*)Xb + base) = u0;
        *(ushort4v*)((short*)Xb + base + 4) = u1;
        return;
    }
    if (bid >= 992) {            // pos table
        int idx = (bid - 992) * 256 + t;
        int n = idx >> 8, i = idx & 255;
        double angle = (double)n / pow(10000.0, (double)(2 * (i >> 1)) / 256.0);
        pos[idx] = (float)((i & 1) ? cos(angle) : sin(angle));
        return;
    }
    const float* W; __hip_bfloat16* Wt; int K, N, bx, by;
    if (bid < 64)       { W = patch_W; Wt = patchWt; K = 256; N = 256; bx = bid % 8; by = bid / 8; }
    else if (bid < 256) { int l = bid - 64;  W = Wqkv;  Wt = qkvWt; K = 256; N = 768;  bx = l % 24; by = l / 24; }
    else if (bid < 320) { int l = bid - 256; W = Wo;    Wt = WoWt;  K = 256; N = 256;  bx = l % 8;  by = l / 8; }
    else if (bid < 576) { int l = bid - 320; W = ff_W1; Wt = W1t;   K = 256; N = 1024; bx = l % 32; by = l / 32; }
    else if (bid < 832) { int l = bid - 576; W = ff_W2; Wt = W2t;   K = 1024; N = 256; bx = l % 8;  by = l / 8; }
    else                { int l = bid - 832; int z = l / 32; int r = l % 32;
                          W = pyr_W + (size_t)z * 256 * 128; Wt = pyrWt + (size_t)z * 256 * 128;
                          K = 256; N = 128; bx = r % 4; by = r / 4; }
    int bx32 = bx * 32, by32 = by * 32;
    int tx = t & 31, ty = t >> 5;
#pragma unroll
    for (int i = 0; i < 32; i += 8)
        tt[ty + i][tx] = W[(size_t)(by32 + ty + i) * N + bx32 + tx];
    __syncthreads();
#pragma unroll
    for (int i = 0; i < 32; i += 8)
        Wt[(size_t)(bx32 + ty + i) * K + by32 + tx] = __float2bfloat16(tt[tx][ty + i]);
}

// ---------------------------------------------------------------- bf16 MFMA GEMM
// BK=64 (h-sub-loop). Tiles: 128x128 (2x2 waves of 64x64), 128x64 (4x1 of 32x64),
// 64x64 (2x2 of 32x32). global_load_lds w16, 8-chunk XOR swizzle.
template <int ACT, bool OUTF, bool OUTB, bool SCAT, bool STATS, int BM, int BN>
__global__ __launch_bounds__(256) void bgemm_kernel(
    const __hip_bfloat16* __restrict__ A, const __hip_bfloat16* __restrict__ Wt,
    const float* __restrict__ bias, const float* __restrict__ resid,
    float* __restrict__ C, __hip_bfloat16* __restrict__ Cb, int M, int Nn, int K,
    int level, float* __restrict__ bnp) {
    __shared__ __hip_bfloat16 Alds[BM * 64];
    __shared__ __hip_bfloat16 Blds[BN * 64];
    constexpr int WM_ = (BM == 128 && BN == 64) ? 4 : 2;
    constexpr int WN_ = 4 / WM_;
    constexpr int WH = BM / WM_;
    constexpr int WC = BN / WN_;
    constexpr int MW = WH / 16;
    constexpr int NW = WC / 16;
    constexpr int AR = BM / 32;
    constexpr int BR = BN / 32;
    int tid = threadIdx.x;
    int wid = tid >> 6, lane = tid & 63;
    int row0 = blockIdx.y * BM, col0 = blockIdx.x * BN;
    int wr = wid / WN_, wc = wid % WN_;
    int r16 = lane & 15, kq = lane >> 4;

    f32x4 acc[MW][NW];
#pragma unroll
    for (int m = 0; m < MW; m++)
#pragma unroll
        for (int n = 0; n < NW; n++) acc[m][n] = (f32x4){0.f, 0.f, 0.f, 0.f};

    for (int k0 = 0; k0 < K; k0 += 64) {
#pragma unroll
        for (int i = 0; i < AR; i++) {
            int slot = i * 256 + tid;
            int row = slot >> 3, qp = slot & 7;
            int q = qp ^ ((row >> 1) & 7);
            const __hip_bfloat16* ga = A + (size_t)(row0 + row) * K + k0 + q * 8;
            __builtin_amdgcn_global_load_lds(
                (const __attribute__((address_space(1))) void*)ga,
                (__attribute__((address_space(3))) void*)((char*)Alds + i * 4096 + wid * 1024),
                16, 0, 0);
        }
#pragma unroll
        for (int i = 0; i < BR; i++) {
            int slot = i * 256 + tid;
            int row = slot >> 3, qp = slot & 7;
            int q = qp ^ ((row >> 1) & 7);
            const __hip_bfloat16* gb = Wt + (size_t)(col0 + row) * K + k0 + q * 8;
            __builtin_amdgcn_global_load_lds(
                (const __attribute__((address_space(1))) void*)gb,
                (__attribute__((address_space(3))) void*)((char*)Blds + i * 4096 + wid * 1024),
                16, 0, 0);
        }
        __syncthreads();
#pragma unroll
        for (int h = 0; h < 2; h++) {
            short8 af[MW], bf4[NW];
#pragma unroll
            for (int m = 0; m < MW; m++) {
                int row = wr * WH + m * 16 + r16;
                int phys = (h * 4 + kq) ^ ((row >> 1) & 7);
                af[m] = *reinterpret_cast<const short8*>(
                    reinterpret_cast<const char*>(Alds) + row * 128 + phys * 16);
            }
#pragma unroll
            for (int n = 0; n < NW; n++) {
                int row = wc * WC + n * 16 + r16;
                int phys = (h * 4 + kq) ^ ((row >> 1) & 7);
                bf4[n] = *reinterpret_cast<const short8*>(
                    reinterpret_cast<const char*>(Blds) + row * 128 + phys * 16);
            }
#pragma unroll
            for (int m = 0; m < MW; m++)
#pragma unroll
                for (int n = 0; n < NW; n++)
                    acc[m][n] = __builtin_amdgcn_mfma_f32_16x16x32_bf16(af[m], bf4[n], acc[m][n], 0, 0, 0);
        }
        __syncthreads();
    }

    int rg = lane >> 4;
    float s1a[NW], s2a[NW];
#pragma unroll
    for (int n = 0; n < NW; n++) { s1a[n] = 0.f; s2a[n] = 0.f; }
    if (SCAT) {
#pragma unroll
        for (int n = 0; n < NW; n++) {
            int cc = col0 + wc * WC + n * 16 + r16;
            int bb = cc >> 9, nn = cc & 511;
            float* dst = C + (size_t)bb * (LEVELS_ * PYOUT_ * N_) +
                         (size_t)level * PYOUT_ * N_ + nn;
#pragma unroll
            for (int m = 0; m < MW; m++) {
                int rbase = row0 + wr * WH + m * 16 + rg * 4;
#pragma unroll
                for (int j = 0; j < 4; j++) {
                    int ch = rbase + j;
                    dst[(size_t)ch * N_] = acc[m][n][j] + bias[ch];
                }
            }
        }
    } else {
#pragma unroll
        for (int n = 0; n < NW; n++) {
            int cc = col0 + wc * WC + n * 16 + r16;
            float bv = bias[cc];
#pragma unroll
            for (int m = 0; m < MW; m++) {
                int rb = row0 + wr * WH + m * 16 + rg * 4;
#pragma unroll
                for (int j = 0; j < 4; j++) {
                    int r = rb + j;
                    float v = acc[m][n][j] + bv;
                    if (resid) v += resid[(size_t)r * Nn + cc];
                    if (ACT == 1) v = gelu_f(v);
                    if (OUTF) C[(size_t)r * Nn + cc] = v;
                    if (OUTB) Cb[(size_t)r * Nn + cc] = __float2bfloat16(v);
                    if (STATS) { s1a[n] += v; s2a[n] += v * v; }
                }
            }
        }
    }
    if (STATS) {
        // scratch in Alds (BM*64*2 >= BN*16*2*4 bytes for BN=64: 8KB) — loop-final barrier passed
        float* sc = (float*)Alds;
        int part = wid * 4 + rg;
#pragma unroll
        for (int n = 0; n < NW; n++) {
            int c = wc * WC + n * 16 + r16;
            sc[c * 16 + part] = s1a[n];
            sc[BN * 16 + c * 16 + part] = s2a[n];
        }
        __syncthreads();
        if (tid < BN) {
            float a = 0.f, b2 = 0.f;
#pragma unroll
            for (int p = 0; p < 16; p++) {
                a += sc[tid * 16 + p];
                b2 += sc[BN * 16 + tid * 16 + p];
            }
            bnp[blockIdx.y * 256 + col0 + tid] = a;
            bnp[32768 + blockIdx.y * 256 + col0 + tid] = b2;
        }
    }
}

// ---------------------------------------------------------------- fused patch GEMM + LN + pos
__global__ __launch_bounds__(256) void patchln_kernel(
    const __hip_bfloat16* __restrict__ A, const __hip_bfloat16* __restrict__ Wt,
    const float* __restrict__ bias, const float* __restrict__ lng,
    const float* __restrict__ lnb, const float* __restrict__ pos,
    float* __restrict__ H, __hip_bfloat16* __restrict__ Hb) {
    __shared__ char __attribute__((aligned(16))) smem[36864];   // A 4K | B 32K ; Cls overlay
    __hip_bfloat16* Alds = (__hip_bfloat16*)smem;
    __hip_bfloat16* Blds = (__hip_bfloat16*)(smem + 4096);
    float (*Cls)[260] = (float(*)[260])smem;
    int tid = threadIdx.x;
    int wid = tid >> 6, lane = tid & 63;
    int row0 = blockIdx.x * 32;
    int r16 = lane & 15, kq = lane >> 4, g = lane >> 4;

    f32x4 acc[2][4];
#pragma unroll
    for (int m = 0; m < 2; m++)
#pragma unroll
        for (int n = 0; n < 4; n++) acc[m][n] = (f32x4){0.f, 0.f, 0.f, 0.f};

    for (int k0 = 0; k0 < 256; k0 += 64) {
        {
            int row = tid >> 3, qp = tid & 7;
            int q = qp ^ ((row >> 1) & 7);
            const __hip_bfloat16* ga = A + (size_t)(row0 + row) * 256 + k0 + q * 8;
            __builtin_amdgcn_global_load_lds(
                (const __attribute__((address_space(1))) void*)ga,
                (__attribute__((address_space(3))) void*)((char*)Alds + wid * 1024),
                16, 0, 0);
        }
#pragma unroll
        for (int i = 0; i < 8; i++) {
            int slot = i * 256 + tid;
            int row = slot >> 3, qp = slot & 7;
            int q = qp ^ ((row >> 1) & 7);
            const __hip_bfloat16* gb = Wt + (size_t)row * 256 + k0 + q * 8;
            __builtin_amdgcn_global_load_lds(
                (const __attribute__((address_space(1))) void*)gb,
                (__attribute__((address_space(3))) void*)((char*)Blds + i * 4096 + wid * 1024),
                16, 0, 0);
        }
        __syncthreads();
#pragma unroll
        for (int h = 0; h < 2; h++) {
            short8 af[2], bf4[4];
#pragma unroll
            for (int m = 0; m < 2; m++) {
                int row = m * 16 + r16;
                int phys = (h * 4 + kq) ^ ((row >> 1) & 7);
                af[m] = *reinterpret_cast<const short8*>(
                    reinterpret_cast<const char*>(Alds) + row * 128 + phys * 16);
            }
#pragma unroll
            for (int n = 0; n < 4; n++) {
                int row = wid * 64 + n * 16 + r16;
                int phys = (h * 4 + kq) ^ ((row >> 1) & 7);
                bf4[n] = *reinterpret_cast<const short8*>(
                    reinterpret_cast<const char*>(Blds) + row * 128 + phys * 16);
            }
#pragma unroll
            for (int m = 0; m < 2; m++)
#pragma unroll
                for (int n = 0; n < 4; n++)
                    acc[m][n] = __builtin_amdgcn_mfma_f32_16x16x32_bf16(af[m], bf4[n], acc[m][n], 0, 0, 0);
        }
        __syncthreads();
    }
#pragma unroll
    for (int n = 0; n < 4; n++) {
        int col = wid * 64 + n * 16 + r16;
        float bv = bias[col];
#pragma unroll
        for (int m = 0; m < 2; m++)
#pragma unroll
            for (int j = 0; j < 4; j++)
                Cls[m * 16 + g * 4 + j][col] = acc[m][n][j] + bv;
    }
    __syncthreads();
    float4 g4 = ((const float4*)lng)[lane];
    float4 b4 = ((const float4*)lnb)[lane];
#pragma unroll
    for (int rr = 0; rr < 8; rr++) {
        int r = wid * 8 + rr;
        float4 v = *(const float4*)&Cls[r][lane * 4];
        float s = v.x + v.y + v.z + v.w;
#pragma unroll
        for (int mk = 32; mk; mk >>= 1) s += __shfl_xor(s, mk);
        float mean = s * (1.f / 256.f);
        float dx = v.x - mean, dy = v.y - mean, dz = v.z - mean, dw = v.w - mean;
        float q = dx * dx + dy * dy + dz * dz + dw * dw;
#pragma unroll
        for (int mk = 32; mk; mk >>= 1) q += __shfl_xor(q, mk);
        float rstd = rsqrtf(q * (1.f / 256.f) + 1e-5f);
        int grow = row0 + r;
        float4 p4 = ((const float4*)pos)[(size_t)(grow & (N_ - 1)) * 64 + lane];
        float o0 = dx * rstd * g4.x + b4.x + p4.x;
        float o1 = dy * rstd * g4.y + b4.y + p4.y;
        float o2 = dz * rstd * g4.z + b4.z + p4.z;
        float o3 = dw * rstd * g4.w + b4.w + p4.w;
        ((float4*)(H + (size_t)grow * D_))[lane] = (float4){o0, o1, o2, o3};
        ushort4v u = {f2bf(o0), f2bf(o1), f2bf(o2), f2bf(o3)};
        *((ushort4v*)(Hb + (size_t)grow * D_) + lane) = u;
    }
}

// ---------------------------------------------------------------- BN finish+apply merged
__global__ __launch_bounds__(256) void bn_applyfin_kernel(
    const float* __restrict__ x, const float* __restrict__ bnp, int prows,
    const float* __restrict__ g, const float* __restrict__ b,
    float* __restrict__ y, __hip_bfloat16* __restrict__ yb) {
    int tid = threadIdx.x;
    __shared__ float sm[256], sv[256];
    {
        float s = 0.f, s2 = 0.f;
#pragma unroll 4
        for (int yy = 0; yy < prows; yy++) {
            s += bnp[yy * 256 + tid];
            s2 += bnp[32768 + yy * 256 + tid];
        }
        float m = s * (1.f / 8192.f);
        sm[tid] = m;
        sv[tid] = rsqrtf(s2 * (1.f / 8192.f) - m * m + 1e-5f);
    }
    __syncthreads();
    int lane = tid & 63, w = tid >> 6;
    int row0 = blockIdx.x * 32;
    float4 m4 = *(const float4*)&sm[lane * 4];
    float4 r4 = *(const float4*)&sv[lane * 4];
    float4 g4 = ((const float4*)g)[lane];
    float4 b4 = ((const float4*)b)[lane];
#pragma unroll
    for (int rr = 0; rr < 8; rr++) {
        int row = row0 + w * 8 + rr;
        float4 x4 = ((const float4*)(x + (size_t)row * D_))[lane];
        float o0 = (x4.x - m4.x) * r4.x * g4.x + b4.x;
        float o1 = (x4.y - m4.y) * r4.y * g4.y + b4.y;
        float o2 = (x4.z - m4.z) * r4.z * g4.z + b4.z;
        float o3 = (x4.w - m4.w) * r4.w * g4.w + b4.w;
        if (y) ((float4*)(y + (size_t)row * D_))[lane] = (float4){o0, o1, o2, o3};
        if (yb) {
            ushort4v u = {f2bf(o0), f2bf(o1), f2bf(o2), f2bf(o3)};
            *((ushort4v*)(yb + (size_t)row * D_) + lane) = u;
        }
    }
}

// ---------------------------------------------------------------- MFMA attention
__global__ __launch_bounds__(256) void attn_kernel(
    const __hip_bfloat16* __restrict__ qkv, __hip_bfloat16* __restrict__ outb) {
    int bx = blockIdx.x, h = blockIdx.y, b = blockIdx.z;
    int tid = threadIdx.x;
    int wid = tid >> 6, lane = tid & 63;
    __shared__ __hip_bfloat16 Klds[256 * 32];
    __shared__ __hip_bfloat16 Vt[32 * 264];
    const short* q16 = (const short*)qkv;

#pragma unroll
    for (int r = 0; r < 4; r++) {
        int slot = r * 256 + tid;
        int row = slot >> 2, qp = slot & 3;
        int ql = qp ^ ((row >> 1) & 3);
        int jb = bx * 4 - 2 + (row >> 5);
        jb = jb < 0 ? 0 : (jb > 15 ? 15 : jb);
        const short* ga = q16 + ((size_t)(b * N_ + jb * 32 + (row & 31))) * 768 + 256 + h * 32 + ql * 8;
        __builtin_amdgcn_global_load_lds(
            (const __attribute__((address_space(1))) void*)ga,
            (__attribute__((address_space(3))) void*)((char*)Klds + r * 4096 + wid * 1024),
            16, 0, 0);
    }
    {
        int row = tid;
        int jb = bx * 4 - 2 + (row >> 5);
        jb = jb < 0 ? 0 : (jb > 15 ? 15 : jb);
        const short* gv = q16 + ((size_t)(b * N_ + jb * 32 + (row & 31))) * 768 + 512 + h * 32;
        short8 v0 = *(const short8*)(gv);
        short8 v1 = *(const short8*)(gv + 8);
        short8 v2 = *(const short8*)(gv + 16);
        short8 v3 = *(const short8*)(gv + 24);
        short* vt = (short*)Vt;
#pragma unroll
        for (int e = 0; e < 8; e++) {
            vt[(e) * 264 + row] = v0[e];
            vt[(8 + e) * 264 + row] = v1[e];
            vt[(16 + e) * 264 + row] = v2[e];
            vt[(24 + e) * 264 + row] = v3[e];
        }
    }
    __syncthreads();

    int i = bx * 4 + wid;
    int c = lane & 15, g = lane >> 4;
    const float scale = 0.17677669529663687f;

#pragma unroll
    for (int qt = 0; qt < 2; qt++) {
        const short* qa = q16 + ((size_t)(b * N_ + i * 32 + qt * 16 + c)) * 768 + h * 32 + g * 8;
        short8 bq = *(const short8*)qa;
        f32x4 st[10];
#pragma unroll
        for (int t = 0; t < 10; t++) {
            int jb = i - 2 + (t >> 1);
            if (jb >= 0 && jb < NBLK_) {
                int row = wid * 32 + t * 16 + c;
                int phys = g ^ ((row >> 1) & 3);
                short8 ak = *(const short8*)((const char*)Klds + row * 64 + phys * 16);
                st[t] = __builtin_amdgcn_mfma_f32_16x16x32_bf16(
                    ak, bq, (f32x4){0.f, 0.f, 0.f, 0.f}, 0, 0, 0);
            }
        }
        float mx = -1e30f;
#pragma unroll
        for (int t = 0; t < 10; t++) {
            int jb = i - 2 + (t >> 1);
            if (jb >= 0 && jb < NBLK_) {
#pragma unroll
                for (int j = 0; j < 4; j++) {
                    st[t][j] *= scale;
                    mx = fmaxf(mx, st[t][j]);
                }
            }
        }
        mx = fmaxf(mx, __shfl_xor(mx, 16));
        mx = fmaxf(mx, __shfl_xor(mx, 32));
        float sum = 0.f;
#pragma unroll
        for (int t = 0; t < 10; t++) {
            int jb = i - 2 + (t >> 1);
            if (jb >= 0 && jb < NBLK_) {
#pragma unroll
                for (int j = 0; j < 4; j++) {
                    float e = __expf(st[t][j] - mx);
                    st[t][j] = e;
                    sum += e;
                }
            }
        }
        sum += __shfl_xor(sum, 16);
        sum += __shfl_xor(sum, 32);
        float inv = 1.f / sum;
        f32x4 o0 = (f32x4){0.f, 0.f, 0.f, 0.f};
        f32x4 o1 = (f32x4){0.f, 0.f, 0.f, 0.f};
        const short* vt = (const short*)Vt;
#pragma unroll
        for (int t = 0; t < 10; t++) {
            int jb = i - 2 + (t >> 1);
            if (jb >= 0 && jb < NBLK_) {
                short8 pa = (short8)0;
#pragma unroll
                for (int j = 0; j < 4; j++) pa[j] = (short)f2bf(st[t][j] * inv);
                int kb = wid * 32 + t * 16 + g * 4;
                short4v vb0 = *(const short4v*)(vt + (0 * 16 + c) * 264 + kb);
                short4v vb1 = *(const short4v*)(vt + (1 * 16 + c) * 264 + kb);
                short8 b0 = (short8)0, b1 = (short8)0;
#pragma unroll
                for (int e = 0; e < 4; e++) { b0[e] = vb0[e]; b1[e] = vb1[e]; }
                o0 = __builtin_amdgcn_mfma_f32_16x16x32_bf16(pa, b0, o0, 0, 0, 0);
                o1 = __builtin_amdgcn_mfma_f32_16x16x32_bf16(pa, b1, o1, 0, 0, 0);
            }
        }
#pragma unroll
        for (int j = 0; j < 4; j++) {
            size_t rbase = ((size_t)(b * N_ + i * 32 + qt * 16 + g * 4 + j)) * D_ + h * DH_;
            outb[rbase + c] = __float2bfloat16(o0[j]);
            outb[rbase + 16 + c] = __float2bfloat16(o1[j]);
        }
    }
}

// ---------------------------------------------------------------- fcl
__global__ __launch_bounds__(256) void fcl_partial_kernel(
    const float* __restrict__ flat, const float* __restrict__ W,
    float* __restrict__ partial) {
    int chunk = blockIdx.x;             // 1280
    int t = threadIdx.x;
    int k0 = chunk * FCL_KB;
    __shared__ float fl[FCL_KB][20];
#pragma unroll
    for (int b = 0; b < 16; b++)
        fl[t][b] = flat[(size_t)b * FCL_K + k0 + t];
    __syncthreads();
    int j = t & 127, bg = t >> 7;
    f32x4 a0 = (f32x4){0.f, 0.f, 0.f, 0.f};
    f32x4 a1 = (f32x4){0.f, 0.f, 0.f, 0.f};
#pragma unroll 8
    for (int k = 0; k < FCL_KB; k++) {
        float w = W[(size_t)(k0 + k) * 128 + j];
        f32x4 f0 = *(const f32x4*)&fl[k][bg * 8];
        f32x4 f1 = *(const f32x4*)&fl[k][bg * 8 + 4];
        a0 += f0 * w;
        a1 += f1 * w;
    }
#pragma unroll
    for (int bi = 0; bi < 4; bi++) {
        partial[((size_t)chunk * 16 + bg * 8 + bi) * 128 + j] = a0[bi];
        partial[((size_t)chunk * 16 + bg * 8 + 4 + bi) * 128 + j] = a1[bi];
    }
}

__global__ __launch_bounds__(256) void fcl_reduce_kernel(
    const float* __restrict__ partial, const float* __restrict__ fcl_b,
    float* __restrict__ add) {
    int c0 = blockIdx.x * 32;
    int t = threadIdx.x;
    int ry = t >> 5, cx = t & 31;
    float s = 0.f;
    for (int r = ry; r < FCL_CHUNKS; r += 8)
        s += partial[(size_t)r * 2048 + c0 + cx];
    __shared__ float red[8][32];
    red[ry][cx] = s; __syncthreads();
    if (ry == 0) {
        float tot = 0.f;
#pragma unroll
        for (int q = 0; q < 8; q++) tot += red[q][cx];
        int col = c0 + cx;
        add[col] = tot + fcl_b[col & 127];
    }
}

// ---------------------------------------------------------------- fused head
__global__ __launch_bounds__(256) void head_kernel(
    const float* __restrict__ add, const float* __restrict__ abg, const float* __restrict__ abb,
    const float* __restrict__ cls_W1, const float* __restrict__ cls_b1,
    const float* __restrict__ cls_W2, const float* __restrict__ cls_b2,
    const float* __restrict__ box_W1, const float* __restrict__ box_b1,
    const float* __restrict__ box_W2, const float* __restrict__ box_b2,
    float* __restrict__ out) {
    __shared__ float a2[16][128];
    __shared__ float cm[16][256];
    __shared__ float cls[16][45];
    __shared__ float bmid[16][128];
    __shared__ float smden[16];
    int t = threadIdx.x;
    if (t < 128) {
        float m = 0.f;
#pragma unroll
        for (int b = 0; b < 16; b++) m += add[b * 128 + t];
        m *= (1.f / 16.f);
        float v = 0.f;
#pragma unroll
        for (int b = 0; b < 16; b++) { float d = add[b * 128 + t] - m; v += d * d; }
        v *= (1.f / 16.f);
        float sc = rsqrtf(v + 1e-5f) * abg[t];
#pragma unroll
        for (int b = 0; b < 16; b++) a2[b][t] = (add[b * 128 + t] - m) * sc + abb[t];
    }
    __syncthreads();
    for (int idx = t; idx < 4096; idx += 256) {
        int m = idx >> 8, c = idx & 255;
        float a = cls_b1[c];
        for (int k = 0; k < 128; k++) a += a2[m][k] * cls_W1[k * 256 + c];
        cm[m][c] = fmaxf(a, 0.f);
    }
    for (int idx = t; idx < 2048; idx += 256) {
        int m = idx >> 7, c = idx & 127;
        float a = box_b1[c];
        for (int k = 0; k < 128; k++) a += a2[m][k] * box_W1[k * 128 + c];
        bmid[m][c] = fmaxf(a, 0.f);
    }
    __syncthreads();
    for (int idx = t; idx < 720; idx += 256) {
        int m = idx / 45, c = idx % 45;
        float a = cls_b2[c];
        for (int k = 0; k < 256; k++) a += cm[m][k] * cls_W2[k * 45 + c];
        cls[m][c] = a;
    }
    __syncthreads();
    if (t < 16) {
        float mx = -1e30f;
        for (int c = 0; c < 45; c++) mx = fmaxf(mx, cls[t][c]);
        float s = 0.f;
        for (int c = 0; c < 45; c++) { float e = expf(cls[t][c] - mx); cls[t][c] = e; s += e; }
        smden[t] = s;
    }
    for (int idx = t; idx < 576; idx += 256) {
        int m = idx / 36, c = idx % 36;
        float a = box_b2[c];
        for (int k = 0; k < 128; k++) a += bmid[m][k] * box_W2[k * 36 + c];
        out[m * 81 + (c >> 2) * 9 + 5 + (c & 3)] = a;
    }
    __syncthreads();
    for (int idx = t; idx < 720; idx += 256) {
        int m = idx / 45, c = idx % 45;
        out[m * 81 + (c / 5) * 9 + (c % 5)] = cls[m][c] / smden[m];
    }
}

// ================================================================ launcher
extern "C" void kernel_launch(void* const* d_in, const int* in_sizes, int n_in,
                              void* d_out, int out_size, void* d_ws, size_t ws_size,
                              hipStream_t stream) {
    const float* x_in    = (const float*)d_in[0];
    const float* patch_W = (const float*)d_in[1];
    const float* patch_b = (const float*)d_in[2];
    const float* ln_g    = (const float*)d_in[3];
    const float* ln_b    = (const float*)d_in[4];
    const float* ff_W1   = (const float*)d_in[5];
    const float* ff_b1   = (const float*)d_in[6];
    const float* ff_W2   = (const float*)d_in[7];
    const float* ff_b2   = (const float*)d_in[8];
    const float* Wqkv    = (const float*)d_in[9];
    const float* bqkv    = (const float*)d_in[10];
    const float* Wo      = (const float*)d_in[11];
    const float* bo      = (const float*)d_in[12];
    const float* bn1_g   = (const float*)d_in[13];
    const float* bn1_b   = (const float*)d_in[14];
    const float* bn2_g   = (const float*)d_in[15];
    const float* bn2_b   = (const float*)d_in[16];
    const float* pyr_W   = (const float*)d_in[17];
    const float* pyr_b   = (const float*)d_in[18];
    const float* fcl_W   = (const float*)d_in[19];
    const float* fcl_b   = (const float*)d_in[20];
    const float* addbn_g = (const float*)d_in[21];
    const float* addbn_b = (const float*)d_in[22];
    const float* cls_W1  = (const float*)d_in[23];
    const float* cls_b1  = (const float*)d_in[24];
    const float* cls_W2  = (const float*)d_in[25];
    const float* cls_b2  = (const float*)d_in[26];
    const float* box_W1  = (const float*)d_in[27];
    const float* box_b1  = (const float*)d_in[28];
    const float* box_W2  = (const float*)d_in[29];
    const float* box_b2  = (const float*)d_in[30];
    float* out = (float*)d_out;

    float* ws = (float*)d_ws;
    size_t off = 0;
    float* POS   = ws + off; off += 131072;
    float* H     = ws + off; off += 2097152;
    float* T     = ws + off; off += 2097152;
    float* UNION = ws + off; off += 4194304;   // MIDb bf16 / QKVb bf16
    float* FLAT  = ws + off; off += 5242880;
    float* PART  = ws + off; off += (size_t)FCL_CHUNKS * 2048;
    float* BNP   = ws + off; off += 2 * 32768;
    float* ADD   = ws + off; off += 2048;
    __hip_bfloat16* Hb   = (__hip_bfloat16*)(ws + off); off += 1048576;
    __hip_bfloat16* Tb   = (__hip_bfloat16*)(ws + off); off += 1048576;
    __hip_bfloat16* Xb   = (__hip_bfloat16*)(ws + off); off += 1048576;
    __hip_bfloat16* ATb  = (__hip_bfloat16*)(ws + off); off += 1048576;
    __hip_bfloat16* patchWt = (__hip_bfloat16*)(ws + off); off += 32768;
    __hip_bfloat16* qkvWt   = (__hip_bfloat16*)(ws + off); off += 98304;
    __hip_bfloat16* WoWt    = (__hip_bfloat16*)(ws + off); off += 32768;
    __hip_bfloat16* W1t     = (__hip_bfloat16*)(ws + off); off += 131072;
    __hip_bfloat16* W2t     = (__hip_bfloat16*)(ws + off); off += 131072;
    __hip_bfloat16* pyrWt   = (__hip_bfloat16*)(ws + off); off += 81920;
    __hip_bfloat16* MIDb = (__hip_bfloat16*)UNION;
    __hip_bfloat16* QKVb = (__hip_bfloat16*)UNION;

    prep_kernel<<<2528, 256, 0, stream>>>(
        patch_W, Wqkv, Wo, ff_W1, ff_W2, pyr_W, x_in,
        patchWt, qkvWt, WoWt, W1t, W2t, pyrWt, POS, Xb);

    for (int it = 0; it < 5; it++) {
        patchln_kernel<<<256, 256, 0, stream>>>(Xb, patchWt, patch_b, ln_g, ln_b, POS, H, Hb);
        // FF1: 128x128 tile, grid 512 (2/CU)
        bgemm_kernel<1, false, true, false, false, 128, 128><<<dim3(8, 64), 256, 0, stream>>>(
            Hb, W1t, ff_b1, nullptr, nullptr, MIDb, ROWS_, HIDEF_, D_, 0, nullptr);
        // FF2: 64x64 tile, grid 512 (2/CU)
        bgemm_kernel<0, false, true, false, false, 64, 64><<<dim3(4, 128), 256, 0, stream>>>(
            MIDb, W2t, ff_b2, nullptr, nullptr, Tb, ROWS_, D_, HIDEF_, 0, nullptr);
        // qkv: 128x64, grid 768 (3/CU)
        bgemm_kernel<0, false, true, false, false, 128, 64><<<dim3(12, 64), 256, 0, stream>>>(
            Tb, qkvWt, bqkv, nullptr, nullptr, QKVb, ROWS_, 768, D_, 0, nullptr);
        attn_kernel<<<dim3(4, HEADS_, B_), 256, 0, stream>>>(QKVb, ATb);
        // proj (+resid, STATS): 64x64, grid 512
        bgemm_kernel<0, true, false, false, true, 64, 64><<<dim3(4, 128), 256, 0, stream>>>(
            ATb, WoWt, bo, H, T, nullptr, ROWS_, D_, D_, 0, BNP);
        bn_applyfin_kernel<<<256, 256, 0, stream>>>(T, BNP, 128, bn1_g, bn1_b, H, Hb);
        bgemm_kernel<1, false, true, false, false, 128, 128><<<dim3(8, 64), 256, 0, stream>>>(
            Hb, W1t, ff_b1, nullptr, nullptr, MIDb, ROWS_, HIDEF_, D_, 0, nullptr);
        bgemm_kernel<0, true, false, false, true, 64, 64><<<dim3(4, 128), 256, 0, stream>>>(
            MIDb, W2t, ff_b2, H, T, nullptr, ROWS_, D_, HIDEF_, 0, BNP);
        bn_applyfin_kernel<<<256, 256, 0, stream>>>(T, BNP, 128, bn2_g, bn2_b, nullptr, Xb);
        // pyramid: 64x64 SCAT, grid 256 (M=128 -> 2 row blocks)
        bgemm_kernel<0, false, false, true, false, 64, 64><<<dim3(128, 2), 256, 0, stream>>>(
            pyrWt + (size_t)it * D_ * PYOUT_, Xb, pyr_b + it * PYOUT_, nullptr,
            FLAT, nullptr, PYOUT_, ROWS_, D_, it, nullptr);
    }

    fcl_partial_kernel<<<FCL_CHUNKS, 256, 0, stream>>>(FLAT, fcl_W, PART);
    fcl_reduce_kernel<<<64, 256, 0, stream>>>(PART, fcl_b, ADD);
    head_kernel<<<1, 256, 0, stream>>>(ADD, addbn_g, addbn_b,
        cls_W1, cls_b1, cls_W2, cls_b2, box_W1, box_b1, box_W2, box_b2, out);
    (void)in_sizes; (void)n_in; (void)out_size; (void)ws_size;
}

// Round 9
// 916.390 us; speedup vs baseline: 5.0640x; 1.0038x over previous
//
#include <hip/hip_runtime.h>
#include <hip/hip_bf16.h>
#include <math.h>

#define B_ 16
#define N_ 512
#define D_ 256
#define HEADS_ 8
#define DH_ 32
#define HIDEF_ 1024
#define NBLK_ 16
#define BS_ 32
#define LEVELS_ 5
#define PYOUT_ 128
#define ROWS_ (B_ * N_)   // 8192
#define FCL_K 327680
#define FCL_KB 256
#define FCL_CHUNKS 1280

typedef __attribute__((ext_vector_type(8))) short short8;
typedef __attribute__((ext_vector_type(4))) short short4v;
typedef __attribute__((ext_vector_type(4))) unsigned short ushort4v;
typedef __attribute__((ext_vector_type(4))) float f32x4;

__device__ __forceinline__ float bf2f(short u) {
    return __uint_as_float(((unsigned int)(unsigned short)u) << 16);
}
__device__ __forceinline__ unsigned short f2bf(float x) {
    __hip_bfloat16 h = __float2bfloat16(x);
    return *reinterpret_cast<unsigned short*>(&h);
}

__device__ __forceinline__ float gelu_f(float x) {
    float x3 = x * x * x;
    return 0.5f * x * (1.f + tanhf(0.7978845608028654f * (x + 0.044715f * x3)));
}

// ---------------------------------------------------------------- combined prep
__global__ __launch_bounds__(256) void prep_kernel(
    const float* __restrict__ patch_W, const float* __restrict__ Wqkv,
    const float* __restrict__ Wo, const float* __restrict__ ff_W1,
    const float* __restrict__ ff_W2, const float* __restrict__ pyr_W,
    const float* __restrict__ x_in,
    __hip_bfloat16* __restrict__ patchWt, __hip_bfloat16* __restrict__ qkvWt,
    __hip_bfloat16* __restrict__ WoWt, __hip_bfloat16* __restrict__ W1t,
    __hip_bfloat16* __restrict__ W2t, __hip_bfloat16* __restrict__ pyrWt,
    float* __restrict__ pos, __hip_bfloat16* __restrict__ Xb) {
    __shared__ float tt[32][33];
    int bid = blockIdx.x, t = threadIdx.x;
    if (bid >= 1504) {           // x -> bf16, 2048 elems/block
        int base = (bid - 1504) * 2048 + t * 8;
        float4 a = *(const float4*)&x_in[base];
        float4 b = *(const float4*)&x_in[base + 4];
        ushort4v u0 = {f2bf(a.x), f2bf(a.y), f2bf(a.z), f2bf(a.w)};
        ushort4v u1 = {f2bf(b.x), f2bf(b.y), f2bf(b.z), f2bf(b.w)};
        *(ushort4v*)((short*)Xb + base) = u0;
        *(ushort4v*)((short*)Xb + base + 4) = u1;
        return;
    }
    if (bid >= 992) {            // pos table
        int idx = (bid - 992) * 256 + t;
        int n = idx >> 8, i = idx & 255;
        double angle = (double)n / pow(10000.0, (double)(2 * (i >> 1)) / 256.0);
        pos[idx] = (float)((i & 1) ? cos(angle) : sin(angle));
        return;
    }
    const float* W; __hip_bfloat16* Wt; int K, N, bx, by;
    if (bid < 64)       { W = patch_W; Wt = patchWt; K = 256; N = 256; bx = bid % 8; by = bid / 8; }
    else if (bid < 256) { int l = bid - 64;  W = Wqkv;  Wt = qkvWt; K = 256; N = 768;  bx = l % 24; by = l / 24; }
    else if (bid < 320) { int l = bid - 256; W = Wo;    Wt = WoWt;  K = 256; N = 256;  bx = l % 8;  by = l / 8; }
    else if (bid < 576) { int l = bid - 320; W = ff_W1; Wt = W1t;   K = 256; N = 1024; bx = l % 32; by = l / 32; }
    else if (bid < 832) { int l = bid - 576; W = ff_W2; Wt = W2t;   K = 1024; N = 256; bx = l % 8;  by = l / 8; }
    else                { int l = bid - 832; int z = l / 32; int r = l % 32;
                          W = pyr_W + (size_t)z * 256 * 128; Wt = pyrWt + (size_t)z * 256 * 128;
                          K = 256; N = 128; bx = r % 4; by = r / 4; }
    int bx32 = bx * 32, by32 = by * 32;
    int tx = t & 31, ty = t >> 5;
#pragma unroll
    for (int i = 0; i < 32; i += 8)
        tt[ty + i][tx] = W[(size_t)(by32 + ty + i) * N + bx32 + tx];
    __syncthreads();
#pragma unroll
    for (int i = 0; i < 32; i += 8)
        Wt[(size_t)(bx32 + ty + i) * K + by32 + tx] = __float2bfloat16(tt[tx][ty + i]);
}

// ---------------------------------------------------------------- bf16 MFMA GEMM
// BK=64, DOUBLE-BUFFERED (2-phase): stage(t+1) issued before compute(t),
// single __syncthreads per K-step (its vmcnt(0) drain lands after compute).
template <int ACT, bool OUTF, bool OUTB, bool SCAT, bool STATS, int BM, int BN>
__global__ __launch_bounds__(256) void bgemm_kernel(
    const __hip_bfloat16* __restrict__ A, const __hip_bfloat16* __restrict__ Wt,
    const float* __restrict__ bias, const float* __restrict__ resid,
    float* __restrict__ C, __hip_bfloat16* __restrict__ Cb, int M, int Nn, int K,
    int level, float* __restrict__ bnp) {
    __shared__ __hip_bfloat16 Alds[2][BM * 64];
    __shared__ __hip_bfloat16 Blds[2][BN * 64];
    constexpr int WM_ = (BM == 128 && BN == 64) ? 4 : 2;
    constexpr int WN_ = 4 / WM_;
    constexpr int WH = BM / WM_;
    constexpr int WC = BN / WN_;
    constexpr int MW = WH / 16;
    constexpr int NW = WC / 16;
    constexpr int AR = BM / 32;
    constexpr int BR = BN / 32;
    int tid = threadIdx.x;
    int wid = tid >> 6, lane = tid & 63;
    int row0 = blockIdx.y * BM, col0 = blockIdx.x * BN;
    int wr = wid / WN_, wc = wid % WN_;
    int r16 = lane & 15, kq = lane >> 4;

    f32x4 acc[MW][NW];
#pragma unroll
    for (int m = 0; m < MW; m++)
#pragma unroll
        for (int n = 0; n < NW; n++) acc[m][n] = (f32x4){0.f, 0.f, 0.f, 0.f};

    // ---- stage lambda (async global_load_lds into buffer b at k-offset k0)
    auto stage = [&](int b, int k0) {
#pragma unroll
        for (int i = 0; i < AR; i++) {
            int slot = i * 256 + tid;
            int row = slot >> 3, qp = slot & 7;
            int q = qp ^ ((row >> 1) & 7);
            const __hip_bfloat16* ga = A + (size_t)(row0 + row) * K + k0 + q * 8;
            __builtin_amdgcn_global_load_lds(
                (const __attribute__((address_space(1))) void*)ga,
                (__attribute__((address_space(3))) void*)((char*)&Alds[b][0] + i * 4096 + wid * 1024),
                16, 0, 0);
        }
#pragma unroll
        for (int i = 0; i < BR; i++) {
            int slot = i * 256 + tid;
            int row = slot >> 3, qp = slot & 7;
            int q = qp ^ ((row >> 1) & 7);
            const __hip_bfloat16* gb = Wt + (size_t)(col0 + row) * K + k0 + q * 8;
            __builtin_amdgcn_global_load_lds(
                (const __attribute__((address_space(1))) void*)gb,
                (__attribute__((address_space(3))) void*)((char*)&Blds[b][0] + i * 4096 + wid * 1024),
                16, 0, 0);
        }
    };

    stage(0, 0);
    __syncthreads();
    int cur = 0;
    for (int k0 = 0; k0 < K; k0 += 64) {
        if (k0 + 64 < K) stage(cur ^ 1, k0 + 64);
#pragma unroll
        for (int h = 0; h < 2; h++) {
            short8 af[MW], bf4[NW];
#pragma unroll
            for (int m = 0; m < MW; m++) {
                int row = wr * WH + m * 16 + r16;
                int phys = (h * 4 + kq) ^ ((row >> 1) & 7);
                af[m] = *reinterpret_cast<const short8*>(
                    reinterpret_cast<const char*>(&Alds[cur][0]) + row * 128 + phys * 16);
            }
#pragma unroll
            for (int n = 0; n < NW; n++) {
                int row = wc * WC + n * 16 + r16;
                int phys = (h * 4 + kq) ^ ((row >> 1) & 7);
                bf4[n] = *reinterpret_cast<const short8*>(
                    reinterpret_cast<const char*>(&Blds[cur][0]) + row * 128 + phys * 16);
            }
#pragma unroll
            for (int m = 0; m < MW; m++)
#pragma unroll
                for (int n = 0; n < NW; n++)
                    acc[m][n] = __builtin_amdgcn_mfma_f32_16x16x32_bf16(af[m], bf4[n], acc[m][n], 0, 0, 0);
        }
        __syncthreads();
        cur ^= 1;
    }

    int rg = lane >> 4;
    float s1a[NW], s2a[NW];
#pragma unroll
    for (int n = 0; n < NW; n++) { s1a[n] = 0.f; s2a[n] = 0.f; }
    if (SCAT) {
#pragma unroll
        for (int n = 0; n < NW; n++) {
            int cc = col0 + wc * WC + n * 16 + r16;
            int bb = cc >> 9, nn = cc & 511;
            float* dst = C + (size_t)bb * (LEVELS_ * PYOUT_ * N_) +
                         (size_t)level * PYOUT_ * N_ + nn;
#pragma unroll
            for (int m = 0; m < MW; m++) {
                int rbase = row0 + wr * WH + m * 16 + rg * 4;
#pragma unroll
                for (int j = 0; j < 4; j++) {
                    int ch = rbase + j;
                    dst[(size_t)ch * N_] = acc[m][n][j] + bias[ch];
                }
            }
        }
    } else {
#pragma unroll
        for (int n = 0; n < NW; n++) {
            int cc = col0 + wc * WC + n * 16 + r16;
            float bv = bias[cc];
#pragma unroll
            for (int m = 0; m < MW; m++) {
                int rb = row0 + wr * WH + m * 16 + rg * 4;
#pragma unroll
                for (int j = 0; j < 4; j++) {
                    int r = rb + j;
                    float v = acc[m][n][j] + bv;
                    if (resid) v += resid[(size_t)r * Nn + cc];
                    if (ACT == 1) v = gelu_f(v);
                    if (OUTF) C[(size_t)r * Nn + cc] = v;
                    if (OUTB) Cb[(size_t)r * Nn + cc] = __float2bfloat16(v);
                    if (STATS) { s1a[n] += v; s2a[n] += v * v; }
                }
            }
        }
    }
    if (STATS) {
        float* sc = (float*)&Alds[0][0];
        int part = wid * 4 + rg;
#pragma unroll
        for (int n = 0; n < NW; n++) {
            int c = wc * WC + n * 16 + r16;
            sc[c * 16 + part] = s1a[n];
            sc[BN * 16 + c * 16 + part] = s2a[n];
        }
        __syncthreads();
        if (tid < BN) {
            float a = 0.f, b2 = 0.f;
#pragma unroll
            for (int p = 0; p < 16; p++) {
                a += sc[tid * 16 + p];
                b2 += sc[BN * 16 + tid * 16 + p];
            }
            bnp[blockIdx.y * 256 + col0 + tid] = a;
            bnp[32768 + blockIdx.y * 256 + col0 + tid] = b2;
        }
    }
}

// ---------------------------------------------------------------- fused patch GEMM + LN + pos
// Double-buffered: A 2x4KB @0, B 2x32KB @8192. Cls overlay after compute.
__global__ __launch_bounds__(256) void patchln_kernel(
    const __hip_bfloat16* __restrict__ A, const __hip_bfloat16* __restrict__ Wt,
    const float* __restrict__ bias, const float* __restrict__ lng,
    const float* __restrict__ lnb, const float* __restrict__ pos,
    float* __restrict__ H, __hip_bfloat16* __restrict__ Hb) {
    __shared__ char __attribute__((aligned(16))) smem[73728];
    float (*Cls)[260] = (float(*)[260])smem;
    int tid = threadIdx.x;
    int wid = tid >> 6, lane = tid & 63;
    int row0 = blockIdx.x * 32;
    int r16 = lane & 15, kq = lane >> 4, g = lane >> 4;

    f32x4 acc[2][4];
#pragma unroll
    for (int m = 0; m < 2; m++)
#pragma unroll
        for (int n = 0; n < 4; n++) acc[m][n] = (f32x4){0.f, 0.f, 0.f, 0.f};

    auto stage = [&](int b, int k0) {
        {
            int row = tid >> 3, qp = tid & 7;
            int q = qp ^ ((row >> 1) & 7);
            const __hip_bfloat16* ga = A + (size_t)(row0 + row) * 256 + k0 + q * 8;
            __builtin_amdgcn_global_load_lds(
                (const __attribute__((address_space(1))) void*)ga,
                (__attribute__((address_space(3))) void*)(smem + b * 4096 + wid * 1024),
                16, 0, 0);
        }
#pragma unroll
        for (int i = 0; i < 8; i++) {
            int slot = i * 256 + tid;
            int row = slot >> 3, qp = slot & 7;
            int q = qp ^ ((row >> 1) & 7);
            const __hip_bfloat16* gb = Wt + (size_t)row * 256 + k0 + q * 8;
            __builtin_amdgcn_global_load_lds(
                (const __attribute__((address_space(1))) void*)gb,
                (__attribute__((address_space(3))) void*)(smem + 8192 + b * 32768 + i * 4096 + wid * 1024),
                16, 0, 0);
        }
    };

    stage(0, 0);
    __syncthreads();
    int cur = 0;
    for (int k0 = 0; k0 < 256; k0 += 64) {
        if (k0 + 64 < 256) stage(cur ^ 1, k0 + 64);
        const char* Ab = smem + cur * 4096;
        const char* Bb = smem + 8192 + cur * 32768;
#pragma unroll
        for (int h = 0; h < 2; h++) {
            short8 af[2], bf4[4];
#pragma unroll
            for (int m = 0; m < 2; m++) {
                int row = m * 16 + r16;
                int phys = (h * 4 + kq) ^ ((row >> 1) & 7);
                af[m] = *reinterpret_cast<const short8*>(Ab + row * 128 + phys * 16);
            }
#pragma unroll
            for (int n = 0; n < 4; n++) {
                int row = wid * 64 + n * 16 + r16;
                int phys = (h * 4 + kq) ^ ((row >> 1) & 7);
                bf4[n] = *reinterpret_cast<const short8*>(Bb + row * 128 + phys * 16);
            }
#pragma unroll
            for (int m = 0; m < 2; m++)
#pragma unroll
                for (int n = 0; n < 4; n++)
                    acc[m][n] = __builtin_amdgcn_mfma_f32_16x16x32_bf16(af[m], bf4[n], acc[m][n], 0, 0, 0);
        }
        __syncthreads();
        cur ^= 1;
    }
#pragma unroll
    for (int n = 0; n < 4; n++) {
        int col = wid * 64 + n * 16 + r16;
        float bv = bias[col];
#pragma unroll
        for (int m = 0; m < 2; m++)
#pragma unroll
            for (int j = 0; j < 4; j++)
                Cls[m * 16 + g * 4 + j][col] = acc[m][n][j] + bv;
    }
    __syncthreads();
    float4 g4 = ((const float4*)lng)[lane];
    float4 b4 = ((const float4*)lnb)[lane];
#pragma unroll
    for (int rr = 0; rr < 8; rr++) {
        int r = wid * 8 + rr;
        float4 v = *(const float4*)&Cls[r][lane * 4];
        float s = v.x + v.y + v.z + v.w;
#pragma unroll
        for (int mk = 32; mk; mk >>= 1) s += __shfl_xor(s, mk);
        float mean = s * (1.f / 256.f);
        float dx = v.x - mean, dy = v.y - mean, dz = v.z - mean, dw = v.w - mean;
        float q = dx * dx + dy * dy + dz * dz + dw * dw;
#pragma unroll
        for (int mk = 32; mk; mk >>= 1) q += __shfl_xor(q, mk);
        float rstd = rsqrtf(q * (1.f / 256.f) + 1e-5f);
        int grow = row0 + r;
        float4 p4 = ((const float4*)pos)[(size_t)(grow & (N_ - 1)) * 64 + lane];
        float o0 = dx * rstd * g4.x + b4.x + p4.x;
        float o1 = dy * rstd * g4.y + b4.y + p4.y;
        float o2 = dz * rstd * g4.z + b4.z + p4.z;
        float o3 = dw * rstd * g4.w + b4.w + p4.w;
        ((float4*)(H + (size_t)grow * D_))[lane] = (float4){o0, o1, o2, o3};
        ushort4v u = {f2bf(o0), f2bf(o1), f2bf(o2), f2bf(o3)};
        *((ushort4v*)(Hb + (size_t)grow * D_) + lane) = u;
    }
}

// ---------------------------------------------------------------- BN finish+apply merged
__global__ __launch_bounds__(256) void bn_applyfin_kernel(
    const float* __restrict__ x, const float* __restrict__ bnp, int prows,
    const float* __restrict__ g, const float* __restrict__ b,
    float* __restrict__ y, __hip_bfloat16* __restrict__ yb) {
    int tid = threadIdx.x;
    __shared__ float sm[256], sv[256];
    {
        float s = 0.f, s2 = 0.f;
#pragma unroll 4
        for (int yy = 0; yy < prows; yy++) {
            s += bnp[yy * 256 + tid];
            s2 += bnp[32768 + yy * 256 + tid];
        }
        float m = s * (1.f / 8192.f);
        sm[tid] = m;
        sv[tid] = rsqrtf(s2 * (1.f / 8192.f) - m * m + 1e-5f);
    }
    __syncthreads();
    int lane = tid & 63, w = tid >> 6;
    int row0 = blockIdx.x * 32;
    float4 m4 = *(const float4*)&sm[lane * 4];
    float4 r4 = *(const float4*)&sv[lane * 4];
    float4 g4 = ((const float4*)g)[lane];
    float4 b4 = ((const float4*)b)[lane];
#pragma unroll
    for (int rr = 0; rr < 8; rr++) {
        int row = row0 + w * 8 + rr;
        float4 x4 = ((const float4*)(x + (size_t)row * D_))[lane];
        float o0 = (x4.x - m4.x) * r4.x * g4.x + b4.x;
        float o1 = (x4.y - m4.y) * r4.y * g4.y + b4.y;
        float o2 = (x4.z - m4.z) * r4.z * g4.z + b4.z;
        float o3 = (x4.w - m4.w) * r4.w * g4.w + b4.w;
        if (y) ((float4*)(y + (size_t)row * D_))[lane] = (float4){o0, o1, o2, o3};
        if (yb) {
            ushort4v u = {f2bf(o0), f2bf(o1), f2bf(o2), f2bf(o3)};
            *((ushort4v*)(yb + (size_t)row * D_) + lane) = u;
        }
    }
}

// ---------------------------------------------------------------- MFMA attention
__global__ __launch_bounds__(256) void attn_kernel(
    const __hip_bfloat16* __restrict__ qkv, __hip_bfloat16* __restrict__ outb) {
    int bx = blockIdx.x, h = blockIdx.y, b = blockIdx.z;
    int tid = threadIdx.x;
    int wid = tid >> 6, lane = tid & 63;
    __shared__ __hip_bfloat16 Klds[256 * 32];
    __shared__ __hip_bfloat16 Vt[32 * 264];
    const short* q16 = (const short*)qkv;

#pragma unroll
    for (int r = 0; r < 4; r++) {
        int slot = r * 256 + tid;
        int row = slot >> 2, qp = slot & 3;
        int ql = qp ^ ((row >> 1) & 3);
        int jb = bx * 4 - 2 + (row >> 5);
        jb = jb < 0 ? 0 : (jb > 15 ? 15 : jb);
        const short* ga = q16 + ((size_t)(b * N_ + jb * 32 + (row & 31))) * 768 + 256 + h * 32 + ql * 8;
        __builtin_amdgcn_global_load_lds(
            (const __attribute__((address_space(1))) void*)ga,
            (__attribute__((address_space(3))) void*)((char*)Klds + r * 4096 + wid * 1024),
            16, 0, 0);
    }
    {
        int row = tid;
        int jb = bx * 4 - 2 + (row >> 5);
        jb = jb < 0 ? 0 : (jb > 15 ? 15 : jb);
        const short* gv = q16 + ((size_t)(b * N_ + jb * 32 + (row & 31))) * 768 + 512 + h * 32;
        short8 v0 = *(const short8*)(gv);
        short8 v1 = *(const short8*)(gv + 8);
        short8 v2 = *(const short8*)(gv + 16);
        short8 v3 = *(const short8*)(gv + 24);
        short* vt = (short*)Vt;
#pragma unroll
        for (int e = 0; e < 8; e++) {
            vt[(e) * 264 + row] = v0[e];
            vt[(8 + e) * 264 + row] = v1[e];
            vt[(16 + e) * 264 + row] = v2[e];
            vt[(24 + e) * 264 + row] = v3[e];
        }
    }
    __syncthreads();

    int i = bx * 4 + wid;
    int c = lane & 15, g = lane >> 4;
    const float scale = 0.17677669529663687f;

#pragma unroll
    for (int qt = 0; qt < 2; qt++) {
        const short* qa = q16 + ((size_t)(b * N_ + i * 32 + qt * 16 + c)) * 768 + h * 32 + g * 8;
        short8 bq = *(const short8*)qa;
        f32x4 st[10];
#pragma unroll
        for (int t = 0; t < 10; t++) {
            int jb = i - 2 + (t >> 1);
            if (jb >= 0 && jb < NBLK_) {
                int row = wid * 32 + t * 16 + c;
                int phys = g ^ ((row >> 1) & 3);
                short8 ak = *(const short8*)((const char*)Klds + row * 64 + phys * 16);
                st[t] = __builtin_amdgcn_mfma_f32_16x16x32_bf16(
                    ak, bq, (f32x4){0.f, 0.f, 0.f, 0.f}, 0, 0, 0);
            }
        }
        float mx = -1e30f;
#pragma unroll
        for (int t = 0; t < 10; t++) {
            int jb = i - 2 + (t >> 1);
            if (jb >= 0 && jb < NBLK_) {
#pragma unroll
                for (int j = 0; j < 4; j++) {
                    st[t][j] *= scale;
                    mx = fmaxf(mx, st[t][j]);
                }
            }
        }
        mx = fmaxf(mx, __shfl_xor(mx, 16));
        mx = fmaxf(mx, __shfl_xor(mx, 32));
        float sum = 0.f;
#pragma unroll
        for (int t = 0; t < 10; t++) {
            int jb = i - 2 + (t >> 1);
            if (jb >= 0 && jb < NBLK_) {
#pragma unroll
                for (int j = 0; j < 4; j++) {
                    float e = __expf(st[t][j] - mx);
                    st[t][j] = e;
                    sum += e;
                }
            }
        }
        sum += __shfl_xor(sum, 16);
        sum += __shfl_xor(sum, 32);
        float inv = 1.f / sum;
        f32x4 o0 = (f32x4){0.f, 0.f, 0.f, 0.f};
        f32x4 o1 = (f32x4){0.f, 0.f, 0.f, 0.f};
        const short* vt = (const short*)Vt;
#pragma unroll
        for (int t = 0; t < 10; t++) {
            int jb = i - 2 + (t >> 1);
            if (jb >= 0 && jb < NBLK_) {
                short8 pa = (short8)0;
#pragma unroll
                for (int j = 0; j < 4; j++) pa[j] = (short)f2bf(st[t][j] * inv);
                int kb = wid * 32 + t * 16 + g * 4;
                short4v vb0 = *(const short4v*)(vt + (0 * 16 + c) * 264 + kb);
                short4v vb1 = *(const short4v*)(vt + (1 * 16 + c) * 264 + kb);
                short8 b0 = (short8)0, b1 = (short8)0;
#pragma unroll
                for (int e = 0; e < 4; e++) { b0[e] = vb0[e]; b1[e] = vb1[e]; }
                o0 = __builtin_amdgcn_mfma_f32_16x16x32_bf16(pa, b0, o0, 0, 0, 0);
                o1 = __builtin_amdgcn_mfma_f32_16x16x32_bf16(pa, b1, o1, 0, 0, 0);
            }
        }
#pragma unroll
        for (int j = 0; j < 4; j++) {
            size_t rbase = ((size_t)(b * N_ + i * 32 + qt * 16 + g * 4 + j)) * D_ + h * DH_;
            outb[rbase + c] = __float2bfloat16(o0[j]);
            outb[rbase + 16 + c] = __float2bfloat16(o1[j]);
        }
    }
}

// ---------------------------------------------------------------- fcl
__global__ __launch_bounds__(256) void fcl_partial_kernel(
    const float* __restrict__ flat, const float* __restrict__ W,
    float* __restrict__ partial) {
    int chunk = blockIdx.x;             // 1280
    int t = threadIdx.x;
    int k0 = chunk * FCL_KB;
    __shared__ float fl[FCL_KB][20];
#pragma unroll
    for (int b = 0; b < 16; b++)
        fl[t][b] = flat[(size_t)b * FCL_K + k0 + t];
    __syncthreads();
    int j = t & 127, bg = t >> 7;
    f32x4 a0 = (f32x4){0.f, 0.f, 0.f, 0.f};
    f32x4 a1 = (f32x4){0.f, 0.f, 0.f, 0.f};
#pragma unroll 8
    for (int k = 0; k < FCL_KB; k++) {
        float w = W[(size_t)(k0 + k) * 128 + j];
        f32x4 f0 = *(const f32x4*)&fl[k][bg * 8];
        f32x4 f1 = *(const f32x4*)&fl[k][bg * 8 + 4];
        a0 += f0 * w;
        a1 += f1 * w;
    }
#pragma unroll
    for (int bi = 0; bi < 4; bi++) {
        partial[((size_t)chunk * 16 + bg * 8 + bi) * 128 + j] = a0[bi];
        partial[((size_t)chunk * 16 + bg * 8 + 4 + bi) * 128 + j] = a1[bi];
    }
}

__global__ __launch_bounds__(256) void fcl_reduce_kernel(
    const float* __restrict__ partial, const float* __restrict__ fcl_b,
    float* __restrict__ add) {
    int c0 = blockIdx.x * 32;
    int t = threadIdx.x;
    int ry = t >> 5, cx = t & 31;
    float s = 0.f;
    for (int r = ry; r < FCL_CHUNKS; r += 8)
        s += partial[(size_t)r * 2048 + c0 + cx];
    __shared__ float red[8][32];
    red[ry][cx] = s; __syncthreads();
    if (ry == 0) {
        float tot = 0.f;
#pragma unroll
        for (int q = 0; q < 8; q++) tot += red[q][cx];
        int col = c0 + cx;
        add[col] = tot + fcl_b[col & 127];
    }
}

// ---------------------------------------------------------------- fused head
__global__ __launch_bounds__(256) void head_kernel(
    const float* __restrict__ add, const float* __restrict__ abg, const float* __restrict__ abb,
    const float* __restrict__ cls_W1, const float* __restrict__ cls_b1,
    const float* __restrict__ cls_W2, const float* __restrict__ cls_b2,
    const float* __restrict__ box_W1, const float* __restrict__ box_b1,
    const float* __restrict__ box_W2, const float* __restrict__ box_b2,
    float* __restrict__ out) {
    __shared__ float a2[16][128];
    __shared__ float cm[16][256];
    __shared__ float cls[16][45];
    __shared__ float bmid[16][128];
    __shared__ float smden[16];
    int t = threadIdx.x;
    if (t < 128) {
        float m = 0.f;
#pragma unroll
        for (int b = 0; b < 16; b++) m += add[b * 128 + t];
        m *= (1.f / 16.f);
        float v = 0.f;
#pragma unroll
        for (int b = 0; b < 16; b++) { float d = add[b * 128 + t] - m; v += d * d; }
        v *= (1.f / 16.f);
        float sc = rsqrtf(v + 1e-5f) * abg[t];
#pragma unroll
        for (int b = 0; b < 16; b++) a2[b][t] = (add[b * 128 + t] - m) * sc + abb[t];
    }
    __syncthreads();
    for (int idx = t; idx < 4096; idx += 256) {
        int m = idx >> 8, c = idx & 255;
        float a = cls_b1[c];
        for (int k = 0; k < 128; k++) a += a2[m][k] * cls_W1[k * 256 + c];
        cm[m][c] = fmaxf(a, 0.f);
    }
    for (int idx = t; idx < 2048; idx += 256) {
        int m = idx >> 7, c = idx & 127;
        float a = box_b1[c];
        for (int k = 0; k < 128; k++) a += a2[m][k] * box_W1[k * 128 + c];
        bmid[m][c] = fmaxf(a, 0.f);
    }
    __syncthreads();
    for (int idx = t; idx < 720; idx += 256) {
        int m = idx / 45, c = idx % 45;
        float a = cls_b2[c];
        for (int k = 0; k < 256; k++) a += cm[m][k] * cls_W2[k * 45 + c];
        cls[m][c] = a;
    }
    __syncthreads();
    if (t < 16) {
        float mx = -1e30f;
        for (int c = 0; c < 45; c++) mx = fmaxf(mx, cls[t][c]);
        float s = 0.f;
        for (int c = 0; c < 45; c++) { float e = expf(cls[t][c] - mx); cls[t][c] = e; s += e; }
        smden[t] = s;
    }
    for (int idx = t; idx < 576; idx += 256) {
        int m = idx / 36, c = idx % 36;
        float a = box_b2[c];
        for (int k = 0; k < 128; k++) a += bmid[m][k] * box_W2[k * 36 + c];
        out[m * 81 + (c >> 2) * 9 + 5 + (c & 3)] = a;
    }
    __syncthreads();
    for (int idx = t; idx < 720; idx += 256) {
        int m = idx / 45, c = idx % 45;
        out[m * 81 + (c / 5) * 9 + (c % 5)] = cls[m][c] / smden[m];
    }
}

// ================================================================ launcher
extern "C" void kernel_launch(void* const* d_in, const int* in_sizes, int n_in,
                              void* d_out, int out_size, void* d_ws, size_t ws_size,
                              hipStream_t stream) {
    const float* x_in    = (const float*)d_in[0];
    const float* patch_W = (const float*)d_in[1];
    const float* patch_b = (const float*)d_in[2];
    const float* ln_g    = (const float*)d_in[3];
    const float* ln_b    = (const float*)d_in[4];
    const float* ff_W1   = (const float*)d_in[5];
    const float* ff_b1   = (const float*)d_in[6];
    const float* ff_W2   = (const float*)d_in[7];
    const float* ff_b2   = (const float*)d_in[8];
    const float* Wqkv    = (const float*)d_in[9];
    const float* bqkv    = (const float*)d_in[10];
    const float* Wo      = (const float*)d_in[11];
    const float* bo      = (const float*)d_in[12];
    const float* bn1_g   = (const float*)d_in[13];
    const float* bn1_b   = (const float*)d_in[14];
    const float* bn2_g   = (const float*)d_in[15];
    const float* bn2_b   = (const float*)d_in[16];
    const float* pyr_W   = (const float*)d_in[17];
    const float* pyr_b   = (const float*)d_in[18];
    const float* fcl_W   = (const float*)d_in[19];
    const float* fcl_b   = (const float*)d_in[20];
    const float* addbn_g = (const float*)d_in[21];
    const float* addbn_b = (const float*)d_in[22];
    const float* cls_W1  = (const float*)d_in[23];
    const float* cls_b1  = (const float*)d_in[24];
    const float* cls_W2  = (const float*)d_in[25];
    const float* cls_b2  = (const float*)d_in[26];
    const float* box_W1  = (const float*)d_in[27];
    const float* box_b1  = (const float*)d_in[28];
    const float* box_W2  = (const float*)d_in[29];
    const float* box_b2  = (const float*)d_in[30];
    float* out = (float*)d_out;

    float* ws = (float*)d_ws;
    size_t off = 0;
    float* POS   = ws + off; off += 131072;
    float* H     = ws + off; off += 2097152;
    float* T     = ws + off; off += 2097152;
    float* UNION = ws + off; off += 4194304;   // MIDb bf16 / QKVb bf16
    float* FLAT  = ws + off; off += 5242880;
    float* PART  = ws + off; off += (size_t)FCL_CHUNKS * 2048;
    float* BNP   = ws + off; off += 2 * 32768;
    float* ADD   = ws + off; off += 2048;
    __hip_bfloat16* Hb   = (__hip_bfloat16*)(ws + off); off += 1048576;
    __hip_bfloat16* Tb   = (__hip_bfloat16*)(ws + off); off += 1048576;
    __hip_bfloat16* Xb   = (__hip_bfloat16*)(ws + off); off += 1048576;
    __hip_bfloat16* ATb  = (__hip_bfloat16*)(ws + off); off += 1048576;
    __hip_bfloat16* patchWt = (__hip_bfloat16*)(ws + off); off += 32768;
    __hip_bfloat16* qkvWt   = (__hip_bfloat16*)(ws + off); off += 98304;
    __hip_bfloat16* WoWt    = (__hip_bfloat16*)(ws + off); off += 32768;
    __hip_bfloat16* W1t     = (__hip_bfloat16*)(ws + off); off += 131072;
    __hip_bfloat16* W2t     = (__hip_bfloat16*)(ws + off); off += 131072;
    __hip_bfloat16* pyrWt   = (__hip_bfloat16*)(ws + off); off += 81920;
    __hip_bfloat16* MIDb = (__hip_bfloat16*)UNION;
    __hip_bfloat16* QKVb = (__hip_bfloat16*)UNION;

    prep_kernel<<<2528, 256, 0, stream>>>(
        patch_W, Wqkv, Wo, ff_W1, ff_W2, pyr_W, x_in,
        patchWt, qkvWt, WoWt, W1t, W2t, pyrWt, POS, Xb);

    for (int it = 0; it < 5; it++) {
        patchln_kernel<<<256, 256, 0, stream>>>(Xb, patchWt, patch_b, ln_g, ln_b, POS, H, Hb);
        // FF1: 128x128 tile, grid 512 (2/CU)
        bgemm_kernel<1, false, true, false, false, 128, 128><<<dim3(8, 64), 256, 0, stream>>>(
            Hb, W1t, ff_b1, nullptr, nullptr, MIDb, ROWS_, HIDEF_, D_, 0, nullptr);
        // FF2: 64x64 tile, grid 512 (2/CU)
        bgemm_kernel<0, false, true, false, false, 64, 64><<<dim3(4, 128), 256, 0, stream>>>(
            MIDb, W2t, ff_b2, nullptr, nullptr, Tb, ROWS_, D_, HIDEF_, 0, nullptr);
        // qkv: 128x64, grid 768 (3/CU)
        bgemm_kernel<0, false, true, false, false, 128, 64><<<dim3(12, 64), 256, 0, stream>>>(
            Tb, qkvWt, bqkv, nullptr, nullptr, QKVb, ROWS_, 768, D_, 0, nullptr);
        attn_kernel<<<dim3(4, HEADS_, B_), 256, 0, stream>>>(QKVb, ATb);
        // proj (+resid, STATS): 64x64, grid 512
        bgemm_kernel<0, true, false, false, true, 64, 64><<<dim3(4, 128), 256, 0, stream>>>(
            ATb, WoWt, bo, H, T, nullptr, ROWS_, D_, D_, 0, BNP);
        bn_applyfin_kernel<<<256, 256, 0, stream>>>(T, BNP, 128, bn1_g, bn1_b, H, Hb);
        bgemm_kernel<1, false, true, false, false, 128, 128><<<dim3(8, 64), 256, 0, stream>>>(
            Hb, W1t, ff_b1, nullptr, nullptr, MIDb, ROWS_, HIDEF_, D_, 0, nullptr);
        bgemm_kernel<0, true, false, false, true, 64, 64><<<dim3(4, 128), 256, 0, stream>>>(
            MIDb, W2t, ff_b2, H, T, nullptr, ROWS_, D_, HIDEF_, 0, BNP);
        bn_applyfin_kernel<<<256, 256, 0, stream>>>(T, BNP, 128, bn2_g, bn2_b, nullptr, Xb);
        // pyramid: 64x64 SCAT
        bgemm_kernel<0, false, false, true, false, 64, 64><<<dim3(128, 2), 256, 0, stream>>>(
            pyrWt + (size_t)it * D_ * PYOUT_, Xb, pyr_b + it * PYOUT_, nullptr,
            FLAT, nullptr, PYOUT_, ROWS_, D_, it, nullptr);
    }

    fcl_partial_kernel<<<FCL_CHUNKS, 256, 0, stream>>>(FLAT, fcl_W, PART);
    fcl_reduce_kernel<<<64, 256, 0, stream>>>(PART, fcl_b, ADD);
    head_kernel<<<1, 256, 0, stream>>>(ADD, addbn_g, addbn_b,
        cls_W1, cls_b1, cls_W2, cls_b2, box_W1, box_b1, box_W2, box_b2, out);
    (void)in_sizes; (void)n_in; (void)out_size; (void)ws_size;
}

// Round 10
// 879.441 us; speedup vs baseline: 5.2768x; 1.0420x over previous
//
#include <hip/hip_runtime.h>
#include <hip/hip_bf16.h>
#include <math.h>

#define B_ 16
#define N_ 512
#define D_ 256
#define HEADS_ 8
#define DH_ 32
#define HIDEF_ 1024
#define NBLK_ 16
#define BS_ 32
#define LEVELS_ 5
#define PYOUT_ 128
#define ROWS_ (B_ * N_)   // 8192
#define FCL_K 327680
#define FCL_KB 256
#define FCL_CHUNKS 1280

typedef __attribute__((ext_vector_type(8))) short short8;
typedef __attribute__((ext_vector_type(4))) short short4v;
typedef __attribute__((ext_vector_type(4))) unsigned short ushort4v;
typedef __attribute__((ext_vector_type(4))) float f32x4;

__device__ __forceinline__ float bf2f(short u) {
    return __uint_as_float(((unsigned int)(unsigned short)u) << 16);
}
__device__ __forceinline__ unsigned short f2bf(float x) {
    __hip_bfloat16 h = __float2bfloat16(x);
    return *reinterpret_cast<unsigned short*>(&h);
}

__device__ __forceinline__ float gelu_f(float x) {
    float x3 = x * x * x;
    return 0.5f * x * (1.f + tanhf(0.7978845608028654f * (x + 0.044715f * x3)));
}

// ---------------------------------------------------------------- combined prep
__global__ __launch_bounds__(256) void prep_kernel(
    const float* __restrict__ patch_W, const float* __restrict__ Wqkv,
    const float* __restrict__ Wo, const float* __restrict__ ff_W1,
    const float* __restrict__ ff_W2, const float* __restrict__ pyr_W,
    const float* __restrict__ x_in,
    __hip_bfloat16* __restrict__ patchWt, __hip_bfloat16* __restrict__ qkvWt,
    __hip_bfloat16* __restrict__ WoWt, __hip_bfloat16* __restrict__ W1t,
    __hip_bfloat16* __restrict__ W2t, __hip_bfloat16* __restrict__ pyrWt,
    float* __restrict__ pos, __hip_bfloat16* __restrict__ Xb) {
    __shared__ float tt[32][33];
    int bid = blockIdx.x, t = threadIdx.x;
    if (bid >= 1504) {           // x -> bf16, 2048 elems/block
        int base = (bid - 1504) * 2048 + t * 8;
        float4 a = *(const float4*)&x_in[base];
        float4 b = *(const float4*)&x_in[base + 4];
        ushort4v u0 = {f2bf(a.x), f2bf(a.y), f2bf(a.z), f2bf(a.w)};
        ushort4v u1 = {f2bf(b.x), f2bf(b.y), f2bf(b.z), f2bf(b.w)};
        *(ushort4v*)((short*)Xb + base) = u0;
        *(ushort4v*)((short*)Xb + base + 4) = u1;
        return;
    }
    if (bid >= 992) {            // pos table
        int idx = (bid - 992) * 256 + t;
        int n = idx >> 8, i = idx & 255;
        double angle = (double)n / pow(10000.0, (double)(2 * (i >> 1)) / 256.0);
        pos[idx] = (float)((i & 1) ? cos(angle) : sin(angle));
        return;
    }
    const float* W; __hip_bfloat16* Wt; int K, N, bx, by;
    if (bid < 64)       { W = patch_W; Wt = patchWt; K = 256; N = 256; bx = bid % 8; by = bid / 8; }
    else if (bid < 256) { int l = bid - 64;  W = Wqkv;  Wt = qkvWt; K = 256; N = 768;  bx = l % 24; by = l / 24; }
    else if (bid < 320) { int l = bid - 256; W = Wo;    Wt = WoWt;  K = 256; N = 256;  bx = l % 8;  by = l / 8; }
    else if (bid < 576) { int l = bid - 320; W = ff_W1; Wt = W1t;   K = 256; N = 1024; bx = l % 32; by = l / 32; }
    else if (bid < 832) { int l = bid - 576; W = ff_W2; Wt = W2t;   K = 1024; N = 256; bx = l % 8;  by = l / 8; }
    else                { int l = bid - 832; int z = l / 32; int r = l % 32;
                          W = pyr_W + (size_t)z * 256 * 128; Wt = pyrWt + (size_t)z * 256 * 128;
                          K = 256; N = 128; bx = r % 4; by = r / 4; }
    int bx32 = bx * 32, by32 = by * 32;
    int tx = t & 31, ty = t >> 5;
#pragma unroll
    for (int i = 0; i < 32; i += 8)
        tt[ty + i][tx] = W[(size_t)(by32 + ty + i) * N + bx32 + tx];
    __syncthreads();
#pragma unroll
    for (int i = 0; i < 32; i += 8)
        Wt[(size_t)(bx32 + ty + i) * K + by32 + tx] = __float2bfloat16(tt[tx][ty + i]);
}

// ---------------------------------------------------------------- bf16 MFMA GEMM
// BK=64, double-buffered, XCD-aware bijective block swizzle (grids % 8 == 0).
template <int ACT, bool OUTF, bool OUTB, bool STATS, int BM, int BN>
__global__ __launch_bounds__(256) void bgemm_kernel(
    const __hip_bfloat16* __restrict__ A, const __hip_bfloat16* __restrict__ Wt,
    const float* __restrict__ bias, const float* __restrict__ resid,
    float* __restrict__ C, __hip_bfloat16* __restrict__ Cb, int M, int Nn, int K,
    float* __restrict__ bnp) {
    __shared__ __hip_bfloat16 Alds[2][BM * 64];
    __shared__ __hip_bfloat16 Blds[2][BN * 64];
    constexpr int WM_ = (BM == 128 && BN == 64) ? 4 : 2;
    constexpr int WN_ = 4 / WM_;
    constexpr int WH = BM / WM_;
    constexpr int WC = BN / WN_;
    constexpr int MW = WH / 16;
    constexpr int NW = WC / 16;
    constexpr int AR = BM / 32;
    constexpr int BR = BN / 32;
    int tid = threadIdx.x;
    int wid = tid >> 6, lane = tid & 63;
    // XCD-aware bijective swizzle: HW assigns dispatch-id % 8 -> XCD.
    int flat = blockIdx.y * gridDim.x + blockIdx.x;
    int q8 = (gridDim.x * gridDim.y) >> 3;
    int wg = (flat & 7) * q8 + (flat >> 3);
    int bx = wg % gridDim.x, by = wg / gridDim.x;
    int row0 = by * BM, col0 = bx * BN;
    int wr = wid / WN_, wc = wid % WN_;
    int r16 = lane & 15, kq = lane >> 4;

    f32x4 acc[MW][NW];
#pragma unroll
    for (int m = 0; m < MW; m++)
#pragma unroll
        for (int n = 0; n < NW; n++) acc[m][n] = (f32x4){0.f, 0.f, 0.f, 0.f};

    auto stage = [&](int b, int k0) {
#pragma unroll
        for (int i = 0; i < AR; i++) {
            int slot = i * 256 + tid;
            int row = slot >> 3, qp = slot & 7;
            int q = qp ^ ((row >> 1) & 7);
            const __hip_bfloat16* ga = A + (size_t)(row0 + row) * K + k0 + q * 8;
            __builtin_amdgcn_global_load_lds(
                (const __attribute__((address_space(1))) void*)ga,
                (__attribute__((address_space(3))) void*)((char*)&Alds[b][0] + i * 4096 + wid * 1024),
                16, 0, 0);
        }
#pragma unroll
        for (int i = 0; i < BR; i++) {
            int slot = i * 256 + tid;
            int row = slot >> 3, qp = slot & 7;
            int q = qp ^ ((row >> 1) & 7);
            const __hip_bfloat16* gb = Wt + (size_t)(col0 + row) * K + k0 + q * 8;
            __builtin_amdgcn_global_load_lds(
                (const __attribute__((address_space(1))) void*)gb,
                (__attribute__((address_space(3))) void*)((char*)&Blds[b][0] + i * 4096 + wid * 1024),
                16, 0, 0);
        }
    };

    stage(0, 0);
    __syncthreads();
    int cur = 0;
    for (int k0 = 0; k0 < K; k0 += 64) {
        if (k0 + 64 < K) stage(cur ^ 1, k0 + 64);
#pragma unroll
        for (int h = 0; h < 2; h++) {
            short8 af[MW], bf4[NW];
#pragma unroll
            for (int m = 0; m < MW; m++) {
                int row = wr * WH + m * 16 + r16;
                int phys = (h * 4 + kq) ^ ((row >> 1) & 7);
                af[m] = *reinterpret_cast<const short8*>(
                    reinterpret_cast<const char*>(&Alds[cur][0]) + row * 128 + phys * 16);
            }
#pragma unroll
            for (int n = 0; n < NW; n++) {
                int row = wc * WC + n * 16 + r16;
                int phys = (h * 4 + kq) ^ ((row >> 1) & 7);
                bf4[n] = *reinterpret_cast<const short8*>(
                    reinterpret_cast<const char*>(&Blds[cur][0]) + row * 128 + phys * 16);
            }
#pragma unroll
            for (int m = 0; m < MW; m++)
#pragma unroll
                for (int n = 0; n < NW; n++)
                    acc[m][n] = __builtin_amdgcn_mfma_f32_16x16x32_bf16(af[m], bf4[n], acc[m][n], 0, 0, 0);
        }
        __syncthreads();
        cur ^= 1;
    }

    int rg = lane >> 4;
    float s1a[NW], s2a[NW];
#pragma unroll
    for (int n = 0; n < NW; n++) { s1a[n] = 0.f; s2a[n] = 0.f; }
#pragma unroll
    for (int n = 0; n < NW; n++) {
        int cc = col0 + wc * WC + n * 16 + r16;
        float bv = bias[cc];
#pragma unroll
        for (int m = 0; m < MW; m++) {
            int rb = row0 + wr * WH + m * 16 + rg * 4;
#pragma unroll
            for (int j = 0; j < 4; j++) {
                int r = rb + j;
                float v = acc[m][n][j] + bv;
                if (resid) v += resid[(size_t)r * Nn + cc];
                if (ACT == 1) v = gelu_f(v);
                if (OUTF) C[(size_t)r * Nn + cc] = v;
                if (OUTB) Cb[(size_t)r * Nn + cc] = __float2bfloat16(v);
                if (STATS) { s1a[n] += v; s2a[n] += v * v; }
            }
        }
    }
    if (STATS) {
        float* sc = (float*)&Alds[0][0];
        int part = wid * 4 + rg;
#pragma unroll
        for (int n = 0; n < NW; n++) {
            int c = wc * WC + n * 16 + r16;
            sc[c * 16 + part] = s1a[n];
            sc[BN * 16 + c * 16 + part] = s2a[n];
        }
        __syncthreads();
        if (tid < BN) {
            float a = 0.f, b2 = 0.f;
#pragma unroll
            for (int p = 0; p < 16; p++) {
                a += sc[tid * 16 + p];
                b2 += sc[BN * 16 + tid * 16 + p];
            }
            bnp[by * 256 + col0 + tid] = a;
            bnp[32768 + by * 256 + col0 + tid] = b2;
        }
    }
}

// ---------------------------------------------------------------- patchln (it=0 only)
__global__ __launch_bounds__(256) void patchln_kernel(
    const __hip_bfloat16* __restrict__ A, const __hip_bfloat16* __restrict__ Wt,
    const float* __restrict__ bias, const float* __restrict__ lng,
    const float* __restrict__ lnb, const float* __restrict__ pos,
    float* __restrict__ H, __hip_bfloat16* __restrict__ Hb) {
    __shared__ char __attribute__((aligned(16))) smem[73728];
    float (*Cls)[260] = (float(*)[260])smem;
    int tid = threadIdx.x;
    int wid = tid >> 6, lane = tid & 63;
    int row0 = blockIdx.x * 32;
    int r16 = lane & 15, kq = lane >> 4, g = lane >> 4;

    f32x4 acc[2][4];
#pragma unroll
    for (int m = 0; m < 2; m++)
#pragma unroll
        for (int n = 0; n < 4; n++) acc[m][n] = (f32x4){0.f, 0.f, 0.f, 0.f};

    auto stage = [&](int b, int k0) {
        {
            int row = tid >> 3, qp = tid & 7;
            int q = qp ^ ((row >> 1) & 7);
            const __hip_bfloat16* ga = A + (size_t)(row0 + row) * 256 + k0 + q * 8;
            __builtin_amdgcn_global_load_lds(
                (const __attribute__((address_space(1))) void*)ga,
                (__attribute__((address_space(3))) void*)(smem + b * 4096 + wid * 1024),
                16, 0, 0);
        }
#pragma unroll
        for (int i = 0; i < 8; i++) {
            int slot = i * 256 + tid;
            int row = slot >> 3, qp = slot & 7;
            int q = qp ^ ((row >> 1) & 7);
            const __hip_bfloat16* gb = Wt + (size_t)row * 256 + k0 + q * 8;
            __builtin_amdgcn_global_load_lds(
                (const __attribute__((address_space(1))) void*)gb,
                (__attribute__((address_space(3))) void*)(smem + 8192 + b * 32768 + i * 4096 + wid * 1024),
                16, 0, 0);
        }
    };

    stage(0, 0);
    __syncthreads();
    int cur = 0;
    for (int k0 = 0; k0 < 256; k0 += 64) {
        if (k0 + 64 < 256) stage(cur ^ 1, k0 + 64);
        const char* Ab = smem + cur * 4096;
        const char* Bb = smem + 8192 + cur * 32768;
#pragma unroll
        for (int h = 0; h < 2; h++) {
            short8 af[2], bf4[4];
#pragma unroll
            for (int m = 0; m < 2; m++) {
                int row = m * 16 + r16;
                int phys = (h * 4 + kq) ^ ((row >> 1) & 7);
                af[m] = *reinterpret_cast<const short8*>(Ab + row * 128 + phys * 16);
            }
#pragma unroll
            for (int n = 0; n < 4; n++) {
                int row = wid * 64 + n * 16 + r16;
                int phys = (h * 4 + kq) ^ ((row >> 1) & 7);
                bf4[n] = *reinterpret_cast<const short8*>(Bb + row * 128 + phys * 16);
            }
#pragma unroll
            for (int m = 0; m < 2; m++)
#pragma unroll
                for (int n = 0; n < 4; n++)
                    acc[m][n] = __builtin_amdgcn_mfma_f32_16x16x32_bf16(af[m], bf4[n], acc[m][n], 0, 0, 0);
        }
        __syncthreads();
        cur ^= 1;
    }
#pragma unroll
    for (int n = 0; n < 4; n++) {
        int col = wid * 64 + n * 16 + r16;
        float bv = bias[col];
#pragma unroll
        for (int m = 0; m < 2; m++)
#pragma unroll
            for (int j = 0; j < 4; j++)
                Cls[m * 16 + g * 4 + j][col] = acc[m][n][j] + bv;
    }
    __syncthreads();
    float4 g4 = ((const float4*)lng)[lane];
    float4 b4 = ((const float4*)lnb)[lane];
#pragma unroll
    for (int rr = 0; rr < 8; rr++) {
        int r = wid * 8 + rr;
        float4 v = *(const float4*)&Cls[r][lane * 4];
        float s = v.x + v.y + v.z + v.w;
#pragma unroll
        for (int mk = 32; mk; mk >>= 1) s += __shfl_xor(s, mk);
        float mean = s * (1.f / 256.f);
        float dx = v.x - mean, dy = v.y - mean, dz = v.z - mean, dw = v.w - mean;
        float q = dx * dx + dy * dy + dz * dz + dw * dw;
#pragma unroll
        for (int mk = 32; mk; mk >>= 1) q += __shfl_xor(q, mk);
        float rstd = rsqrtf(q * (1.f / 256.f) + 1e-5f);
        int grow = row0 + r;
        float4 p4 = ((const float4*)pos)[(size_t)(grow & (N_ - 1)) * 64 + lane];
        float o0 = dx * rstd * g4.x + b4.x + p4.x;
        float o1 = dy * rstd * g4.y + b4.y + p4.y;
        float o2 = dz * rstd * g4.z + b4.z + p4.z;
        float o3 = dw * rstd * g4.w + b4.w + p4.w;
        ((float4*)(H + (size_t)grow * D_))[lane] = (float4){o0, o1, o2, o3};
        ushort4v u = {f2bf(o0), f2bf(o1), f2bf(o2), f2bf(o3)};
        *((ushort4v*)(Hb + (size_t)grow * D_) + lane) = u;
    }
}

// ---------------------------------------------------------------- fused BN2 + patch + LN + pyr
// Block = 32 rows. Phases: (1) BN finish+apply -> xbLDS (bf16, chunk-XOR swz)
// (2) patch GEMM (A from xbLDS, B=patchWt staged) -> Cls -> LN+pos -> H,Hb
// (3) pyr GEMM (A from xbLDS, B=pyrWt staged) -> transposed LDS -> FLAT
template <bool DO_PATCH>
__global__ __launch_bounds__(256) void bnpatch_kernel(
    const float* __restrict__ T, const float* __restrict__ bnp,
    const float* __restrict__ bng, const float* __restrict__ bnb,
    const __hip_bfloat16* __restrict__ patchWt, const float* __restrict__ patch_b,
    const float* __restrict__ lng, const float* __restrict__ lnb,
    const float* __restrict__ pos,
    const __hip_bfloat16* __restrict__ pyrWt_l, const float* __restrict__ pyr_b_l,
    int level, float* __restrict__ FLAT,
    float* __restrict__ H, __hip_bfloat16* __restrict__ Hb) {
    __shared__ char __attribute__((aligned(16))) smem[68096];
    // layout: xb [0,16384) | REG_A [16384,49664) (patchW stage 32K / Cls 33.3K / olds)
    //         pyr stage [49664,66048) | sm/sv [66048,68096)
    float* sm = (float*)(smem + 66048);
    float* sv = sm + 256;
    int tid = threadIdx.x;
    int wid = tid >> 6, lane = tid & 63;
    int row0 = blockIdx.x * 32;
    int r16 = lane & 15, kq = lane >> 4, g = lane >> 4;
    int wr = wid >> 1, wc = wid & 1;

    // ---- phase 1: BN stats finish (redundant per block, L2-served)
    {
        float s = 0.f, s2 = 0.f;
#pragma unroll 4
        for (int yy = 0; yy < 128; yy++) {
            s += bnp[yy * 256 + tid];
            s2 += bnp[32768 + yy * 256 + tid];
        }
        float m = s * (1.f / 8192.f);
        sm[tid] = m;
        sv[tid] = rsqrtf(s2 * (1.f / 8192.f) - m * m + 1e-5f);
    }
    __syncthreads();
    // apply -> xbLDS (swizzled bf16)
    {
        float4 m4 = ((const float4*)sm)[lane];
        float4 r4 = ((const float4*)sv)[lane];
        float4 g4 = ((const float4*)bng)[lane];
        float4 b4 = ((const float4*)bnb)[lane];
#pragma unroll
        for (int rr = 0; rr < 8; rr++) {
            int r = wid * 8 + rr;
            float4 x4 = ((const float4*)(T + (size_t)(row0 + r) * D_))[lane];
            float o0 = (x4.x - m4.x) * r4.x * g4.x + b4.x;
            float o1 = (x4.y - m4.y) * r4.y * g4.y + b4.y;
            float o2 = (x4.z - m4.z) * r4.z * g4.z + b4.z;
            float o3 = (x4.w - m4.w) * r4.w * g4.w + b4.w;
            ushort4v u = {f2bf(o0), f2bf(o1), f2bf(o2), f2bf(o3)};
            int c = lane >> 1;
            int phys = c ^ (r & 7);
            *(ushort4v*)(smem + r * 512 + phys * 16 + (lane & 1) * 8) = u;
        }
    }
    __syncthreads();

    if (DO_PATCH) {
        // ---- phase 2: patch GEMM 32x256, K=256, A from xbLDS
        f32x4 acc[8];
#pragma unroll
        for (int n = 0; n < 8; n++) acc[n] = (f32x4){0.f, 0.f, 0.f, 0.f};
        for (int k0 = 0; k0 < 256; k0 += 64) {
#pragma unroll
            for (int i = 0; i < 8; i++) {      // stage patchWt 256 rows x 64k = 32KB
                int slot = i * 256 + tid;
                int row = slot >> 3, qp = slot & 7;
                int q = qp ^ ((row >> 1) & 7);
                const __hip_bfloat16* gb = patchWt + (size_t)row * 256 + k0 + q * 8;
                __builtin_amdgcn_global_load_lds(
                    (const __attribute__((address_space(1))) void*)gb,
                    (__attribute__((address_space(3))) void*)(smem + 16384 + i * 4096 + wid * 1024),
                    16, 0, 0);
            }
            __syncthreads();
#pragma unroll
            for (int h = 0; h < 2; h++) {
                int arow = wr * 16 + r16;
                int ac = (k0 >> 3) + h * 4 + kq;
                int aphys = ac ^ (arow & 7);
                short8 af = *(const short8*)(smem + arow * 512 + aphys * 16);
                short8 bf4[8];
#pragma unroll
                for (int n = 0; n < 8; n++) {
                    int brow = wc * 128 + n * 16 + r16;
                    int bphys = (h * 4 + kq) ^ ((brow >> 1) & 7);
                    bf4[n] = *(const short8*)(smem + 16384 + brow * 128 + bphys * 16);
                }
#pragma unroll
                for (int n = 0; n < 8; n++)
                    acc[n] = __builtin_amdgcn_mfma_f32_16x16x32_bf16(af, bf4[n], acc[n], 0, 0, 0);
            }
            __syncthreads();
        }
        // Cls overlay on staging region
        float (*Cls)[260] = (float(*)[260])(smem + 16384);
#pragma unroll
        for (int n = 0; n < 8; n++) {
            int col = wc * 128 + n * 16 + r16;
            float bv = patch_b[col];
#pragma unroll
            for (int j = 0; j < 4; j++)
                Cls[wr * 16 + g * 4 + j][col] = acc[n][j] + bv;
        }
        __syncthreads();
        // ---- phase 3: LN + pos -> H, Hb
        float4 g4 = ((const float4*)lng)[lane];
        float4 b4 = ((const float4*)lnb)[lane];
#pragma unroll
        for (int rr = 0; rr < 8; rr++) {
            int r = wid * 8 + rr;
            float4 v = *(const float4*)&Cls[r][lane * 4];
            float s = v.x + v.y + v.z + v.w;
#pragma unroll
            for (int mk = 32; mk; mk >>= 1) s += __shfl_xor(s, mk);
            float mean = s * (1.f / 256.f);
            float dx = v.x - mean, dy = v.y - mean, dz = v.z - mean, dw = v.w - mean;
            float q = dx * dx + dy * dy + dz * dz + dw * dw;
#pragma unroll
            for (int mk = 32; mk; mk >>= 1) q += __shfl_xor(q, mk);
            float rstd = rsqrtf(q * (1.f / 256.f) + 1e-5f);
            int grow = row0 + r;
            float4 p4 = ((const float4*)pos)[(size_t)(grow & (N_ - 1)) * 64 + lane];
            float o0 = dx * rstd * g4.x + b4.x + p4.x;
            float o1 = dy * rstd * g4.y + b4.y + p4.y;
            float o2 = dz * rstd * g4.z + b4.z + p4.z;
            float o3 = dw * rstd * g4.w + b4.w + p4.w;
            ((float4*)(H + (size_t)grow * D_))[lane] = (float4){o0, o1, o2, o3};
            ushort4v u = {f2bf(o0), f2bf(o1), f2bf(o2), f2bf(o3)};
            *((ushort4v*)(Hb + (size_t)grow * D_) + lane) = u;
        }
    }

    // ---- phase 4: pyr GEMM 32x128, K=256, A from xbLDS
    f32x4 pacc[4];
#pragma unroll
    for (int n = 0; n < 4; n++) pacc[n] = (f32x4){0.f, 0.f, 0.f, 0.f};
    for (int k0 = 0; k0 < 256; k0 += 64) {
#pragma unroll
        for (int i = 0; i < 4; i++) {          // stage pyrWt 128 rows x 64k = 16KB
            int slot = i * 256 + tid;
            int row = slot >> 3, qp = slot & 7;
            int q = qp ^ ((row >> 1) & 7);
            const __hip_bfloat16* gb = pyrWt_l + (size_t)row * 256 + k0 + q * 8;
            __builtin_amdgcn_global_load_lds(
                (const __attribute__((address_space(1))) void*)gb,
                (__attribute__((address_space(3))) void*)(smem + 49664 + i * 4096 + wid * 1024),
                16, 0, 0);
        }
        __syncthreads();
#pragma unroll
        for (int h = 0; h < 2; h++) {
            int arow = wr * 16 + r16;
            int ac = (k0 >> 3) + h * 4 + kq;
            int aphys = ac ^ (arow & 7);
            short8 af = *(const short8*)(smem + arow * 512 + aphys * 16);
            short8 bf4[4];
#pragma unroll
            for (int n = 0; n < 4; n++) {
                int brow = wc * 64 + n * 16 + r16;
                int bphys = (h * 4 + kq) ^ ((brow >> 1) & 7);
                bf4[n] = *(const short8*)(smem + 49664 + brow * 128 + bphys * 16);
            }
#pragma unroll
            for (int n = 0; n < 4; n++)
                pacc[n] = __builtin_amdgcn_mfma_f32_16x16x32_bf16(af, bf4[n], pacc[n], 0, 0, 0);
        }
        __syncthreads();
    }
    // transpose via LDS (overlay REG_A; Cls dead after LN barrier in pyr loop)
    float (*olds)[33] = (float(*)[33])(smem + 16384);
#pragma unroll
    for (int n = 0; n < 4; n++) {
        int ch = wc * 64 + n * 16 + r16;
        float bv = pyr_b_l[ch];
#pragma unroll
        for (int j = 0; j < 4; j++)
            olds[ch][wr * 16 + g * 4 + j] = pacc[n][j] + bv;
    }
    __syncthreads();
    {
        int ch = tid >> 1, half = tid & 1;
        int bb = row0 >> 9, nn0 = (row0 & 511) + half * 16;
        float* dst = FLAT + (size_t)bb * 327680 + (size_t)(level * 128 + ch) * 512 + nn0;
        const float* src = &olds[ch][half * 16];
#pragma unroll
        for (int q = 0; q < 4; q++)
            *(float4*)(dst + q * 4) = *(const float4*)(src + q * 4);
    }
}

// ---------------------------------------------------------------- BN finish+apply (bn1)
__global__ __launch_bounds__(256) void bn_applyfin_kernel(
    const float* __restrict__ x, const float* __restrict__ bnp, int prows,
    const float* __restrict__ g, const float* __restrict__ b,
    float* __restrict__ y, __hip_bfloat16* __restrict__ yb) {
    int tid = threadIdx.x;
    __shared__ float sm[256], sv[256];
    {
        float s = 0.f, s2 = 0.f;
#pragma unroll 4
        for (int yy = 0; yy < prows; yy++) {
            s += bnp[yy * 256 + tid];
            s2 += bnp[32768 + yy * 256 + tid];
        }
        float m = s * (1.f / 8192.f);
        sm[tid] = m;
        sv[tid] = rsqrtf(s2 * (1.f / 8192.f) - m * m + 1e-5f);
    }
    __syncthreads();
    int lane = tid & 63, w = tid >> 6;
    int row0 = blockIdx.x * 32;
    float4 m4 = *(const float4*)&sm[lane * 4];
    float4 r4 = *(const float4*)&sv[lane * 4];
    float4 g4 = ((const float4*)g)[lane];
    float4 b4 = ((const float4*)b)[lane];
#pragma unroll
    for (int rr = 0; rr < 8; rr++) {
        int row = row0 + w * 8 + rr;
        float4 x4 = ((const float4*)(x + (size_t)row * D_))[lane];
        float o0 = (x4.x - m4.x) * r4.x * g4.x + b4.x;
        float o1 = (x4.y - m4.y) * r4.y * g4.y + b4.y;
        float o2 = (x4.z - m4.z) * r4.z * g4.z + b4.z;
        float o3 = (x4.w - m4.w) * r4.w * g4.w + b4.w;
        if (y) ((float4*)(y + (size_t)row * D_))[lane] = (float4){o0, o1, o2, o3};
        if (yb) {
            ushort4v u = {f2bf(o0), f2bf(o1), f2bf(o2), f2bf(o3)};
            *((ushort4v*)(yb + (size_t)row * D_) + lane) = u;
        }
    }
}

// ---------------------------------------------------------------- MFMA attention
__global__ __launch_bounds__(256) void attn_kernel(
    const __hip_bfloat16* __restrict__ qkv, __hip_bfloat16* __restrict__ outb) {
    int bx = blockIdx.x, h = blockIdx.y, b = blockIdx.z;
    int tid = threadIdx.x;
    int wid = tid >> 6, lane = tid & 63;
    __shared__ __hip_bfloat16 Klds[256 * 32];
    __shared__ __hip_bfloat16 Vt[32 * 264];
    const short* q16 = (const short*)qkv;

#pragma unroll
    for (int r = 0; r < 4; r++) {
        int slot = r * 256 + tid;
        int row = slot >> 2, qp = slot & 3;
        int ql = qp ^ ((row >> 1) & 3);
        int jb = bx * 4 - 2 + (row >> 5);
        jb = jb < 0 ? 0 : (jb > 15 ? 15 : jb);
        const short* ga = q16 + ((size_t)(b * N_ + jb * 32 + (row & 31))) * 768 + 256 + h * 32 + ql * 8;
        __builtin_amdgcn_global_load_lds(
            (const __attribute__((address_space(1))) void*)ga,
            (__attribute__((address_space(3))) void*)((char*)Klds + r * 4096 + wid * 1024),
            16, 0, 0);
    }
    {
        int row = tid;
        int jb = bx * 4 - 2 + (row >> 5);
        jb = jb < 0 ? 0 : (jb > 15 ? 15 : jb);
        const short* gv = q16 + ((size_t)(b * N_ + jb * 32 + (row & 31))) * 768 + 512 + h * 32;
        short8 v0 = *(const short8*)(gv);
        short8 v1 = *(const short8*)(gv + 8);
        short8 v2 = *(const short8*)(gv + 16);
        short8 v3 = *(const short8*)(gv + 24);
        short* vt = (short*)Vt;
#pragma unroll
        for (int e = 0; e < 8; e++) {
            vt[(e) * 264 + row] = v0[e];
            vt[(8 + e) * 264 + row] = v1[e];
            vt[(16 + e) * 264 + row] = v2[e];
            vt[(24 + e) * 264 + row] = v3[e];
        }
    }
    __syncthreads();

    int i = bx * 4 + wid;
    int c = lane & 15, g = lane >> 4;
    const float scale = 0.17677669529663687f;

#pragma unroll
    for (int qt = 0; qt < 2; qt++) {
        const short* qa = q16 + ((size_t)(b * N_ + i * 32 + qt * 16 + c)) * 768 + h * 32 + g * 8;
        short8 bq = *(const short8*)qa;
        f32x4 st[10];
#pragma unroll
        for (int t = 0; t < 10; t++) {
            int jb = i - 2 + (t >> 1);
            if (jb >= 0 && jb < NBLK_) {
                int row = wid * 32 + t * 16 + c;
                int phys = g ^ ((row >> 1) & 3);
                short8 ak = *(const short8*)((const char*)Klds + row * 64 + phys * 16);
                st[t] = __builtin_amdgcn_mfma_f32_16x16x32_bf16(
                    ak, bq, (f32x4){0.f, 0.f, 0.f, 0.f}, 0, 0, 0);
            }
        }
        float mx = -1e30f;
#pragma unroll
        for (int t = 0; t < 10; t++) {
            int jb = i - 2 + (t >> 1);
            if (jb >= 0 && jb < NBLK_) {
#pragma unroll
                for (int j = 0; j < 4; j++) {
                    st[t][j] *= scale;
                    mx = fmaxf(mx, st[t][j]);
                }
            }
        }
        mx = fmaxf(mx, __shfl_xor(mx, 16));
        mx = fmaxf(mx, __shfl_xor(mx, 32));
        float sum = 0.f;
#pragma unroll
        for (int t = 0; t < 10; t++) {
            int jb = i - 2 + (t >> 1);
            if (jb >= 0 && jb < NBLK_) {
#pragma unroll
                for (int j = 0; j < 4; j++) {
                    float e = __expf(st[t][j] - mx);
                    st[t][j] = e;
                    sum += e;
                }
            }
        }
        sum += __shfl_xor(sum, 16);
        sum += __shfl_xor(sum, 32);
        float inv = 1.f / sum;
        f32x4 o0 = (f32x4){0.f, 0.f, 0.f, 0.f};
        f32x4 o1 = (f32x4){0.f, 0.f, 0.f, 0.f};
        const short* vt = (const short*)Vt;
#pragma unroll
        for (int t = 0; t < 10; t++) {
            int jb = i - 2 + (t >> 1);
            if (jb >= 0 && jb < NBLK_) {
                short8 pa = (short8)0;
#pragma unroll
                for (int j = 0; j < 4; j++) pa[j] = (short)f2bf(st[t][j] * inv);
                int kb = wid * 32 + t * 16 + g * 4;
                short4v vb0 = *(const short4v*)(vt + (0 * 16 + c) * 264 + kb);
                short4v vb1 = *(const short4v*)(vt + (1 * 16 + c) * 264 + kb);
                short8 b0 = (short8)0, b1 = (short8)0;
#pragma unroll
                for (int e = 0; e < 4; e++) { b0[e] = vb0[e]; b1[e] = vb1[e]; }
                o0 = __builtin_amdgcn_mfma_f32_16x16x32_bf16(pa, b0, o0, 0, 0, 0);
                o1 = __builtin_amdgcn_mfma_f32_16x16x32_bf16(pa, b1, o1, 0, 0, 0);
            }
        }
#pragma unroll
        for (int j = 0; j < 4; j++) {
            size_t rbase = ((size_t)(b * N_ + i * 32 + qt * 16 + g * 4 + j)) * D_ + h * DH_;
            outb[rbase + c] = __float2bfloat16(o0[j]);
            outb[rbase + 16 + c] = __float2bfloat16(o1[j]);
        }
    }
}

// ---------------------------------------------------------------- fcl
__global__ __launch_bounds__(256) void fcl_partial_kernel(
    const float* __restrict__ flat, const float* __restrict__ W,
    float* __restrict__ partial) {
    int chunk = blockIdx.x;             // 1280
    int t = threadIdx.x;
    int k0 = chunk * FCL_KB;
    __shared__ float fl[FCL_KB][20];
#pragma unroll
    for (int b = 0; b < 16; b++)
        fl[t][b] = flat[(size_t)b * FCL_K + k0 + t];
    __syncthreads();
    int j = t & 127, bg = t >> 7;
    f32x4 a0 = (f32x4){0.f, 0.f, 0.f, 0.f};
    f32x4 a1 = (f32x4){0.f, 0.f, 0.f, 0.f};
#pragma unroll 8
    for (int k = 0; k < FCL_KB; k++) {
        float w = W[(size_t)(k0 + k) * 128 + j];
        f32x4 f0 = *(const f32x4*)&fl[k][bg * 8];
        f32x4 f1 = *(const f32x4*)&fl[k][bg * 8 + 4];
        a0 += f0 * w;
        a1 += f1 * w;
    }
#pragma unroll
    for (int bi = 0; bi < 4; bi++) {
        partial[((size_t)chunk * 16 + bg * 8 + bi) * 128 + j] = a0[bi];
        partial[((size_t)chunk * 16 + bg * 8 + 4 + bi) * 128 + j] = a1[bi];
    }
}

__global__ __launch_bounds__(256) void fcl_reduce_kernel(
    const float* __restrict__ partial, const float* __restrict__ fcl_b,
    float* __restrict__ add) {
    int c0 = blockIdx.x * 32;
    int t = threadIdx.x;
    int ry = t >> 5, cx = t & 31;
    float s = 0.f;
    for (int r = ry; r < FCL_CHUNKS; r += 8)
        s += partial[(size_t)r * 2048 + c0 + cx];
    __shared__ float red[8][32];
    red[ry][cx] = s; __syncthreads();
    if (ry == 0) {
        float tot = 0.f;
#pragma unroll
        for (int q = 0; q < 8; q++) tot += red[q][cx];
        int col = c0 + cx;
        add[col] = tot + fcl_b[col & 127];
    }
}

// ---------------------------------------------------------------- fused head
__global__ __launch_bounds__(256) void head_kernel(
    const float* __restrict__ add, const float* __restrict__ abg, const float* __restrict__ abb,
    const float* __restrict__ cls_W1, const float* __restrict__ cls_b1,
    const float* __restrict__ cls_W2, const float* __restrict__ cls_b2,
    const float* __restrict__ box_W1, const float* __restrict__ box_b1,
    const float* __restrict__ box_W2, const float* __restrict__ box_b2,
    float* __restrict__ out) {
    __shared__ float a2[16][128];
    __shared__ float cm[16][256];
    __shared__ float cls[16][45];
    __shared__ float bmid[16][128];
    __shared__ float smden[16];
    int t = threadIdx.x;
    if (t < 128) {
        float m = 0.f;
#pragma unroll
        for (int b = 0; b < 16; b++) m += add[b * 128 + t];
        m *= (1.f / 16.f);
        float v = 0.f;
#pragma unroll
        for (int b = 0; b < 16; b++) { float d = add[b * 128 + t] - m; v += d * d; }
        v *= (1.f / 16.f);
        float sc = rsqrtf(v + 1e-5f) * abg[t];
#pragma unroll
        for (int b = 0; b < 16; b++) a2[b][t] = (add[b * 128 + t] - m) * sc + abb[t];
    }
    __syncthreads();
    for (int idx = t; idx < 4096; idx += 256) {
        int m = idx >> 8, c = idx & 255;
        float a = cls_b1[c];
        for (int k = 0; k < 128; k++) a += a2[m][k] * cls_W1[k * 256 + c];
        cm[m][c] = fmaxf(a, 0.f);
    }
    for (int idx = t; idx < 2048; idx += 256) {
        int m = idx >> 7, c = idx & 127;
        float a = box_b1[c];
        for (int k = 0; k < 128; k++) a += a2[m][k] * box_W1[k * 128 + c];
        bmid[m][c] = fmaxf(a, 0.f);
    }
    __syncthreads();
    for (int idx = t; idx < 720; idx += 256) {
        int m = idx / 45, c = idx % 45;
        float a = cls_b2[c];
        for (int k = 0; k < 256; k++) a += cm[m][k] * cls_W2[k * 45 + c];
        cls[m][c] = a;
    }
    __syncthreads();
    if (t < 16) {
        float mx = -1e30f;
        for (int c = 0; c < 45; c++) mx = fmaxf(mx, cls[t][c]);
        float s = 0.f;
        for (int c = 0; c < 45; c++) { float e = expf(cls[t][c] - mx); cls[t][c] = e; s += e; }
        smden[t] = s;
    }
    for (int idx = t; idx < 576; idx += 256) {
        int m = idx / 36, c = idx % 36;
        float a = box_b2[c];
        for (int k = 0; k < 128; k++) a += bmid[m][k] * box_W2[k * 36 + c];
        out[m * 81 + (c >> 2) * 9 + 5 + (c & 3)] = a;
    }
    __syncthreads();
    for (int idx = t; idx < 720; idx += 256) {
        int m = idx / 45, c = idx % 45;
        out[m * 81 + (c / 5) * 9 + (c % 5)] = cls[m][c] / smden[m];
    }
}

// ================================================================ launcher
extern "C" void kernel_launch(void* const* d_in, const int* in_sizes, int n_in,
                              void* d_out, int out_size, void* d_ws, size_t ws_size,
                              hipStream_t stream) {
    const float* x_in    = (const float*)d_in[0];
    const float* patch_W = (const float*)d_in[1];
    const float* patch_b = (const float*)d_in[2];
    const float* ln_g    = (const float*)d_in[3];
    const float* ln_b    = (const float*)d_in[4];
    const float* ff_W1   = (const float*)d_in[5];
    const float* ff_b1   = (const float*)d_in[6];
    const float* ff_W2   = (const float*)d_in[7];
    const float* ff_b2   = (const float*)d_in[8];
    const float* Wqkv    = (const float*)d_in[9];
    const float* bqkv    = (const float*)d_in[10];
    const float* Wo      = (const float*)d_in[11];
    const float* bo      = (const float*)d_in[12];
    const float* bn1_g   = (const float*)d_in[13];
    const float* bn1_b   = (const float*)d_in[14];
    const float* bn2_g   = (const float*)d_in[15];
    const float* bn2_b   = (const float*)d_in[16];
    const float* pyr_W   = (const float*)d_in[17];
    const float* pyr_b   = (const float*)d_in[18];
    const float* fcl_W   = (const float*)d_in[19];
    const float* fcl_b   = (const float*)d_in[20];
    const float* addbn_g = (const float*)d_in[21];
    const float* addbn_b = (const float*)d_in[22];
    const float* cls_W1  = (const float*)d_in[23];
    const float* cls_b1  = (const float*)d_in[24];
    const float* cls_W2  = (const float*)d_in[25];
    const float* cls_b2  = (const float*)d_in[26];
    const float* box_W1  = (const float*)d_in[27];
    const float* box_b1  = (const float*)d_in[28];
    const float* box_W2  = (const float*)d_in[29];
    const float* box_b2  = (const float*)d_in[30];
    float* out = (float*)d_out;

    float* ws = (float*)d_ws;
    size_t off = 0;
    float* POS   = ws + off; off += 131072;
    float* H     = ws + off; off += 2097152;
    float* T     = ws + off; off += 2097152;
    float* UNION = ws + off; off += 4194304;   // MIDb bf16 / QKVb bf16
    float* FLAT  = ws + off; off += 5242880;
    float* PART  = ws + off; off += (size_t)FCL_CHUNKS * 2048;
    float* BNP   = ws + off; off += 2 * 32768;
    float* ADD   = ws + off; off += 2048;
    __hip_bfloat16* Hb   = (__hip_bfloat16*)(ws + off); off += 1048576;
    __hip_bfloat16* Tb   = (__hip_bfloat16*)(ws + off); off += 1048576;
    __hip_bfloat16* Xb   = (__hip_bfloat16*)(ws + off); off += 1048576;
    __hip_bfloat16* ATb  = (__hip_bfloat16*)(ws + off); off += 1048576;
    __hip_bfloat16* patchWt = (__hip_bfloat16*)(ws + off); off += 32768;
    __hip_bfloat16* qkvWt   = (__hip_bfloat16*)(ws + off); off += 98304;
    __hip_bfloat16* WoWt    = (__hip_bfloat16*)(ws + off); off += 32768;
    __hip_bfloat16* W1t     = (__hip_bfloat16*)(ws + off); off += 131072;
    __hip_bfloat16* W2t     = (__hip_bfloat16*)(ws + off); off += 131072;
    __hip_bfloat16* pyrWt   = (__hip_bfloat16*)(ws + off); off += 81920;
    __hip_bfloat16* MIDb = (__hip_bfloat16*)UNION;
    __hip_bfloat16* QKVb = (__hip_bfloat16*)UNION;

    prep_kernel<<<2528, 256, 0, stream>>>(
        patch_W, Wqkv, Wo, ff_W1, ff_W2, pyr_W, x_in,
        patchWt, qkvWt, WoWt, W1t, W2t, pyrWt, POS, Xb);

    // it=0 patch+LN from initial Xb
    patchln_kernel<<<256, 256, 0, stream>>>(Xb, patchWt, patch_b, ln_g, ln_b, POS, H, Hb);

    for (int it = 0; it < 5; it++) {
        bgemm_kernel<1, false, true, false, 128, 128><<<dim3(8, 64), 256, 0, stream>>>(
            Hb, W1t, ff_b1, nullptr, nullptr, MIDb, ROWS_, HIDEF_, D_, nullptr);
        bgemm_kernel<0, false, true, false, 64, 64><<<dim3(4, 128), 256, 0, stream>>>(
            MIDb, W2t, ff_b2, nullptr, nullptr, Tb, ROWS_, D_, HIDEF_, nullptr);
        bgemm_kernel<0, false, true, false, 128, 64><<<dim3(12, 64), 256, 0, stream>>>(
            Tb, qkvWt, bqkv, nullptr, nullptr, QKVb, ROWS_, 768, D_, nullptr);
        attn_kernel<<<dim3(4, HEADS_, B_), 256, 0, stream>>>(QKVb, ATb);
        bgemm_kernel<0, true, false, true, 64, 64><<<dim3(4, 128), 256, 0, stream>>>(
            ATb, WoWt, bo, H, T, nullptr, ROWS_, D_, D_, BNP);
        bn_applyfin_kernel<<<256, 256, 0, stream>>>(T, BNP, 128, bn1_g, bn1_b, H, Hb);
        bgemm_kernel<1, false, true, false, 128, 128><<<dim3(8, 64), 256, 0, stream>>>(
            Hb, W1t, ff_b1, nullptr, nullptr, MIDb, ROWS_, HIDEF_, D_, nullptr);
        bgemm_kernel<0, true, false, true, 64, 64><<<dim3(4, 128), 256, 0, stream>>>(
            MIDb, W2t, ff_b2, H, T, nullptr, ROWS_, D_, HIDEF_, BNP);
        // fused: BN2 finish+apply + (patch GEMM + LN + pos for next iter) + pyr level it
        if (it < 4) {
            bnpatch_kernel<true><<<256, 256, 0, stream>>>(
                T, BNP, bn2_g, bn2_b, patchWt, patch_b, ln_g, ln_b, POS,
                pyrWt + (size_t)it * D_ * PYOUT_, pyr_b + it * PYOUT_, it, FLAT, H, Hb);
        } else {
            bnpatch_kernel<false><<<256, 256, 0, stream>>>(
                T, BNP, bn2_g, bn2_b, patchWt, patch_b, ln_g, ln_b, POS,
                pyrWt + (size_t)it * D_ * PYOUT_, pyr_b + it * PYOUT_, it, FLAT, H, Hb);
        }
    }

    fcl_partial_kernel<<<FCL_CHUNKS, 256, 0, stream>>>(FLAT, fcl_W, PART);
    fcl_reduce_kernel<<<64, 256, 0, stream>>>(PART, fcl_b, ADD);
    head_kernel<<<1, 256, 0, stream>>>(ADD, addbn_g, addbn_b,
        cls_W1, cls_b1, cls_W2, cls_b2, box_W1, box_b1, box_W2, box_b2, out);
    (void)in_sizes; (void)n_in; (void)out_size; (void)ws_size;
}